// Round 1
// baseline (1283.545 us; speedup 1.0000x reference)
//
#include <hip/hip_runtime.h>
#include <cmath>

static constexpr int TPB = 256;

// ---------- ordered-float encoding for atomicMax on float ----------
__device__ __forceinline__ unsigned enc_ord(float f) {
  unsigned b = __float_as_uint(f);
  return (b & 0x80000000u) ? ~b : (b | 0x80000000u);
}
__device__ __forceinline__ float dec_ord(unsigned k) {
  unsigned b = (k & 0x80000000u) ? (k ^ 0x80000000u) : ~k;
  return __uint_as_float(b);
}

// ---------- fp32 tiled GEMM: C[n,Nc] = A[n,K] @ B[K,Nc] ----------
__global__ __launch_bounds__(256) void gemm64(const float* __restrict__ A,
                                              const float* __restrict__ B,
                                              float* __restrict__ C,
                                              int n, int K, int Nc) {
  __shared__ float As[16][64];
  __shared__ float Bs[16][64];
  const int tid = threadIdx.x;
  const int tx = tid & 15, ty = tid >> 4;
  const int row0 = blockIdx.x * 64, col0 = blockIdx.y * 64;
  const int lr = tid >> 2, lc = (tid & 3) << 2;   // A tile load coords
  const int bk = tid >> 4, bc = (tid & 15) << 2;  // B tile load coords
  float acc[4][4] = {};
  for (int k0 = 0; k0 < K; k0 += 16) {
    float4 av = make_float4(0.f, 0.f, 0.f, 0.f);
    int gr = row0 + lr;
    if (gr < n) av = *(const float4*)(A + (size_t)gr * K + k0 + lc);
    As[lc + 0][lr] = av.x; As[lc + 1][lr] = av.y;
    As[lc + 2][lr] = av.z; As[lc + 3][lr] = av.w;
    *(float4*)&Bs[bk][bc] = *(const float4*)(B + (size_t)(k0 + bk) * Nc + col0 + bc);
    __syncthreads();
#pragma unroll
    for (int k = 0; k < 16; ++k) {
      float4 a = *(const float4*)&As[k][ty << 2];
      float4 b = *(const float4*)&Bs[k][tx << 2];
      acc[0][0] += a.x * b.x; acc[0][1] += a.x * b.y; acc[0][2] += a.x * b.z; acc[0][3] += a.x * b.w;
      acc[1][0] += a.y * b.x; acc[1][1] += a.y * b.y; acc[1][2] += a.y * b.z; acc[1][3] += a.y * b.w;
      acc[2][0] += a.z * b.x; acc[2][1] += a.z * b.y; acc[2][2] += a.z * b.z; acc[2][3] += a.z * b.w;
      acc[3][0] += a.w * b.x; acc[3][1] += a.w * b.y; acc[3][2] += a.w * b.z; acc[3][3] += a.w * b.w;
    }
    __syncthreads();
  }
#pragma unroll
  for (int i = 0; i < 4; ++i) {
    int r = row0 + (ty << 2) + i;
    if (r < n) {
      float4 v = make_float4(acc[i][0], acc[i][1], acc[i][2], acc[i][3]);
      *(float4*)(C + (size_t)r * Nc + col0 + (tx << 2)) = v;
    }
  }
}

// ---------- per-(node,head) attention logits: al = sum_c h*a ----------
template <int HH, int CC>
__global__ void compute_al(const float* __restrict__ hf, const float* __restrict__ a_s,
                           const float* __restrict__ a_d, float* __restrict__ als,
                           float* __restrict__ ald, int n) {
  int idx = blockIdx.x * TPB + threadIdx.x;
  if (idx >= n * HH) return;
  int node = idx / HH, h = idx - (idx / HH) * HH;
  const float* hp = hf + (size_t)node * (HH * CC) + h * CC;
  float s = 0.f, d = 0.f;
#pragma unroll
  for (int c = 0; c < CC; ++c) {
    float v = hp[c];
    s += v * a_s[h * CC + c];
    d += v * a_d[h * CC + c];
  }
  als[idx] = s;
  ald[idx] = d;
}

// ---------- init m/s/agg buffers ----------
__global__ void init_bufs(unsigned* __restrict__ menc, float* __restrict__ ssum,
                          float* __restrict__ agg, int nH, long long nAgg) {
  long long i = (long long)blockIdx.x * TPB + threadIdx.x;
  if (i < nH) { menc[i] = 0u; ssum[i] = 0.f; }  // 0 encodes < any finite float
  if (i < nAgg) agg[i] = 0.f;
}

// ---------- edge pass A: logits + leaky relu + segment max ----------
template <int HH>
__global__ void edge_pass_a(const int* __restrict__ esrc, const int* __restrict__ edst,
                            const float* __restrict__ als, const float* __restrict__ ald,
                            float* __restrict__ ebuf, unsigned* __restrict__ menc,
                            int E0, int Et) {
  int idx = blockIdx.x * TPB + threadIdx.x;
  if (idx >= Et * HH) return;
  int e = idx / HH, h = idx - (idx / HH) * HH;
  int s = e < E0 ? esrc[e] : e - E0;
  int d = e < E0 ? edst[e] : e - E0;
  float v = als[s * HH + h] + ald[d * HH + h];
  v = v > 0.f ? v : 0.2f * v;
  ebuf[idx] = v;
  atomicMax(&menc[d * HH + h], enc_ord(v));
}

// ---------- edge pass B: exp(e - m) + segment sum ----------
template <int HH>
__global__ void edge_pass_b(const int* __restrict__ edst, float* __restrict__ ebuf,
                            const unsigned* __restrict__ menc, float* __restrict__ ssum,
                            int E0, int Et) {
  int idx = blockIdx.x * TPB + threadIdx.x;
  if (idx >= Et * HH) return;
  int e = idx / HH, h = idx - (idx / HH) * HH;
  int d = e < E0 ? edst[e] : e - E0;
  float ex = expf(ebuf[idx] - dec_ord(menc[d * HH + h]));
  ebuf[idx] = ex;
  atomicAdd(&ssum[d * HH + h], ex);
}

// ---------- edge pass C: weighted scatter-add of h[src] into agg[dst] ----------
template <int HH, int CC>
__global__ void edge_pass_c(const int* __restrict__ esrc, const int* __restrict__ edst,
                            const float* __restrict__ hf, const float* __restrict__ ebuf,
                            const float* __restrict__ ssum, float* __restrict__ agg,
                            int E0, int Et) {
  constexpr int HIDL = HH * CC;
  long long idx = (long long)blockIdx.x * TPB + threadIdx.x;
  if (idx >= (long long)Et * HIDL) return;
  int e = (int)(idx / HIDL);
  int ch = (int)(idx - (long long)e * HIDL);
  int h = ch / CC;
  int s = e < E0 ? esrc[e] : e - E0;
  int d = e < E0 ? edst[e] : e - E0;
  float alpha = ebuf[e * HH + h] / (ssum[d * HH + h] + 1e-16f);
  atomicAdd(&agg[(size_t)d * HIDL + ch], hf[(size_t)s * HIDL + ch] * alpha);
}

// ---------- bias + LayerNorm + ELU (one wave per node) ----------
template <bool TWO>  // TWO: width 128, else 64
__global__ void ln_elu(const float* __restrict__ agg, const float* __restrict__ bias,
                       const float* __restrict__ g, const float* __restrict__ be,
                       float* __restrict__ xout, int n) {
  const int W = TWO ? 128 : 64;
  int wid = (int)((blockIdx.x * (size_t)blockDim.x + threadIdx.x) >> 6);
  int lane = threadIdx.x & 63;
  if (wid >= n) return;
  float v0 = agg[(size_t)wid * W + lane] + bias[lane];
  float v1 = 0.f;
  if (TWO) v1 = agg[(size_t)wid * W + 64 + lane] + bias[64 + lane];
  float s = v0 + v1;
  float s2 = v0 * v0 + v1 * v1;
#pragma unroll
  for (int off = 32; off >= 1; off >>= 1) {
    s += __shfl_xor(s, off);
    s2 += __shfl_xor(s2, off);
  }
  const float inv = 1.0f / W;
  float mu = s * inv;
  float var = s2 * inv - mu * mu;
  float r = rsqrtf(var + 1e-5f);
  float y0 = g[lane] * (v0 - mu) * r + be[lane];
  y0 = y0 > 0.f ? y0 : expf(y0) - 1.f;
  xout[(size_t)wid * W + lane] = y0;
  if (TWO) {
    float y1 = g[64 + lane] * (v1 - mu) * r + be[64 + lane];
    y1 = y1 > 0.f ? y1 : expf(y1) - 1.f;
    xout[(size_t)wid * W + 64 + lane] = y1;
  }
}

// ---------- pooling: per-block partial sum/max over nodes, 64 channels ----------
__global__ void pool_partial(const float* __restrict__ h, float* __restrict__ psum,
                             float* __restrict__ pmax, int n) {
  int tid = threadIdx.x;
  float lsum = 0.f, lmax = -1e30f;
  for (size_t idx = (size_t)blockIdx.x * 256 + tid; idx < (size_t)n * 64;
       idx += (size_t)gridDim.x * 256) {
    float v = h[idx];
    lsum += v;
    lmax = fmaxf(lmax, v);
  }
  __shared__ float ss[256], sm[256];
  ss[tid] = lsum; sm[tid] = lmax;
  __syncthreads();
  if (tid < 64) {
    float a = ss[tid] + ss[tid + 64] + ss[tid + 128] + ss[tid + 192];
    float m = fmaxf(fmaxf(sm[tid], sm[tid + 64]), fmaxf(sm[tid + 128], sm[tid + 192]));
    psum[blockIdx.x * 64 + tid] = a;
    pmax[blockIdx.x * 64 + tid] = m;
  }
}

// ---------- final reduce + classifier ----------
__global__ void pool_final(const float* __restrict__ psum, const float* __restrict__ pmax,
                           int nblocks, int n, const float* __restrict__ cW1,
                           const float* __restrict__ cb1, const float* __restrict__ cW2,
                           const float* __restrict__ cb2, float* __restrict__ out) {
  __shared__ float z[128];
  __shared__ float hid[128];
  int tid = threadIdx.x;
  if (tid < 64) {
    float s = 0.f, m = -1e30f;
    for (int b = 0; b < nblocks; ++b) {
      s += psum[b * 64 + tid];
      m = fmaxf(m, pmax[b * 64 + tid]);
    }
    z[tid] = s / (float)n;
    z[64 + tid] = m;
  }
  __syncthreads();
  float a = cb1[tid];
  for (int k = 0; k < 128; ++k) a += z[k] * cW1[k * 128 + tid];
  hid[tid] = fmaxf(a, 0.f);
  __syncthreads();
  if (tid < 2) {
    float o = cb2[tid];
    for (int j = 0; j < 128; ++j) o += hid[j] * cW2[j * 2 + tid];
    out[tid] = o;
  }
}

static inline int cdiv(long long a, long long b) { return (int)((a + b - 1) / b); }

extern "C" void kernel_launch(void* const* d_in, const int* in_sizes, int n_in,
                              void* d_out, int out_size, void* d_ws, size_t ws_size,
                              hipStream_t stream) {
  const float* x   = (const float*)d_in[0];
  const int*   ei  = (const int*)d_in[1];
  const float* W1  = (const float*)d_in[3];
  const float* as1 = (const float*)d_in[4];
  const float* ad1 = (const float*)d_in[5];
  const float* b1  = (const float*)d_in[6];
  const float* g1  = (const float*)d_in[7];
  const float* be1 = (const float*)d_in[8];
  const float* W2  = (const float*)d_in[9];
  const float* as2 = (const float*)d_in[10];
  const float* ad2 = (const float*)d_in[11];
  const float* b2  = (const float*)d_in[12];
  const float* g2  = (const float*)d_in[13];
  const float* be2 = (const float*)d_in[14];
  const float* W3  = (const float*)d_in[15];
  const float* as3 = (const float*)d_in[16];
  const float* ad3 = (const float*)d_in[17];
  const float* b3  = (const float*)d_in[18];
  const float* g3  = (const float*)d_in[19];
  const float* be3 = (const float*)d_in[20];
  const float* cW1 = (const float*)d_in[21];
  const float* cb1 = (const float*)d_in[22];
  const float* cW2 = (const float*)d_in[23];
  const float* cb2 = (const float*)d_in[24];
  float* out = (float*)d_out;

  const int N   = in_sizes[2];
  const int E0  = in_sizes[1] / 2;
  const int Et  = E0 + N;
  const int FIN = in_sizes[0] / N;

  float* ws = (float*)d_ws;
  size_t o = 0;
  float* Abuf = ws + o; o += (size_t)N * 128;
  float* Bbuf = ws + o; o += (size_t)N * 128;
  float* als  = ws + o; o += (size_t)N * 4;
  float* ald  = ws + o; o += (size_t)N * 4;
  unsigned* menc = (unsigned*)(ws + o); o += (size_t)N * 4;
  float* ssum = ws + o; o += (size_t)N * 4;
  float* ebuf = ws + o; o += (size_t)Et * 4;
  float* psum = ws + o; o += 256 * 64;
  float* pmax = ws + o; o += 256 * 64;

  const int* esrc = ei;
  const int* edst = ei + E0;

  // ===== Layer 1: x[N,512] -> h in Abuf, agg in Bbuf, ln -> Abuf =====
  {
    dim3 g(cdiv(N, 64), 2);
    gemm64<<<g, 256, 0, stream>>>(x, W1, Abuf, N, FIN, 128);
    compute_al<4, 32><<<cdiv((long long)N * 4, TPB), TPB, 0, stream>>>(Abuf, as1, ad1, als, ald, N);
    init_bufs<<<cdiv((long long)N * 128, TPB), TPB, 0, stream>>>(menc, ssum, Bbuf, N * 4, (long long)N * 128);
    edge_pass_a<4><<<cdiv((long long)Et * 4, TPB), TPB, 0, stream>>>(esrc, edst, als, ald, ebuf, menc, E0, Et);
    edge_pass_b<4><<<cdiv((long long)Et * 4, TPB), TPB, 0, stream>>>(edst, ebuf, menc, ssum, E0, Et);
    edge_pass_c<4, 32><<<cdiv((long long)Et * 128, TPB), TPB, 0, stream>>>(esrc, edst, Abuf, ebuf, ssum, Bbuf, E0, Et);
    ln_elu<true><<<cdiv(N, 4), 256, 0, stream>>>(Bbuf, b1, g1, be1, Abuf, N);
  }
  // ===== Layer 2: Abuf[N,128] -> h in Bbuf, agg in Abuf, ln -> Bbuf =====
  {
    dim3 g(cdiv(N, 64), 2);
    gemm64<<<g, 256, 0, stream>>>(Abuf, W2, Bbuf, N, 128, 128);
    compute_al<4, 32><<<cdiv((long long)N * 4, TPB), TPB, 0, stream>>>(Bbuf, as2, ad2, als, ald, N);
    init_bufs<<<cdiv((long long)N * 128, TPB), TPB, 0, stream>>>(menc, ssum, Abuf, N * 4, (long long)N * 128);
    edge_pass_a<4><<<cdiv((long long)Et * 4, TPB), TPB, 0, stream>>>(esrc, edst, als, ald, ebuf, menc, E0, Et);
    edge_pass_b<4><<<cdiv((long long)Et * 4, TPB), TPB, 0, stream>>>(edst, ebuf, menc, ssum, E0, Et);
    edge_pass_c<4, 32><<<cdiv((long long)Et * 128, TPB), TPB, 0, stream>>>(esrc, edst, Bbuf, ebuf, ssum, Abuf, E0, Et);
    ln_elu<true><<<cdiv(N, 4), 256, 0, stream>>>(Abuf, b2, g2, be2, Bbuf, N);
  }
  // ===== Layer 3: Bbuf[N,128] -> h[N,64] in Abuf, agg in Bbuf, ln -> Abuf =====
  {
    dim3 g(cdiv(N, 64), 1);
    gemm64<<<g, 256, 0, stream>>>(Bbuf, W3, Abuf, N, 128, 64);
    compute_al<1, 64><<<cdiv((long long)N, TPB), TPB, 0, stream>>>(Abuf, as3, ad3, als, ald, N);
    init_bufs<<<cdiv((long long)N * 64, TPB), TPB, 0, stream>>>(menc, ssum, Bbuf, N, (long long)N * 64);
    edge_pass_a<1><<<cdiv((long long)Et, TPB), TPB, 0, stream>>>(esrc, edst, als, ald, ebuf, menc, E0, Et);
    edge_pass_b<1><<<cdiv((long long)Et, TPB), TPB, 0, stream>>>(edst, ebuf, menc, ssum, E0, Et);
    edge_pass_c<1, 64><<<cdiv((long long)Et * 64, TPB), TPB, 0, stream>>>(esrc, edst, Abuf, ebuf, ssum, Bbuf, E0, Et);
    ln_elu<false><<<cdiv(N, 4), 256, 0, stream>>>(Bbuf, b3, g3, be3, Abuf, N);
  }
  // ===== Pool + classifier =====
  pool_partial<<<256, 256, 0, stream>>>(Abuf, psum, pmax, N);
  pool_final<<<1, 128, 0, stream>>>(psum, pmax, 256, N, cW1, cb1, cW2, cb2, out);
}

// Round 2
// 645.617 us; speedup vs baseline: 1.9881x; 1.9881x over previous
//
#include <hip/hip_runtime.h>
#include <cmath>

static constexpr int TPB = 256;

// ---------- fp32 tiled GEMM: C[n,Nc] = A[n,K] @ B[K,Nc] ----------
__global__ __launch_bounds__(256) void gemm64(const float* __restrict__ A,
                                              const float* __restrict__ B,
                                              float* __restrict__ C,
                                              int n, int K, int Nc) {
  __shared__ float As[16][64];
  __shared__ float Bs[16][64];
  const int tid = threadIdx.x;
  const int tx = tid & 15, ty = tid >> 4;
  const int row0 = blockIdx.x * 64, col0 = blockIdx.y * 64;
  const int lr = tid >> 2, lc = (tid & 3) << 2;   // A tile load coords
  const int bk = tid >> 4, bc = (tid & 15) << 2;  // B tile load coords
  float acc[4][4] = {};
  for (int k0 = 0; k0 < K; k0 += 16) {
    float4 av = make_float4(0.f, 0.f, 0.f, 0.f);
    int gr = row0 + lr;
    if (gr < n) av = *(const float4*)(A + (size_t)gr * K + k0 + lc);
    As[lc + 0][lr] = av.x; As[lc + 1][lr] = av.y;
    As[lc + 2][lr] = av.z; As[lc + 3][lr] = av.w;
    *(float4*)&Bs[bk][bc] = *(const float4*)(B + (size_t)(k0 + bk) * Nc + col0 + bc);
    __syncthreads();
#pragma unroll
    for (int k = 0; k < 16; ++k) {
      float4 a = *(const float4*)&As[k][ty << 2];
      float4 b = *(const float4*)&Bs[k][tx << 2];
      acc[0][0] += a.x * b.x; acc[0][1] += a.x * b.y; acc[0][2] += a.x * b.z; acc[0][3] += a.x * b.w;
      acc[1][0] += a.y * b.x; acc[1][1] += a.y * b.y; acc[1][2] += a.y * b.z; acc[1][3] += a.y * b.w;
      acc[2][0] += a.z * b.x; acc[2][1] += a.z * b.y; acc[2][2] += a.z * b.z; acc[2][3] += a.z * b.w;
      acc[3][0] += a.w * b.x; acc[3][1] += a.w * b.y; acc[3][2] += a.w * b.z; acc[3][3] += a.w * b.w;
    }
    __syncthreads();
  }
#pragma unroll
  for (int i = 0; i < 4; ++i) {
    int r = row0 + (ty << 2) + i;
    if (r < n) {
      float4 v = make_float4(acc[i][0], acc[i][1], acc[i][2], acc[i][3]);
      *(float4*)(C + (size_t)r * Nc + col0 + (tx << 2)) = v;
    }
  }
}

// ---------- per-(node,head) attention logits: al = sum_c h*a ----------
template <int HH, int CC>
__global__ void compute_al(const float* __restrict__ hf, const float* __restrict__ a_s,
                           const float* __restrict__ a_d, float* __restrict__ als,
                           float* __restrict__ ald, int n) {
  int idx = blockIdx.x * TPB + threadIdx.x;
  if (idx >= n * HH) return;
  int node = idx / HH, h = idx - (idx / HH) * HH;
  const float* hp = hf + (size_t)node * (HH * CC) + h * CC;
  float s = 0.f, d = 0.f;
#pragma unroll
  for (int c = 0; c < CC; ++c) {
    float v = hp[c];
    s += v * a_s[h * CC + c];
    d += v * a_d[h * CC + c];
  }
  als[idx] = s;
  ald[idx] = d;
}

// ---------- CSR build ----------
__global__ void zero_int(int* __restrict__ p, int n) {
  int i = blockIdx.x * TPB + threadIdx.x;
  if (i < n) p[i] = 0;
}

__global__ void hist_dst(const int* __restrict__ edst, int* __restrict__ counts,
                         int E0, int Et) {
  int e = blockIdx.x * TPB + threadIdx.x;
  if (e >= Et) return;
  int d = e < E0 ? edst[e] : e - E0;
  atomicAdd(&counts[d], 1);
}

__global__ void block_sums(const int* __restrict__ counts, int* __restrict__ bsum, int N) {
  __shared__ int sh[256];
  int t = threadIdx.x, idx = blockIdx.x * 256 + t;
  sh[t] = idx < N ? counts[idx] : 0;
  __syncthreads();
  for (int off = 128; off >= 1; off >>= 1) {
    if (t < off) sh[t] += sh[t + off];
    __syncthreads();
  }
  if (t == 0) bsum[blockIdx.x] = sh[0];
}

// exclusive scan of bsum in place (nb <= 256)
__global__ void scan_bsum(int* __restrict__ bsum, int nb) {
  __shared__ int sh[256];
  int t = threadIdx.x;
  int v = t < nb ? bsum[t] : 0;
  sh[t] = v;
  __syncthreads();
  for (int off = 1; off < 256; off <<= 1) {
    int u = (t >= off) ? sh[t - off] : 0;
    __syncthreads();
    sh[t] += u;
    __syncthreads();
  }
  if (t < nb) bsum[t] = sh[t] - v;  // exclusive
}

__global__ void scan_final(const int* __restrict__ counts, const int* __restrict__ bsum_ex,
                           int* __restrict__ offsets, int* __restrict__ cursor,
                           int N, int Et) {
  __shared__ int sh[256];
  int t = threadIdx.x, b = blockIdx.x;
  int idx = b * 256 + t;
  int v = (idx < N) ? counts[idx] : 0;
  sh[t] = v;
  __syncthreads();
  for (int off = 1; off < 256; off <<= 1) {
    int u = (t >= off) ? sh[t - off] : 0;
    __syncthreads();
    sh[t] += u;
    __syncthreads();
  }
  if (idx < N) {
    int o = bsum_ex[b] + sh[t] - v;
    offsets[idx] = o;
    cursor[idx] = o;
  }
  if (idx == 0) offsets[N] = Et;
}

__global__ void scatter_csr(const int* __restrict__ esrc, const int* __restrict__ edst,
                            int* __restrict__ cursor, int* __restrict__ csr_src,
                            int E0, int Et) {
  int e = blockIdx.x * TPB + threadIdx.x;
  if (e >= Et) return;
  int s = e < E0 ? esrc[e] : e - E0;
  int d = e < E0 ? edst[e] : e - E0;
  int pos = atomicAdd(&cursor[d], 1);
  csr_src[pos] = s;
}

// ---------- fused attention + bias + LayerNorm + ELU, one wave per dst node ----------
template <int HH, int CC>
__global__ __launch_bounds__(256) void fused_attn(
    const float* __restrict__ hf, const float* __restrict__ als,
    const float* __restrict__ ald, const int* __restrict__ offsets,
    const int* __restrict__ csr_src, const float* __restrict__ bias,
    const float* __restrict__ g, const float* __restrict__ be,
    float* __restrict__ xout, int n) {
  constexpr int W = HH * CC;   // 128 or 64
  constexpr int NV = W / 64;   // 2 or 1
  int wid = (int)((blockIdx.x * (size_t)blockDim.x + threadIdx.x) >> 6);
  int lane = threadIdx.x & 63;
  if (wid >= n) return;
  const int d = wid;
  const int begin = offsets[d], end = offsets[d + 1];

  float aldv[HH];
  if constexpr (HH == 4) {
    float4 t = *(const float4*)(ald + (size_t)d * 4);
    aldv[0] = t.x; aldv[1] = t.y; aldv[2] = t.z; aldv[3] = t.w;
  } else {
    aldv[0] = ald[d];
  }

  // phase 1: segment max, lane-parallel over edges
  float me[HH];
#pragma unroll
  for (int h = 0; h < HH; ++h) me[h] = -1e30f;
  for (int k = begin + lane; k < end; k += 64) {
    int s = csr_src[k];
    if constexpr (HH == 4) {
      float4 t = *(const float4*)(als + (size_t)s * 4);
      float e0 = t.x + aldv[0]; e0 = e0 > 0.f ? e0 : 0.2f * e0; me[0] = fmaxf(me[0], e0);
      float e1 = t.y + aldv[1]; e1 = e1 > 0.f ? e1 : 0.2f * e1; me[1] = fmaxf(me[1], e1);
      float e2 = t.z + aldv[2]; e2 = e2 > 0.f ? e2 : 0.2f * e2; me[2] = fmaxf(me[2], e2);
      float e3 = t.w + aldv[3]; e3 = e3 > 0.f ? e3 : 0.2f * e3; me[3] = fmaxf(me[3], e3);
    } else {
      float e0 = als[s] + aldv[0]; e0 = e0 > 0.f ? e0 : 0.2f * e0; me[0] = fmaxf(me[0], e0);
    }
  }
#pragma unroll
  for (int off = 32; off >= 1; off >>= 1)
#pragma unroll
    for (int h = 0; h < HH; ++h) me[h] = fmaxf(me[h], __shfl_xor(me[h], off));

  // phase 2: exp-sum, lane-parallel
  float se[HH];
#pragma unroll
  for (int h = 0; h < HH; ++h) se[h] = 0.f;
  for (int k = begin + lane; k < end; k += 64) {
    int s = csr_src[k];
    if constexpr (HH == 4) {
      float4 t = *(const float4*)(als + (size_t)s * 4);
      float e0 = t.x + aldv[0]; e0 = e0 > 0.f ? e0 : 0.2f * e0; se[0] += __expf(e0 - me[0]);
      float e1 = t.y + aldv[1]; e1 = e1 > 0.f ? e1 : 0.2f * e1; se[1] += __expf(e1 - me[1]);
      float e2 = t.z + aldv[2]; e2 = e2 > 0.f ? e2 : 0.2f * e2; se[2] += __expf(e2 - me[2]);
      float e3 = t.w + aldv[3]; e3 = e3 > 0.f ? e3 : 0.2f * e3; se[3] += __expf(e3 - me[3]);
    } else {
      float e0 = als[s] + aldv[0]; e0 = e0 > 0.f ? e0 : 0.2f * e0; se[0] += __expf(e0 - me[0]);
    }
  }
#pragma unroll
  for (int off = 32; off >= 1; off >>= 1)
#pragma unroll
    for (int h = 0; h < HH; ++h) se[h] += __shfl_xor(se[h], off);
  float inv[HH];
#pragma unroll
  for (int h = 0; h < HH; ++h) inv[h] = 1.f / (se[h] + 1e-16f);

  // per-lane channel/head mapping (compile-time-unrolled selects; no runtime array idx)
  const int h0 = lane / CC;  // 0..(64/CC - 1)
  float me0, in0, ad0, me1 = 0.f, in1 = 0.f, ad1 = 0.f;
  if constexpr (HH == 4) {
    me0 = h0 ? me[1] : me[0]; in0 = h0 ? inv[1] : inv[0]; ad0 = h0 ? aldv[1] : aldv[0];
    me1 = h0 ? me[3] : me[2]; in1 = h0 ? inv[3] : inv[2]; ad1 = h0 ? aldv[3] : aldv[2];
  } else {
    me0 = me[0]; in0 = inv[0]; ad0 = aldv[0];
  }

  // phase 3: serial over edges, lanes cover channels (coalesced gather, no atomics)
  float acc0 = 0.f, acc1 = 0.f;
  for (int k = begin; k < end; ++k) {
    int s = csr_src[k];
    const float* hp = hf + (size_t)s * W;
    if constexpr (HH == 4) {
      float4 t = *(const float4*)(als + (size_t)s * 4);
      float as0 = h0 ? t.y : t.x;
      float as1 = h0 ? t.w : t.z;
      float e0 = as0 + ad0; e0 = e0 > 0.f ? e0 : 0.2f * e0;
      float e1 = as1 + ad1; e1 = e1 > 0.f ? e1 : 0.2f * e1;
      float a0 = __expf(e0 - me0) * in0;
      float a1 = __expf(e1 - me1) * in1;
      acc0 += a0 * hp[lane];
      acc1 += a1 * hp[64 + lane];
    } else {
      float e0 = als[s] + ad0; e0 = e0 > 0.f ? e0 : 0.2f * e0;
      float a0 = __expf(e0 - me0) * in0;
      acc0 += a0 * hp[lane];
    }
  }

  // bias + LayerNorm + ELU, in-register
  float v0 = acc0 + bias[lane];
  float v1 = 0.f;
  if constexpr (NV == 2) v1 = acc1 + bias[64 + lane];
  float sm = v0 + v1;
  float s2 = v0 * v0 + v1 * v1;
#pragma unroll
  for (int off = 32; off >= 1; off >>= 1) {
    sm += __shfl_xor(sm, off);
    s2 += __shfl_xor(s2, off);
  }
  const float invW = 1.0f / W;
  float mu = sm * invW;
  float var = s2 * invW - mu * mu;
  float r = rsqrtf(var + 1e-5f);
  float y0 = g[lane] * (v0 - mu) * r + be[lane];
  y0 = y0 > 0.f ? y0 : __expf(y0) - 1.f;
  xout[(size_t)wid * W + lane] = y0;
  if constexpr (NV == 2) {
    float y1 = g[64 + lane] * (v1 - mu) * r + be[64 + lane];
    y1 = y1 > 0.f ? y1 : __expf(y1) - 1.f;
    xout[(size_t)wid * W + 64 + lane] = y1;
  }
}

// ---------- pooling: per-block partial sum/max over nodes, 64 channels ----------
__global__ void pool_partial(const float* __restrict__ h, float* __restrict__ psum,
                             float* __restrict__ pmax, int n) {
  int tid = threadIdx.x;
  float lsum = 0.f, lmax = -1e30f;
  for (size_t idx = (size_t)blockIdx.x * 256 + tid; idx < (size_t)n * 64;
       idx += (size_t)gridDim.x * 256) {
    float v = h[idx];
    lsum += v;
    lmax = fmaxf(lmax, v);
  }
  __shared__ float ss[256], sm[256];
  ss[tid] = lsum; sm[tid] = lmax;
  __syncthreads();
  if (tid < 64) {
    float a = ss[tid] + ss[tid + 64] + ss[tid + 128] + ss[tid + 192];
    float m = fmaxf(fmaxf(sm[tid], sm[tid + 64]), fmaxf(sm[tid + 128], sm[tid + 192]));
    psum[blockIdx.x * 64 + tid] = a;
    pmax[blockIdx.x * 64 + tid] = m;
  }
}

// ---------- final reduce + classifier ----------
__global__ void pool_final(const float* __restrict__ psum, const float* __restrict__ pmax,
                           int nblocks, int n, const float* __restrict__ cW1,
                           const float* __restrict__ cb1, const float* __restrict__ cW2,
                           const float* __restrict__ cb2, float* __restrict__ out) {
  __shared__ float z[128];
  __shared__ float hid[128];
  int tid = threadIdx.x;
  if (tid < 64) {
    float s = 0.f, m = -1e30f;
    for (int b = 0; b < nblocks; ++b) {
      s += psum[b * 64 + tid];
      m = fmaxf(m, pmax[b * 64 + tid]);
    }
    z[tid] = s / (float)n;
    z[64 + tid] = m;
  }
  __syncthreads();
  float a = cb1[tid];
  for (int k = 0; k < 128; ++k) a += z[k] * cW1[k * 128 + tid];
  hid[tid] = fmaxf(a, 0.f);
  __syncthreads();
  if (tid < 2) {
    float o = cb2[tid];
    for (int j = 0; j < 128; ++j) o += hid[j] * cW2[j * 2 + tid];
    out[tid] = o;
  }
}

static inline int cdiv(long long a, long long b) { return (int)((a + b - 1) / b); }

extern "C" void kernel_launch(void* const* d_in, const int* in_sizes, int n_in,
                              void* d_out, int out_size, void* d_ws, size_t ws_size,
                              hipStream_t stream) {
  const float* x   = (const float*)d_in[0];
  const int*   ei  = (const int*)d_in[1];
  const float* W1  = (const float*)d_in[3];
  const float* as1 = (const float*)d_in[4];
  const float* ad1 = (const float*)d_in[5];
  const float* b1  = (const float*)d_in[6];
  const float* g1  = (const float*)d_in[7];
  const float* be1 = (const float*)d_in[8];
  const float* W2  = (const float*)d_in[9];
  const float* as2 = (const float*)d_in[10];
  const float* ad2 = (const float*)d_in[11];
  const float* b2  = (const float*)d_in[12];
  const float* g2  = (const float*)d_in[13];
  const float* be2 = (const float*)d_in[14];
  const float* W3  = (const float*)d_in[15];
  const float* as3 = (const float*)d_in[16];
  const float* ad3 = (const float*)d_in[17];
  const float* b3  = (const float*)d_in[18];
  const float* g3  = (const float*)d_in[19];
  const float* be3 = (const float*)d_in[20];
  const float* cW1 = (const float*)d_in[21];
  const float* cb1 = (const float*)d_in[22];
  const float* cW2 = (const float*)d_in[23];
  const float* cb2 = (const float*)d_in[24];
  float* out = (float*)d_out;

  const int N   = in_sizes[2];
  const int E0  = in_sizes[1] / 2;
  const int Et  = E0 + N;
  const int FIN = in_sizes[0] / N;

  float* ws = (float*)d_ws;
  size_t o = 0;
  float* Abuf = ws + o; o += (size_t)N * 128;
  float* Bbuf = ws + o; o += (size_t)N * 128;
  float* als  = ws + o; o += (size_t)N * 4;
  float* ald  = ws + o; o += (size_t)N * 4;
  float* psum = ws + o; o += 256 * 64;
  float* pmax = ws + o; o += 256 * 64;
  int* counts  = (int*)(ws + o); o += N + 1;
  int* offsets = (int*)(ws + o); o += N + 1;
  int* cursor  = (int*)(ws + o); o += N;
  int* bsum    = (int*)(ws + o); o += 256;
  int* csr_src = (int*)(ws + o); o += Et;

  const int* esrc = ei;
  const int* edst = ei + E0;
  const int NB = cdiv(N, 256);

  // ===== CSR build (once, reused by all 3 layers) =====
  zero_int<<<cdiv(N + 1, TPB), TPB, 0, stream>>>(counts, N + 1);
  hist_dst<<<cdiv(Et, TPB), TPB, 0, stream>>>(edst, counts, E0, Et);
  block_sums<<<NB, 256, 0, stream>>>(counts, bsum, N);
  scan_bsum<<<1, 256, 0, stream>>>(bsum, NB);
  scan_final<<<NB, 256, 0, stream>>>(counts, bsum, offsets, cursor, N, Et);
  scatter_csr<<<cdiv(Et, TPB), TPB, 0, stream>>>(esrc, edst, cursor, csr_src, E0, Et);

  // ===== Layer 1: x[N,512] -> h in Abuf -> x1 in Bbuf =====
  {
    dim3 g(cdiv(N, 64), 2);
    gemm64<<<g, 256, 0, stream>>>(x, W1, Abuf, N, FIN, 128);
    compute_al<4, 32><<<cdiv((long long)N * 4, TPB), TPB, 0, stream>>>(Abuf, as1, ad1, als, ald, N);
    fused_attn<4, 32><<<cdiv(N, 4), 256, 0, stream>>>(Abuf, als, ald, offsets, csr_src, b1, g1, be1, Bbuf, N);
  }
  // ===== Layer 2: Bbuf[N,128] -> h in Abuf -> x2 in Bbuf =====
  {
    dim3 g(cdiv(N, 64), 2);
    gemm64<<<g, 256, 0, stream>>>(Bbuf, W2, Abuf, N, 128, 128);
    compute_al<4, 32><<<cdiv((long long)N * 4, TPB), TPB, 0, stream>>>(Abuf, as2, ad2, als, ald, N);
    fused_attn<4, 32><<<cdiv(N, 4), 256, 0, stream>>>(Abuf, als, ald, offsets, csr_src, b2, g2, be2, Bbuf, N);
  }
  // ===== Layer 3: Bbuf[N,128] -> h[N,64] in Abuf -> x3 in Bbuf =====
  {
    dim3 g(cdiv(N, 64), 1);
    gemm64<<<g, 256, 0, stream>>>(Bbuf, W3, Abuf, N, 128, 64);
    compute_al<1, 64><<<cdiv((long long)N, TPB), TPB, 0, stream>>>(Abuf, as3, ad3, als, ald, N);
    fused_attn<1, 64><<<cdiv(N, 4), 256, 0, stream>>>(Abuf, als, ald, offsets, csr_src, b3, g3, be3, Bbuf, N);
  }
  // ===== Pool + classifier =====
  pool_partial<<<256, 256, 0, stream>>>(Bbuf, psum, pmax, N);
  pool_final<<<1, 128, 0, stream>>>(psum, pmax, 256, N, cW1, cb1, cW2, cb2, out);
}

// Round 3
// 446.702 us; speedup vs baseline: 2.8734x; 1.4453x over previous
//
#include <hip/hip_runtime.h>
#include <cmath>

static constexpr int TPB = 256;

using short8 = __attribute__((ext_vector_type(8))) short;
using f32x4  = __attribute__((ext_vector_type(4))) float;
typedef unsigned short ushort;

__device__ __forceinline__ ushort f2b(float f) {
  unsigned x = __builtin_bit_cast(unsigned, f);
  unsigned r = (x + 0x7fffu + ((x >> 16) & 1u)) >> 16;   // RNE
  return (ushort)r;
}
__device__ __forceinline__ float b2f(ushort u) {
  unsigned v = ((unsigned)u) << 16;
  return __builtin_bit_cast(float, v);
}

// ---------- W [K][Nc] fp32 -> Wt [Nc][K] bf16 ----------
__global__ void prep_wt(const float* __restrict__ W, ushort* __restrict__ Wt, int K, int Nc) {
  int idx = blockIdx.x * TPB + threadIdx.x;
  if (idx >= K * Nc) return;
  int nc = idx / K, k = idx - nc * K;
  Wt[idx] = f2b(W[(size_t)k * Nc + nc]);
}

// ---------- MFMA GEMM: C[n,Nc](bf16) = A[n,K] @ W[K,Nc], Wt pre-transposed ----------
// BM=64, BN=64, BK=64, 256 threads = 4 waves (2x2 of 32x32 wave tiles)
template <int ABF16>
__global__ __launch_bounds__(256) void gemm_mfma(const void* __restrict__ Ap,
                                                 const ushort* __restrict__ Wt,
                                                 ushort* __restrict__ Cb,
                                                 int n, int K, int Nc) {
  __shared__ short As[64 * 72];
  __shared__ short Bs[64 * 72];
  const int tid = threadIdx.x;
  const int row0 = blockIdx.x * 64, col0 = blockIdx.y * 64;
  const int srow = tid >> 2, sks = (tid & 3) << 4;  // staging: row, k-segment(16)
  const int wave = tid >> 6, lane = tid & 63;
  const int wr = wave >> 1, wc = wave & 1;
  const int lm = lane & 15, lg = lane >> 4;

  f32x4 acc[2][2] = {};

  for (int k0 = 0; k0 < K; k0 += 64) {
    // ---- stage A tile (convert fp32->bf16 if needed) ----
    {
      int gr = row0 + srow;
      short8 v0 = {0, 0, 0, 0, 0, 0, 0, 0}, v1 = v0;
      if constexpr (ABF16 == 0) {
        const float* A = (const float*)Ap;
        if (gr < n) {
          const float* p = A + (size_t)gr * K + k0 + sks;
          float4 f0 = *(const float4*)(p + 0);
          float4 f1 = *(const float4*)(p + 4);
          float4 f2 = *(const float4*)(p + 8);
          float4 f3 = *(const float4*)(p + 12);
          v0[0] = (short)f2b(f0.x); v0[1] = (short)f2b(f0.y); v0[2] = (short)f2b(f0.z); v0[3] = (short)f2b(f0.w);
          v0[4] = (short)f2b(f1.x); v0[5] = (short)f2b(f1.y); v0[6] = (short)f2b(f1.z); v0[7] = (short)f2b(f1.w);
          v1[0] = (short)f2b(f2.x); v1[1] = (short)f2b(f2.y); v1[2] = (short)f2b(f2.z); v1[3] = (short)f2b(f2.w);
          v1[4] = (short)f2b(f3.x); v1[5] = (short)f2b(f3.y); v1[6] = (short)f2b(f3.z); v1[7] = (short)f2b(f3.w);
        }
      } else {
        const ushort* A = (const ushort*)Ap;
        if (gr < n) {
          const ushort* p = A + (size_t)gr * K + k0 + sks;
          v0 = *(const short8*)(p + 0);
          v1 = *(const short8*)(p + 8);
        }
      }
      *(short8*)&As[srow * 72 + sks + 0] = v0;
      *(short8*)&As[srow * 72 + sks + 8] = v1;
      // ---- stage B tile from Wt [Nc][K] ----
      const ushort* wp = Wt + (size_t)(col0 + srow) * K + k0 + sks;
      *(short8*)&Bs[srow * 72 + sks + 0] = *(const short8*)(wp + 0);
      *(short8*)&Bs[srow * 72 + sks + 8] = *(const short8*)(wp + 8);
    }
    __syncthreads();
#pragma unroll
    for (int kk = 0; kk < 64; kk += 32) {
      short8 a0 = *(const short8*)&As[(wr * 32 + lm) * 72 + kk + lg * 8];
      short8 a1 = *(const short8*)&As[(wr * 32 + 16 + lm) * 72 + kk + lg * 8];
      short8 b0 = *(const short8*)&Bs[(wc * 32 + lm) * 72 + kk + lg * 8];
      short8 b1 = *(const short8*)&Bs[(wc * 32 + 16 + lm) * 72 + kk + lg * 8];
      acc[0][0] = __builtin_amdgcn_mfma_f32_16x16x32_bf16(a0, b0, acc[0][0], 0, 0, 0);
      acc[0][1] = __builtin_amdgcn_mfma_f32_16x16x32_bf16(a0, b1, acc[0][1], 0, 0, 0);
      acc[1][0] = __builtin_amdgcn_mfma_f32_16x16x32_bf16(a1, b0, acc[1][0], 0, 0, 0);
      acc[1][1] = __builtin_amdgcn_mfma_f32_16x16x32_bf16(a1, b1, acc[1][1], 0, 0, 0);
    }
    __syncthreads();
  }
  // epilogue: D row = (lg*4 + r), col = lm within each 16x16 frag
#pragma unroll
  for (int m = 0; m < 2; ++m)
#pragma unroll
    for (int nn = 0; nn < 2; ++nn)
#pragma unroll
      for (int r = 0; r < 4; ++r) {
        int row = row0 + wr * 32 + m * 16 + lg * 4 + r;
        if (row < n) {
          int col = col0 + wc * 32 + nn * 16 + lm;
          Cb[(size_t)row * Nc + col] = f2b(acc[m][nn][r]);
        }
      }
}

// ---------- per-(node,head) attention logits from bf16 h ----------
template <int HH, int CC>
__global__ void compute_al(const ushort* __restrict__ hb, const float* __restrict__ a_s,
                           const float* __restrict__ a_d, float* __restrict__ als,
                           float* __restrict__ ald, int n) {
  int idx = blockIdx.x * TPB + threadIdx.x;
  if (idx >= n * HH) return;
  int node = idx / HH, h = idx - (idx / HH) * HH;
  const ushort* hp = hb + (size_t)node * (HH * CC) + h * CC;
  float s = 0.f, d = 0.f;
#pragma unroll
  for (int c8 = 0; c8 < CC; c8 += 8) {
    short8 v = *(const short8*)(hp + c8);
#pragma unroll
    for (int j = 0; j < 8; ++j) {
      float f = b2f((ushort)v[j]);
      s += f * a_s[h * CC + c8 + j];
      d += f * a_d[h * CC + c8 + j];
    }
  }
  als[idx] = s;
  ald[idx] = d;
}

// ---------- CSR build ----------
__global__ void zero_int(int* __restrict__ p, int n) {
  int i = blockIdx.x * TPB + threadIdx.x;
  if (i < n) p[i] = 0;
}

__global__ void hist_dst(const int* __restrict__ edst, int* __restrict__ counts,
                         int E0, int Et) {
  int e = blockIdx.x * TPB + threadIdx.x;
  if (e >= Et) return;
  int d = e < E0 ? edst[e] : e - E0;
  atomicAdd(&counts[d], 1);
}

__global__ void block_sums(const int* __restrict__ counts, int* __restrict__ bsum, int N) {
  __shared__ int sh[256];
  int t = threadIdx.x, idx = blockIdx.x * 256 + t;
  sh[t] = idx < N ? counts[idx] : 0;
  __syncthreads();
  for (int off = 128; off >= 1; off >>= 1) {
    if (t < off) sh[t] += sh[t + off];
    __syncthreads();
  }
  if (t == 0) bsum[blockIdx.x] = sh[0];
}

__global__ void scan_bsum(int* __restrict__ bsum, int nb) {
  __shared__ int sh[256];
  int t = threadIdx.x;
  int v = t < nb ? bsum[t] : 0;
  sh[t] = v;
  __syncthreads();
  for (int off = 1; off < 256; off <<= 1) {
    int u = (t >= off) ? sh[t - off] : 0;
    __syncthreads();
    sh[t] += u;
    __syncthreads();
  }
  if (t < nb) bsum[t] = sh[t] - v;  // exclusive
}

__global__ void scan_final(const int* __restrict__ counts, const int* __restrict__ bsum_ex,
                           int* __restrict__ offsets, int* __restrict__ cursor,
                           int N, int Et) {
  __shared__ int sh[256];
  int t = threadIdx.x, b = blockIdx.x;
  int idx = b * 256 + t;
  int v = (idx < N) ? counts[idx] : 0;
  sh[t] = v;
  __syncthreads();
  for (int off = 1; off < 256; off <<= 1) {
    int u = (t >= off) ? sh[t - off] : 0;
    __syncthreads();
    sh[t] += u;
    __syncthreads();
  }
  if (idx < N) {
    int o = bsum_ex[b] + sh[t] - v;
    offsets[idx] = o;
    cursor[idx] = o;
  }
  if (idx == 0) offsets[N] = Et;
}

__global__ void scatter_csr(const int* __restrict__ esrc, const int* __restrict__ edst,
                            int* __restrict__ cursor, int* __restrict__ csr_src,
                            int E0, int Et) {
  int e = blockIdx.x * TPB + threadIdx.x;
  if (e >= Et) return;
  int s = e < E0 ? esrc[e] : e - E0;
  int d = e < E0 ? edst[e] : e - E0;
  int pos = atomicAdd(&cursor[d], 1);
  csr_src[pos] = s;
}

// ---------- fused attention + bias + LayerNorm + ELU, one wave per dst node ----------
template <int HH, int CC>
__global__ __launch_bounds__(256) void fused_attn(
    const ushort* __restrict__ hb, const float* __restrict__ als,
    const float* __restrict__ ald, const int* __restrict__ offsets,
    const int* __restrict__ csr_src, const float* __restrict__ bias,
    const float* __restrict__ g, const float* __restrict__ be,
    ushort* __restrict__ xout, int n) {
  constexpr int W = HH * CC;   // 128 or 64
  constexpr int NV = W / 64;   // 2 or 1
  int wid = (int)((blockIdx.x * (size_t)blockDim.x + threadIdx.x) >> 6);
  int lane = threadIdx.x & 63;
  if (wid >= n) return;
  const int d = wid;
  const int begin = offsets[d], end = offsets[d + 1];
  const int deg = end - begin;

  float aldv[HH];
  if constexpr (HH == 4) {
    float4 t = *(const float4*)(ald + (size_t)d * 4);
    aldv[0] = t.x; aldv[1] = t.y; aldv[2] = t.z; aldv[3] = t.w;
  } else {
    aldv[0] = ald[d];
  }

  float acc0 = 0.f, acc1 = 0.f;

  if (deg <= 64) {
    // ---- fast path: whole neighborhood in registers, one lane per edge ----
    bool act = lane < deg;
    int s_e = act ? csr_src[begin + lane] : 0;
    float e0 = -1e30f, e1 = -1e30f, e2 = -1e30f, e3 = -1e30f;
    if constexpr (HH == 4) {
      if (act) {
        float4 t = *(const float4*)(als + (size_t)s_e * 4);
        e0 = t.x + aldv[0]; e0 = e0 > 0.f ? e0 : 0.2f * e0;
        e1 = t.y + aldv[1]; e1 = e1 > 0.f ? e1 : 0.2f * e1;
        e2 = t.z + aldv[2]; e2 = e2 > 0.f ? e2 : 0.2f * e2;
        e3 = t.w + aldv[3]; e3 = e3 > 0.f ? e3 : 0.2f * e3;
      }
    } else {
      if (act) {
        e0 = als[s_e] + aldv[0]; e0 = e0 > 0.f ? e0 : 0.2f * e0;
      }
    }
    float m0 = e0, m1 = e1, m2 = e2, m3 = e3;
#pragma unroll
    for (int off = 32; off >= 1; off >>= 1) {
      m0 = fmaxf(m0, __shfl_xor(m0, off));
      if constexpr (HH == 4) {
        m1 = fmaxf(m1, __shfl_xor(m1, off));
        m2 = fmaxf(m2, __shfl_xor(m2, off));
        m3 = fmaxf(m3, __shfl_xor(m3, off));
      }
    }
    float p0 = act ? __expf(e0 - m0) : 0.f;
    float p1 = 0.f, p2 = 0.f, p3 = 0.f;
    if constexpr (HH == 4) {
      p1 = act ? __expf(e1 - m1) : 0.f;
      p2 = act ? __expf(e2 - m2) : 0.f;
      p3 = act ? __expf(e3 - m3) : 0.f;
    }
    float s0 = p0, s1 = p1, s2 = p2, s3 = p3;
#pragma unroll
    for (int off = 32; off >= 1; off >>= 1) {
      s0 += __shfl_xor(s0, off);
      if constexpr (HH == 4) {
        s1 += __shfl_xor(s1, off);
        s2 += __shfl_xor(s2, off);
        s3 += __shfl_xor(s3, off);
      }
    }
    float a0 = p0 / (s0 + 1e-16f);
    float a1 = 0.f, a2 = 0.f, a3 = 0.f;
    if constexpr (HH == 4) {
      a1 = p1 / (s1 + 1e-16f);
      a2 = p2 / (s2 + 1e-16f);
      a3 = p3 / (s3 + 1e-16f);
    }
    const bool lo = lane < 32;  // head selector for my channel
    for (int j = 0; j < deg; ++j) {
      int s = __shfl(s_e, j);
      const ushort* hp = hb + (size_t)s * W;
      if constexpr (HH == 4) {
        float wa = __shfl(a0, j), wb = __shfl(a1, j), wc = __shfl(a2, j), wd = __shfl(a3, j);
        float w0 = lo ? wa : wb;
        float w1 = lo ? wc : wd;
        acc0 += w0 * b2f(hp[lane]);
        acc1 += w1 * b2f(hp[64 + lane]);
      } else {
        float wa = __shfl(a0, j);
        acc0 += wa * b2f(hp[lane]);
      }
    }
  } else {
    // ---- slow path (deg > 64): 3-phase with reload ----
    float me[HH];
#pragma unroll
    for (int h = 0; h < HH; ++h) me[h] = -1e30f;
    for (int k = begin + lane; k < end; k += 64) {
      int s = csr_src[k];
      if constexpr (HH == 4) {
        float4 t = *(const float4*)(als + (size_t)s * 4);
        float e0 = t.x + aldv[0]; e0 = e0 > 0.f ? e0 : 0.2f * e0; me[0] = fmaxf(me[0], e0);
        float e1 = t.y + aldv[1]; e1 = e1 > 0.f ? e1 : 0.2f * e1; me[1] = fmaxf(me[1], e1);
        float e2 = t.z + aldv[2]; e2 = e2 > 0.f ? e2 : 0.2f * e2; me[2] = fmaxf(me[2], e2);
        float e3 = t.w + aldv[3]; e3 = e3 > 0.f ? e3 : 0.2f * e3; me[3] = fmaxf(me[3], e3);
      } else {
        float e0 = als[s] + aldv[0]; e0 = e0 > 0.f ? e0 : 0.2f * e0; me[0] = fmaxf(me[0], e0);
      }
    }
#pragma unroll
    for (int off = 32; off >= 1; off >>= 1)
#pragma unroll
      for (int h = 0; h < HH; ++h) me[h] = fmaxf(me[h], __shfl_xor(me[h], off));
    float se[HH];
#pragma unroll
    for (int h = 0; h < HH; ++h) se[h] = 0.f;
    for (int k = begin + lane; k < end; k += 64) {
      int s = csr_src[k];
      if constexpr (HH == 4) {
        float4 t = *(const float4*)(als + (size_t)s * 4);
        float e0 = t.x + aldv[0]; e0 = e0 > 0.f ? e0 : 0.2f * e0; se[0] += __expf(e0 - me[0]);
        float e1 = t.y + aldv[1]; e1 = e1 > 0.f ? e1 : 0.2f * e1; se[1] += __expf(e1 - me[1]);
        float e2 = t.z + aldv[2]; e2 = e2 > 0.f ? e2 : 0.2f * e2; se[2] += __expf(e2 - me[2]);
        float e3 = t.w + aldv[3]; e3 = e3 > 0.f ? e3 : 0.2f * e3; se[3] += __expf(e3 - me[3]);
      } else {
        float e0 = als[s] + aldv[0]; e0 = e0 > 0.f ? e0 : 0.2f * e0; se[0] += __expf(e0 - me[0]);
      }
    }
#pragma unroll
    for (int off = 32; off >= 1; off >>= 1)
#pragma unroll
      for (int h = 0; h < HH; ++h) se[h] += __shfl_xor(se[h], off);
    float inv[HH];
#pragma unroll
    for (int h = 0; h < HH; ++h) inv[h] = 1.f / (se[h] + 1e-16f);

    const int h0 = lane / CC;
    float me0, in0, ad0, me1 = 0.f, in1 = 0.f, ad1 = 0.f;
    if constexpr (HH == 4) {
      me0 = h0 ? me[1] : me[0]; in0 = h0 ? inv[1] : inv[0]; ad0 = h0 ? aldv[1] : aldv[0];
      me1 = h0 ? me[3] : me[2]; in1 = h0 ? inv[3] : inv[2]; ad1 = h0 ? aldv[3] : aldv[2];
    } else {
      me0 = me[0]; in0 = inv[0]; ad0 = aldv[0];
    }
    for (int k = begin; k < end; ++k) {
      int s = csr_src[k];
      const ushort* hp = hb + (size_t)s * W;
      if constexpr (HH == 4) {
        float4 t = *(const float4*)(als + (size_t)s * 4);
        float as0 = h0 ? t.y : t.x;
        float as1 = h0 ? t.w : t.z;
        float e0 = as0 + ad0; e0 = e0 > 0.f ? e0 : 0.2f * e0;
        float e1 = as1 + ad1; e1 = e1 > 0.f ? e1 : 0.2f * e1;
        float aa0 = __expf(e0 - me0) * in0;
        float aa1 = __expf(e1 - me1) * in1;
        acc0 += aa0 * b2f(hp[lane]);
        acc1 += aa1 * b2f(hp[64 + lane]);
      } else {
        float e0 = als[s] + ad0; e0 = e0 > 0.f ? e0 : 0.2f * e0;
        float aa0 = __expf(e0 - me0) * in0;
        acc0 += aa0 * b2f(hp[lane]);
      }
    }
  }

  // bias + LayerNorm + ELU, in-register
  float v0 = acc0 + bias[lane];
  float v1 = 0.f;
  if constexpr (NV == 2) v1 = acc1 + bias[64 + lane];
  float sm = v0 + v1;
  float s2 = v0 * v0 + v1 * v1;
#pragma unroll
  for (int off = 32; off >= 1; off >>= 1) {
    sm += __shfl_xor(sm, off);
    s2 += __shfl_xor(s2, off);
  }
  const float invW = 1.0f / W;
  float mu = sm * invW;
  float var = s2 * invW - mu * mu;
  float r = rsqrtf(var + 1e-5f);
  float y0 = g[lane] * (v0 - mu) * r + be[lane];
  y0 = y0 > 0.f ? y0 : __expf(y0) - 1.f;
  xout[(size_t)wid * W + lane] = f2b(y0);
  if constexpr (NV == 2) {
    float y1 = g[64 + lane] * (v1 - mu) * r + be[64 + lane];
    y1 = y1 > 0.f ? y1 : __expf(y1) - 1.f;
    xout[(size_t)wid * W + 64 + lane] = f2b(y1);
  }
}

// ---------- pooling over bf16 h3 ----------
__global__ void pool_partial(const ushort* __restrict__ h, float* __restrict__ psum,
                             float* __restrict__ pmax, int n) {
  int tid = threadIdx.x;
  float lsum = 0.f, lmax = -1e30f;
  for (size_t idx = (size_t)blockIdx.x * 256 + tid; idx < (size_t)n * 64;
       idx += (size_t)gridDim.x * 256) {
    float v = b2f(h[idx]);
    lsum += v;
    lmax = fmaxf(lmax, v);
  }
  __shared__ float ss[256], sm[256];
  ss[tid] = lsum; sm[tid] = lmax;
  __syncthreads();
  if (tid < 64) {
    float a = ss[tid] + ss[tid + 64] + ss[tid + 128] + ss[tid + 192];
    float m = fmaxf(fmaxf(sm[tid], sm[tid + 64]), fmaxf(sm[tid + 128], sm[tid + 192]));
    psum[blockIdx.x * 64 + tid] = a;
    pmax[blockIdx.x * 64 + tid] = m;
  }
}

// ---------- final reduce + classifier ----------
__global__ void pool_final(const float* __restrict__ psum, const float* __restrict__ pmax,
                           int nblocks, int n, const float* __restrict__ cW1,
                           const float* __restrict__ cb1, const float* __restrict__ cW2,
                           const float* __restrict__ cb2, float* __restrict__ out) {
  __shared__ float z[128];
  __shared__ float hid[128];
  int tid = threadIdx.x;
  if (tid < 64) {
    float s = 0.f, m = -1e30f;
    for (int b = 0; b < nblocks; ++b) {
      s += psum[b * 64 + tid];
      m = fmaxf(m, pmax[b * 64 + tid]);
    }
    z[tid] = s / (float)n;
    z[64 + tid] = m;
  }
  __syncthreads();
  float a = cb1[tid];
  for (int k = 0; k < 128; ++k) a += z[k] * cW1[k * 128 + tid];
  hid[tid] = fmaxf(a, 0.f);
  __syncthreads();
  if (tid < 2) {
    float o = cb2[tid];
    for (int j = 0; j < 128; ++j) o += hid[j] * cW2[j * 2 + tid];
    out[tid] = o;
  }
}

static inline int cdiv(long long a, long long b) { return (int)((a + b - 1) / b); }

extern "C" void kernel_launch(void* const* d_in, const int* in_sizes, int n_in,
                              void* d_out, int out_size, void* d_ws, size_t ws_size,
                              hipStream_t stream) {
  const float* x   = (const float*)d_in[0];
  const int*   ei  = (const int*)d_in[1];
  const float* W1  = (const float*)d_in[3];
  const float* as1 = (const float*)d_in[4];
  const float* ad1 = (const float*)d_in[5];
  const float* b1  = (const float*)d_in[6];
  const float* g1  = (const float*)d_in[7];
  const float* be1 = (const float*)d_in[8];
  const float* W2  = (const float*)d_in[9];
  const float* as2 = (const float*)d_in[10];
  const float* ad2 = (const float*)d_in[11];
  const float* b2  = (const float*)d_in[12];
  const float* g2  = (const float*)d_in[13];
  const float* be2 = (const float*)d_in[14];
  const float* W3  = (const float*)d_in[15];
  const float* as3 = (const float*)d_in[16];
  const float* ad3 = (const float*)d_in[17];
  const float* b3  = (const float*)d_in[18];
  const float* g3  = (const float*)d_in[19];
  const float* be3 = (const float*)d_in[20];
  const float* cW1 = (const float*)d_in[21];
  const float* cb1 = (const float*)d_in[22];
  const float* cW2 = (const float*)d_in[23];
  const float* cb2 = (const float*)d_in[24];
  float* out = (float*)d_out;

  const int N   = in_sizes[2];
  const int E0  = in_sizes[1] / 2;
  const int Et  = E0 + N;
  const int FIN = in_sizes[0] / N;

  float* ws = (float*)d_ws;
  size_t o = 0;
  ushort* Ab = (ushort*)(ws + o); o += (size_t)N * 64;   // N x 128 bf16 (h)
  ushort* Bb = (ushort*)(ws + o); o += (size_t)N * 64;   // N x 128 bf16 (x_l)
  float* als  = ws + o; o += (size_t)N * 4;
  float* ald  = ws + o; o += (size_t)N * 4;
  ushort* Wt1 = (ushort*)(ws + o); o += (128 * 512) / 2;
  ushort* Wt2 = (ushort*)(ws + o); o += (128 * 128) / 2;
  ushort* Wt3 = (ushort*)(ws + o); o += (64 * 128) / 2;
  float* psum = ws + o; o += 256 * 64;
  float* pmax = ws + o; o += 256 * 64;
  int* counts  = (int*)(ws + o); o += N + 1;
  int* offsets = (int*)(ws + o); o += N + 1;
  int* cursor  = (int*)(ws + o); o += N;
  int* bsum    = (int*)(ws + o); o += 256;
  int* csr_src = (int*)(ws + o); o += Et;

  const int* esrc = ei;
  const int* edst = ei + E0;
  const int NB = cdiv(N, 256);

  // ===== weight prep =====
  prep_wt<<<cdiv((long long)FIN * 128, TPB), TPB, 0, stream>>>(W1, Wt1, FIN, 128);
  prep_wt<<<cdiv((long long)128 * 128, TPB), TPB, 0, stream>>>(W2, Wt2, 128, 128);
  prep_wt<<<cdiv((long long)128 * 64, TPB), TPB, 0, stream>>>(W3, Wt3, 128, 64);

  // ===== CSR build (once, reused by all 3 layers) =====
  zero_int<<<cdiv(N + 1, TPB), TPB, 0, stream>>>(counts, N + 1);
  hist_dst<<<cdiv(Et, TPB), TPB, 0, stream>>>(edst, counts, E0, Et);
  block_sums<<<NB, 256, 0, stream>>>(counts, bsum, N);
  scan_bsum<<<1, 256, 0, stream>>>(bsum, NB);
  scan_final<<<NB, 256, 0, stream>>>(counts, bsum, offsets, cursor, N, Et);
  scatter_csr<<<cdiv(Et, TPB), TPB, 0, stream>>>(esrc, edst, cursor, csr_src, E0, Et);

  // ===== Layer 1: x[N,512] fp32 -> h(Ab) -> x1(Bb) =====
  {
    dim3 g(cdiv(N, 64), 2);
    gemm_mfma<0><<<g, 256, 0, stream>>>(x, Wt1, Ab, N, FIN, 128);
    compute_al<4, 32><<<cdiv((long long)N * 4, TPB), TPB, 0, stream>>>(Ab, as1, ad1, als, ald, N);
    fused_attn<4, 32><<<cdiv(N, 4), 256, 0, stream>>>(Ab, als, ald, offsets, csr_src, b1, g1, be1, Bb, N);
  }
  // ===== Layer 2: x1(Bb) -> h(Ab) -> x2(Bb) =====
  {
    dim3 g(cdiv(N, 64), 2);
    gemm_mfma<1><<<g, 256, 0, stream>>>(Bb, Wt2, Ab, N, 128, 128);
    compute_al<4, 32><<<cdiv((long long)N * 4, TPB), TPB, 0, stream>>>(Ab, as2, ad2, als, ald, N);
    fused_attn<4, 32><<<cdiv(N, 4), 256, 0, stream>>>(Ab, als, ald, offsets, csr_src, b2, g2, be2, Bb, N);
  }
  // ===== Layer 3: x2(Bb) -> h[N,64](Ab) -> x3(Bb) =====
  {
    dim3 g(cdiv(N, 64), 1);
    gemm_mfma<1><<<g, 256, 0, stream>>>(Bb, Wt3, Ab, N, 128, 64);
    compute_al<1, 64><<<cdiv((long long)N, TPB), TPB, 0, stream>>>(Ab, as3, ad3, als, ald, N);
    fused_attn<1, 64><<<cdiv(N, 4), 256, 0, stream>>>(Ab, als, ald, offsets, csr_src, b3, g3, be3, Bb, N);
  }
  // ===== Pool + classifier =====
  pool_partial<<<256, 256, 0, stream>>>(Bb, psum, pmax, N);
  pool_final<<<1, 128, 0, stream>>>(psum, pmax, 256, N, cW1, cb1, cW2, cb2, out);
}

// Round 4
// 419.798 us; speedup vs baseline: 3.0575x; 1.0641x over previous
//
#include <hip/hip_runtime.h>
#include <cmath>

static constexpr int TPB = 256;

using short8 = __attribute__((ext_vector_type(8))) short;
using f32x4  = __attribute__((ext_vector_type(4))) float;
typedef unsigned short ushort;
typedef unsigned int uint;

__device__ __forceinline__ ushort f2b(float f) {
  unsigned x = __builtin_bit_cast(unsigned, f);
  unsigned r = (x + 0x7fffu + ((x >> 16) & 1u)) >> 16;   // RNE
  return (ushort)r;
}
__device__ __forceinline__ float b2f(ushort u) {
  unsigned v = ((unsigned)u) << 16;
  return __builtin_bit_cast(float, v);
}
__device__ __forceinline__ float blo(uint u) {        // low bf16 of dword
  return __builtin_bit_cast(float, u << 16);
}
__device__ __forceinline__ float bhi(uint u) {        // high bf16 of dword
  return __builtin_bit_cast(float, u & 0xffff0000u);
}

// ---------- W [K][Nc] fp32 -> Wt [Nc][K] bf16 ----------
__global__ void prep_wt(const float* __restrict__ W, ushort* __restrict__ Wt, int K, int Nc) {
  int idx = blockIdx.x * TPB + threadIdx.x;
  if (idx >= K * Nc) return;
  int nc = idx / K, k = idx - nc * K;
  Wt[idx] = f2b(W[(size_t)k * Nc + nc]);
}

// ---------- MFMA GEMM: C[n,Nc](bf16) = A[n,K] @ W[K,Nc], Wt pre-transposed ----------
// BM=64, BN=64, BK=64, 256 threads = 4 waves (2x2 of 32x32 wave tiles)
// FUSE: also emit als/ald = h . a_s / a_d per (row, head) — requires Nc=128, C=32.
template <int ABF16, bool FUSE>
__global__ __launch_bounds__(256) void gemm_mfma(const void* __restrict__ Ap,
                                                 const ushort* __restrict__ Wt,
                                                 ushort* __restrict__ Cb,
                                                 int n, int K, int Nc,
                                                 const float* __restrict__ a_s,
                                                 const float* __restrict__ a_d,
                                                 float* __restrict__ als,
                                                 float* __restrict__ ald) {
  __shared__ short As[64 * 72];
  __shared__ short Bs[64 * 72];
  const int tid = threadIdx.x;
  const int row0 = blockIdx.x * 64, col0 = blockIdx.y * 64;
  const int srow = tid >> 2, sks = (tid & 3) << 4;  // staging: row, k-segment(16)
  const int wave = tid >> 6, lane = tid & 63;
  const int wr = wave >> 1, wc = wave & 1;
  const int lm = lane & 15, lg = lane >> 4;

  f32x4 acc[2][2] = {};

  for (int k0 = 0; k0 < K; k0 += 64) {
    {
      int gr = row0 + srow;
      short8 v0 = {0, 0, 0, 0, 0, 0, 0, 0}, v1 = v0;
      if constexpr (ABF16 == 0) {
        const float* A = (const float*)Ap;
        if (gr < n) {
          const float* p = A + (size_t)gr * K + k0 + sks;
          float4 f0 = *(const float4*)(p + 0);
          float4 f1 = *(const float4*)(p + 4);
          float4 f2 = *(const float4*)(p + 8);
          float4 f3 = *(const float4*)(p + 12);
          v0[0] = (short)f2b(f0.x); v0[1] = (short)f2b(f0.y); v0[2] = (short)f2b(f0.z); v0[3] = (short)f2b(f0.w);
          v0[4] = (short)f2b(f1.x); v0[5] = (short)f2b(f1.y); v0[6] = (short)f2b(f1.z); v0[7] = (short)f2b(f1.w);
          v1[0] = (short)f2b(f2.x); v1[1] = (short)f2b(f2.y); v1[2] = (short)f2b(f2.z); v1[3] = (short)f2b(f2.w);
          v1[4] = (short)f2b(f3.x); v1[5] = (short)f2b(f3.y); v1[6] = (short)f2b(f3.z); v1[7] = (short)f2b(f3.w);
        }
      } else {
        const ushort* A = (const ushort*)Ap;
        if (gr < n) {
          const ushort* p = A + (size_t)gr * K + k0 + sks;
          v0 = *(const short8*)(p + 0);
          v1 = *(const short8*)(p + 8);
        }
      }
      *(short8*)&As[srow * 72 + sks + 0] = v0;
      *(short8*)&As[srow * 72 + sks + 8] = v1;
      const ushort* wp = Wt + (size_t)(col0 + srow) * K + k0 + sks;
      *(short8*)&Bs[srow * 72 + sks + 0] = *(const short8*)(wp + 0);
      *(short8*)&Bs[srow * 72 + sks + 8] = *(const short8*)(wp + 8);
    }
    __syncthreads();
#pragma unroll
    for (int kk = 0; kk < 64; kk += 32) {
      short8 a0 = *(const short8*)&As[(wr * 32 + lm) * 72 + kk + lg * 8];
      short8 a1 = *(const short8*)&As[(wr * 32 + 16 + lm) * 72 + kk + lg * 8];
      short8 b0 = *(const short8*)&Bs[(wc * 32 + lm) * 72 + kk + lg * 8];
      short8 b1 = *(const short8*)&Bs[(wc * 32 + 16 + lm) * 72 + kk + lg * 8];
      acc[0][0] = __builtin_amdgcn_mfma_f32_16x16x32_bf16(a0, b0, acc[0][0], 0, 0, 0);
      acc[0][1] = __builtin_amdgcn_mfma_f32_16x16x32_bf16(a0, b1, acc[0][1], 0, 0, 0);
      acc[1][0] = __builtin_amdgcn_mfma_f32_16x16x32_bf16(a1, b0, acc[1][0], 0, 0, 0);
      acc[1][1] = __builtin_amdgcn_mfma_f32_16x16x32_bf16(a1, b1, acc[1][1], 0, 0, 0);
    }
    __syncthreads();
  }
  // C epilogue: D row = (lg*4 + r), col = lm within each 16x16 frag
#pragma unroll
  for (int m = 0; m < 2; ++m)
#pragma unroll
    for (int nn = 0; nn < 2; ++nn)
#pragma unroll
      for (int r = 0; r < 4; ++r) {
        int row = row0 + wr * 32 + m * 16 + lg * 4 + r;
        if (row < n) {
          int col = col0 + wc * 32 + nn * 16 + lm;
          Cb[(size_t)row * Nc + col] = f2b(acc[m][nn][r]);
        }
      }
  // fused attention-logit epilogue (head = 32 contiguous cols, fully in-wave)
  if constexpr (FUSE) {
    const int head = (col0 >> 5) + wc;
    float as0 = a_s[head * 32 + lm],      as1 = a_s[head * 32 + 16 + lm];
    float ad0 = a_d[head * 32 + lm],      ad1 = a_d[head * 32 + 16 + lm];
#pragma unroll
    for (int m = 0; m < 2; ++m)
#pragma unroll
      for (int r = 0; r < 4; ++r) {
        float tS = acc[m][0][r] * as0 + acc[m][1][r] * as1;
        float tD = acc[m][0][r] * ad0 + acc[m][1][r] * ad1;
#pragma unroll
        for (int off = 8; off >= 1; off >>= 1) {
          tS += __shfl_xor(tS, off);
          tD += __shfl_xor(tD, off);
        }
        if (lm == 0) {
          int row = row0 + wr * 32 + m * 16 + lg * 4 + r;
          if (row < n) {
            als[(size_t)row * 4 + head] = tS;
            ald[(size_t)row * 4 + head] = tD;
          }
        }
      }
  }
}

// ---------- per-(node,head) attention logits from bf16 h (layer 3 only) ----------
template <int HH, int CC>
__global__ void compute_al(const ushort* __restrict__ hb, const float* __restrict__ a_s,
                           const float* __restrict__ a_d, float* __restrict__ als,
                           float* __restrict__ ald, int n) {
  int idx = blockIdx.x * TPB + threadIdx.x;
  if (idx >= n * HH) return;
  int node = idx / HH, h = idx - (idx / HH) * HH;
  const ushort* hp = hb + (size_t)node * (HH * CC) + h * CC;
  float s = 0.f, d = 0.f;
#pragma unroll
  for (int c8 = 0; c8 < CC; c8 += 8) {
    short8 v = *(const short8*)(hp + c8);
#pragma unroll
    for (int j = 0; j < 8; ++j) {
      float f = b2f((ushort)v[j]);
      s += f * a_s[h * CC + c8 + j];
      d += f * a_d[h * CC + c8 + j];
    }
  }
  als[idx] = s;
  ald[idx] = d;
}

// ---------- CSR build ----------
__global__ void zero_int(int* __restrict__ p, int n) {
  int i = blockIdx.x * TPB + threadIdx.x;
  if (i < n) p[i] = 0;
}

__global__ void hist_dst(const int* __restrict__ edst, int* __restrict__ counts,
                         int E0, int Et) {
  int e = blockIdx.x * TPB + threadIdx.x;
  if (e >= Et) return;
  int d = e < E0 ? edst[e] : e - E0;
  atomicAdd(&counts[d], 1);
}

__global__ void block_sums(const int* __restrict__ counts, int* __restrict__ bsum, int N) {
  __shared__ int sh[256];
  int t = threadIdx.x, idx = blockIdx.x * 256 + t;
  sh[t] = idx < N ? counts[idx] : 0;
  __syncthreads();
  for (int off = 128; off >= 1; off >>= 1) {
    if (t < off) sh[t] += sh[t + off];
    __syncthreads();
  }
  if (t == 0) bsum[blockIdx.x] = sh[0];
}

__global__ void scan_bsum(int* __restrict__ bsum, int nb) {
  __shared__ int sh[256];
  int t = threadIdx.x;
  int v = t < nb ? bsum[t] : 0;
  sh[t] = v;
  __syncthreads();
  for (int off = 1; off < 256; off <<= 1) {
    int u = (t >= off) ? sh[t - off] : 0;
    __syncthreads();
    sh[t] += u;
    __syncthreads();
  }
  if (t < nb) bsum[t] = sh[t] - v;  // exclusive
}

__global__ void scan_final(const int* __restrict__ counts, const int* __restrict__ bsum_ex,
                           int* __restrict__ offsets, int* __restrict__ cursor,
                           int N, int Et) {
  __shared__ int sh[256];
  int t = threadIdx.x, b = blockIdx.x;
  int idx = b * 256 + t;
  int v = (idx < N) ? counts[idx] : 0;
  sh[t] = v;
  __syncthreads();
  for (int off = 1; off < 256; off <<= 1) {
    int u = (t >= off) ? sh[t - off] : 0;
    __syncthreads();
    sh[t] += u;
    __syncthreads();
  }
  if (idx < N) {
    int o = bsum_ex[b] + sh[t] - v;
    offsets[idx] = o;
    cursor[idx] = o;
  }
  if (idx == 0) offsets[N] = Et;
}

__global__ void scatter_csr(const int* __restrict__ esrc, const int* __restrict__ edst,
                            int* __restrict__ cursor, int* __restrict__ csr_src,
                            int E0, int Et) {
  int e = blockIdx.x * TPB + threadIdx.x;
  if (e >= Et) return;
  int s = e < E0 ? esrc[e] : e - E0;
  int d = e < E0 ? edst[e] : e - E0;
  int pos = atomicAdd(&cursor[d], 1);
  csr_src[pos] = s;
}

// ---------- fused attention + bias + LayerNorm + ELU, one wave per dst node ----------
// Channel-pair layout: lane owns channels (2*lane, 2*lane+1) [HH=4, W=128]
// or ((lane&31)*2, +1) with the two wave-halves covering 2 edges at once [HH=1, W=64].
template <int HH, int CC>
__global__ __launch_bounds__(256) void fused_attn(
    const ushort* __restrict__ hb, const float* __restrict__ als,
    const float* __restrict__ ald, const int* __restrict__ offsets,
    const int* __restrict__ csr_src, const float* __restrict__ bias,
    const float* __restrict__ g, const float* __restrict__ be,
    ushort* __restrict__ xout, int n) {
  constexpr int W = HH * CC;   // 128 or 64
  int wid = (int)((blockIdx.x * (size_t)blockDim.x + threadIdx.x) >> 6);
  int lane = threadIdx.x & 63;
  if (wid >= n) return;
  const int d = wid;
  const int begin = offsets[d], end = offsets[d + 1];
  const int deg = end - begin;

  const int hsel = lane >> 4;                       // head of my channel pair (HH=4)
  const int c0 = (HH == 4) ? (2 * lane) : (2 * (lane & 31));

  float aldv[HH];
  if constexpr (HH == 4) {
    float4 t = *(const float4*)(ald + (size_t)d * 4);
    aldv[0] = t.x; aldv[1] = t.y; aldv[2] = t.z; aldv[3] = t.w;
  } else {
    aldv[0] = ald[d];
  }

  auto sel4 = [&](float x0, float x1, float x2, float x3) {
    float lo = (hsel & 1) ? x1 : x0;
    float hi = (hsel & 1) ? x3 : x2;
    return (hsel & 2) ? hi : lo;
  };

  float acc0 = 0.f, acc1 = 0.f;

  if (deg <= 64) {
    // ---- fast path: one lane per edge for logits ----
    bool act = lane < deg;
    int s_e = act ? csr_src[begin + lane] : 0;
    float e0 = -1e30f, e1 = -1e30f, e2 = -1e30f, e3 = -1e30f;
    if constexpr (HH == 4) {
      if (act) {
        float4 t = *(const float4*)(als + (size_t)s_e * 4);
        e0 = t.x + aldv[0]; e0 = e0 > 0.f ? e0 : 0.2f * e0;
        e1 = t.y + aldv[1]; e1 = e1 > 0.f ? e1 : 0.2f * e1;
        e2 = t.z + aldv[2]; e2 = e2 > 0.f ? e2 : 0.2f * e2;
        e3 = t.w + aldv[3]; e3 = e3 > 0.f ? e3 : 0.2f * e3;
      }
    } else {
      if (act) {
        e0 = als[s_e] + aldv[0]; e0 = e0 > 0.f ? e0 : 0.2f * e0;
      }
    }
    float m0 = e0, m1 = e1, m2 = e2, m3 = e3;
#pragma unroll
    for (int off = 32; off >= 1; off >>= 1) {
      m0 = fmaxf(m0, __shfl_xor(m0, off));
      if constexpr (HH == 4) {
        m1 = fmaxf(m1, __shfl_xor(m1, off));
        m2 = fmaxf(m2, __shfl_xor(m2, off));
        m3 = fmaxf(m3, __shfl_xor(m3, off));
      }
    }
    float p0 = act ? __expf(e0 - m0) : 0.f;
    float p1 = 0.f, p2 = 0.f, p3 = 0.f;
    if constexpr (HH == 4) {
      p1 = act ? __expf(e1 - m1) : 0.f;
      p2 = act ? __expf(e2 - m2) : 0.f;
      p3 = act ? __expf(e3 - m3) : 0.f;
    }
    float s0 = p0, s1 = p1, s2 = p2, s3 = p3;
#pragma unroll
    for (int off = 32; off >= 1; off >>= 1) {
      s0 += __shfl_xor(s0, off);
      if constexpr (HH == 4) {
        s1 += __shfl_xor(s1, off);
        s2 += __shfl_xor(s2, off);
        s3 += __shfl_xor(s3, off);
      }
    }
    float a0 = p0 / (s0 + 1e-16f);
    float a1 = 0.f, a2 = 0.f, a3 = 0.f;
    if constexpr (HH == 4) {
      a1 = p1 / (s1 + 1e-16f);
      a2 = p2 / (s2 + 1e-16f);
      a3 = p3 / (s3 + 1e-16f);
    }

    if constexpr (HH == 4) {
      // software-pipelined gather: 2 edges per iter, 2 row-loads in flight
      int sA = __shfl(s_e, 0);
      int sB = deg > 1 ? __shfl(s_e, 1) : sA;
      uint va = *(const uint*)(hb + (size_t)sA * W + c0);
      uint vb = *(const uint*)(hb + (size_t)sB * W + c0);
      for (int j = 0; j < deg; j += 2) {
        uint ua = va, ub = vb;
        int jn = j + 2;
        if (jn < deg) {
          int sa = __shfl(s_e, jn);
          int sb = jn + 1 < deg ? __shfl(s_e, jn + 1) : sa;
          va = *(const uint*)(hb + (size_t)sa * W + c0);
          vb = *(const uint*)(hb + (size_t)sb * W + c0);
        }
        float wa = sel4(__shfl(a0, j), __shfl(a1, j), __shfl(a2, j), __shfl(a3, j));
        acc0 = fmaf(wa, blo(ua), acc0);
        acc1 = fmaf(wa, bhi(ua), acc1);
        if (j + 1 < deg) {
          float wb = sel4(__shfl(a0, j + 1), __shfl(a1, j + 1), __shfl(a2, j + 1), __shfl(a3, j + 1));
          acc0 = fmaf(wb, blo(ub), acc0);
          acc1 = fmaf(wb, bhi(ub), acc1);
        }
      }
    } else {
      // 2 edges at once: lanes<32 edge j, lanes>=32 edge j+1
      int sA = __shfl(s_e, 0);
      int sB = deg > 1 ? __shfl(s_e, 1) : sA;
      int smy = lane < 32 ? sA : sB;
      uint v = *(const uint*)(hb + (size_t)smy * W + c0);
      for (int j = 0; j < deg; j += 2) {
        uint u = v;
        int jn = j + 2;
        if (jn < deg) {
          int sa = __shfl(s_e, jn);
          int sb = jn + 1 < deg ? __shfl(s_e, jn + 1) : sa;
          int sm2 = lane < 32 ? sa : sb;
          v = *(const uint*)(hb + (size_t)sm2 * W + c0);
        }
        float wa = __shfl(a0, j);
        float wb = (j + 1 < deg) ? __shfl(a0, j + 1) : 0.f;
        float wm = lane < 32 ? wa : wb;
        acc0 = fmaf(wm, blo(u), acc0);
        acc1 = fmaf(wm, bhi(u), acc1);
      }
    }
  } else {
    // ---- slow path (deg > 64): 3-phase with reload ----
    float me[HH];
#pragma unroll
    for (int h = 0; h < HH; ++h) me[h] = -1e30f;
    for (int k = begin + lane; k < end; k += 64) {
      int s = csr_src[k];
      if constexpr (HH == 4) {
        float4 t = *(const float4*)(als + (size_t)s * 4);
        float e0 = t.x + aldv[0]; e0 = e0 > 0.f ? e0 : 0.2f * e0; me[0] = fmaxf(me[0], e0);
        float e1 = t.y + aldv[1]; e1 = e1 > 0.f ? e1 : 0.2f * e1; me[1] = fmaxf(me[1], e1);
        float e2 = t.z + aldv[2]; e2 = e2 > 0.f ? e2 : 0.2f * e2; me[2] = fmaxf(me[2], e2);
        float e3 = t.w + aldv[3]; e3 = e3 > 0.f ? e3 : 0.2f * e3; me[3] = fmaxf(me[3], e3);
      } else {
        float e0 = als[s] + aldv[0]; e0 = e0 > 0.f ? e0 : 0.2f * e0; me[0] = fmaxf(me[0], e0);
      }
    }
#pragma unroll
    for (int off = 32; off >= 1; off >>= 1)
#pragma unroll
      for (int h = 0; h < HH; ++h) me[h] = fmaxf(me[h], __shfl_xor(me[h], off));
    float se[HH];
#pragma unroll
    for (int h = 0; h < HH; ++h) se[h] = 0.f;
    for (int k = begin + lane; k < end; k += 64) {
      int s = csr_src[k];
      if constexpr (HH == 4) {
        float4 t = *(const float4*)(als + (size_t)s * 4);
        float e0 = t.x + aldv[0]; e0 = e0 > 0.f ? e0 : 0.2f * e0; se[0] += __expf(e0 - me[0]);
        float e1 = t.y + aldv[1]; e1 = e1 > 0.f ? e1 : 0.2f * e1; se[1] += __expf(e1 - me[1]);
        float e2 = t.z + aldv[2]; e2 = e2 > 0.f ? e2 : 0.2f * e2; se[2] += __expf(e2 - me[2]);
        float e3 = t.w + aldv[3]; e3 = e3 > 0.f ? e3 : 0.2f * e3; se[3] += __expf(e3 - me[3]);
      } else {
        float e0 = als[s] + aldv[0]; e0 = e0 > 0.f ? e0 : 0.2f * e0; se[0] += __expf(e0 - me[0]);
      }
    }
#pragma unroll
    for (int off = 32; off >= 1; off >>= 1)
#pragma unroll
      for (int h = 0; h < HH; ++h) se[h] += __shfl_xor(se[h], off);
    float inv[HH];
#pragma unroll
    for (int h = 0; h < HH; ++h) inv[h] = 1.f / (se[h] + 1e-16f);

    if constexpr (HH == 4) {
      float m_my = sel4(me[0], me[1], me[2], me[3]);
      float i_my = sel4(inv[0], inv[1], inv[2], inv[3]);
      float ad_my = sel4(aldv[0], aldv[1], aldv[2], aldv[3]);
      for (int k = begin; k < end; ++k) {
        int s = csr_src[k];
        float4 t = *(const float4*)(als + (size_t)s * 4);
        float as_my = sel4(t.x, t.y, t.z, t.w);
        float e = as_my + ad_my; e = e > 0.f ? e : 0.2f * e;
        float w = __expf(e - m_my) * i_my;
        uint u = *(const uint*)(hb + (size_t)s * W + c0);
        acc0 = fmaf(w, blo(u), acc0);
        acc1 = fmaf(w, bhi(u), acc1);
      }
    } else {
      for (int k = begin; k < end; ++k) {
        int s = csr_src[k];
        float e = als[s] + aldv[0]; e = e > 0.f ? e : 0.2f * e;
        float w = __expf(e - me[0]) * inv[0];
        float wm = lane < 32 ? w : 0.f;
        uint u = *(const uint*)(hb + (size_t)s * W + c0);
        acc0 = fmaf(wm, blo(u), acc0);
        acc1 = fmaf(wm, bhi(u), acc1);
      }
    }
  }

  if constexpr (HH == 1) {
    acc0 += __shfl_xor(acc0, 32);
    acc1 += __shfl_xor(acc1, 32);
  }

  // bias + LayerNorm + ELU on channel pair (c0, c0+1)
  float2 bv = *(const float2*)(bias + c0);
  float v0 = acc0 + bv.x;
  float v1 = acc1 + bv.y;
  float sm = v0 + v1;
  float s2 = v0 * v0 + v1 * v1;
  constexpr int TOPOFF = (HH == 4) ? 32 : 16;  // HH=1: halves hold duplicates
#pragma unroll
  for (int off = TOPOFF; off >= 1; off >>= 1) {
    sm += __shfl_xor(sm, off);
    s2 += __shfl_xor(s2, off);
  }
  const float invW = 1.0f / W;
  float mu = sm * invW;
  float var = s2 * invW - mu * mu;
  float r = rsqrtf(var + 1e-5f);
  float2 gv = *(const float2*)(g + c0);
  float2 bev = *(const float2*)(be + c0);
  float y0 = gv.x * (v0 - mu) * r + bev.x;
  y0 = y0 > 0.f ? y0 : __expf(y0) - 1.f;
  float y1 = gv.y * (v1 - mu) * r + bev.y;
  y1 = y1 > 0.f ? y1 : __expf(y1) - 1.f;
  uint pk = (uint)f2b(y0) | ((uint)f2b(y1) << 16);
  if (HH == 4 || lane < 32)
    *(uint*)(xout + (size_t)wid * W + c0) = pk;
}

// ---------- pooling over bf16 h3 ----------
__global__ void pool_partial(const ushort* __restrict__ h, float* __restrict__ psum,
                             float* __restrict__ pmax, int n) {
  int tid = threadIdx.x;
  float lsum = 0.f, lmax = -1e30f;
  for (size_t idx = (size_t)blockIdx.x * 256 + tid; idx < (size_t)n * 64;
       idx += (size_t)gridDim.x * 256) {
    float v = b2f(h[idx]);
    lsum += v;
    lmax = fmaxf(lmax, v);
  }
  __shared__ float ss[256], sm[256];
  ss[tid] = lsum; sm[tid] = lmax;
  __syncthreads();
  if (tid < 64) {
    float a = ss[tid] + ss[tid + 64] + ss[tid + 128] + ss[tid + 192];
    float m = fmaxf(fmaxf(sm[tid], sm[tid + 64]), fmaxf(sm[tid + 128], sm[tid + 192]));
    psum[blockIdx.x * 64 + tid] = a;
    pmax[blockIdx.x * 64 + tid] = m;
  }
}

// ---------- final reduce + classifier ----------
__global__ void pool_final(const float* __restrict__ psum, const float* __restrict__ pmax,
                           int nblocks, int n, const float* __restrict__ cW1,
                           const float* __restrict__ cb1, const float* __restrict__ cW2,
                           const float* __restrict__ cb2, float* __restrict__ out) {
  __shared__ float z[128];
  __shared__ float hid[128];
  int tid = threadIdx.x;
  if (tid < 64) {
    float s = 0.f, m = -1e30f;
    for (int b = 0; b < nblocks; ++b) {
      s += psum[b * 64 + tid];
      m = fmaxf(m, pmax[b * 64 + tid]);
    }
    z[tid] = s / (float)n;
    z[64 + tid] = m;
  }
  __syncthreads();
  float a = cb1[tid];
  for (int k = 0; k < 128; ++k) a += z[k] * cW1[k * 128 + tid];
  hid[tid] = fmaxf(a, 0.f);
  __syncthreads();
  if (tid < 2) {
    float o = cb2[tid];
    for (int j = 0; j < 128; ++j) o += hid[j] * cW2[j * 2 + tid];
    out[tid] = o;
  }
}

static inline int cdiv(long long a, long long b) { return (int)((a + b - 1) / b); }

extern "C" void kernel_launch(void* const* d_in, const int* in_sizes, int n_in,
                              void* d_out, int out_size, void* d_ws, size_t ws_size,
                              hipStream_t stream) {
  const float* x   = (const float*)d_in[0];
  const int*   ei  = (const int*)d_in[1];
  const float* W1  = (const float*)d_in[3];
  const float* as1 = (const float*)d_in[4];
  const float* ad1 = (const float*)d_in[5];
  const float* b1  = (const float*)d_in[6];
  const float* g1  = (const float*)d_in[7];
  const float* be1 = (const float*)d_in[8];
  const float* W2  = (const float*)d_in[9];
  const float* as2 = (const float*)d_in[10];
  const float* ad2 = (const float*)d_in[11];
  const float* b2  = (const float*)d_in[12];
  const float* g2  = (const float*)d_in[13];
  const float* be2 = (const float*)d_in[14];
  const float* W3  = (const float*)d_in[15];
  const float* as3 = (const float*)d_in[16];
  const float* ad3 = (const float*)d_in[17];
  const float* b3  = (const float*)d_in[18];
  const float* g3  = (const float*)d_in[19];
  const float* be3 = (const float*)d_in[20];
  const float* cW1 = (const float*)d_in[21];
  const float* cb1 = (const float*)d_in[22];
  const float* cW2 = (const float*)d_in[23];
  const float* cb2 = (const float*)d_in[24];
  float* out = (float*)d_out;

  const int N   = in_sizes[2];
  const int E0  = in_sizes[1] / 2;
  const int Et  = E0 + N;
  const int FIN = in_sizes[0] / N;

  float* ws = (float*)d_ws;
  size_t o = 0;
  ushort* Ab = (ushort*)(ws + o); o += (size_t)N * 64;   // N x 128 bf16 (h)
  ushort* Bb = (ushort*)(ws + o); o += (size_t)N * 64;   // N x 128 bf16 (x_l)
  float* als  = ws + o; o += (size_t)N * 4;
  float* ald  = ws + o; o += (size_t)N * 4;
  ushort* Wt1 = (ushort*)(ws + o); o += (128 * 512) / 2;
  ushort* Wt2 = (ushort*)(ws + o); o += (128 * 128) / 2;
  ushort* Wt3 = (ushort*)(ws + o); o += (64 * 128) / 2;
  float* psum = ws + o; o += 256 * 64;
  float* pmax = ws + o; o += 256 * 64;
  int* counts  = (int*)(ws + o); o += N + 1;
  int* offsets = (int*)(ws + o); o += N + 1;
  int* cursor  = (int*)(ws + o); o += N;
  int* bsum    = (int*)(ws + o); o += 256;
  int* csr_src = (int*)(ws + o); o += Et;

  const int* esrc = ei;
  const int* edst = ei + E0;
  const int NB = cdiv(N, 256);

  // ===== weight prep =====
  prep_wt<<<cdiv((long long)FIN * 128, TPB), TPB, 0, stream>>>(W1, Wt1, FIN, 128);
  prep_wt<<<cdiv((long long)128 * 128, TPB), TPB, 0, stream>>>(W2, Wt2, 128, 128);
  prep_wt<<<cdiv((long long)128 * 64, TPB), TPB, 0, stream>>>(W3, Wt3, 128, 64);

  // ===== CSR build (once, reused by all 3 layers) =====
  zero_int<<<cdiv(N + 1, TPB), TPB, 0, stream>>>(counts, N + 1);
  hist_dst<<<cdiv(Et, TPB), TPB, 0, stream>>>(edst, counts, E0, Et);
  block_sums<<<NB, 256, 0, stream>>>(counts, bsum, N);
  scan_bsum<<<1, 256, 0, stream>>>(bsum, NB);
  scan_final<<<NB, 256, 0, stream>>>(counts, bsum, offsets, cursor, N, Et);
  scatter_csr<<<cdiv(Et, TPB), TPB, 0, stream>>>(esrc, edst, cursor, csr_src, E0, Et);

  // ===== Layer 1: x[N,512] fp32 -> h(Ab)+al -> x1(Bb) =====
  {
    dim3 gg(cdiv(N, 64), 2);
    gemm_mfma<0, true><<<gg, 256, 0, stream>>>(x, Wt1, Ab, N, FIN, 128, as1, ad1, als, ald);
    fused_attn<4, 32><<<cdiv(N, 4), 256, 0, stream>>>(Ab, als, ald, offsets, csr_src, b1, g1, be1, Bb, N);
  }
  // ===== Layer 2: x1(Bb) -> h(Ab)+al -> x2(Bb) =====
  {
    dim3 gg(cdiv(N, 64), 2);
    gemm_mfma<1, true><<<gg, 256, 0, stream>>>(Bb, Wt2, Ab, N, 128, 128, as2, ad2, als, ald);
    fused_attn<4, 32><<<cdiv(N, 4), 256, 0, stream>>>(Ab, als, ald, offsets, csr_src, b2, g2, be2, Bb, N);
  }
  // ===== Layer 3: x2(Bb) -> h[N,64](Ab) -> x3(Bb) =====
  {
    dim3 gg(cdiv(N, 64), 1);
    gemm_mfma<1, false><<<gg, 256, 0, stream>>>(Bb, Wt3, Ab, N, 128, 64, nullptr, nullptr, nullptr, nullptr);
    compute_al<1, 64><<<cdiv((long long)N, TPB), TPB, 0, stream>>>(Ab, as3, ad3, als, ald, N);
    fused_attn<1, 64><<<cdiv(N, 4), 256, 0, stream>>>(Ab, als, ald, offsets, csr_src, b3, g3, be3, Bb, N);
  }
  // ===== Pool + classifier =====
  pool_partial<<<256, 256, 0, stream>>>(Bb, psum, pmax, N);
  pool_final<<<1, 128, 0, stream>>>(psum, pmax, 256, N, cW1, cb1, cW2, cb2, out);
}

// Round 5
// 369.260 us; speedup vs baseline: 3.4760x; 1.1369x over previous
//
#include <hip/hip_runtime.h>
#include <cmath>

static constexpr int TPB = 256;

using short8 = __attribute__((ext_vector_type(8))) short;
using f32x4  = __attribute__((ext_vector_type(4))) float;
using uint4v = __attribute__((ext_vector_type(4))) unsigned int;
typedef unsigned short ushort;
typedef unsigned int uint;

__device__ __forceinline__ ushort f2b(float f) {
  unsigned x = __builtin_bit_cast(unsigned, f);
  unsigned r = (x + 0x7fffu + ((x >> 16) & 1u)) >> 16;   // RNE
  return (ushort)r;
}
__device__ __forceinline__ float b2f(ushort u) {
  unsigned v = ((unsigned)u) << 16;
  return __builtin_bit_cast(float, v);
}
__device__ __forceinline__ float blo(uint u) { return __builtin_bit_cast(float, u << 16); }
__device__ __forceinline__ float bhi(uint u) { return __builtin_bit_cast(float, u & 0xffff0000u); }

// ---------- W [K][Nc] fp32 -> Wt [Nc][K] bf16 ----------
__global__ void prep_wt(const float* __restrict__ W, ushort* __restrict__ Wt, int K, int Nc) {
  int idx = blockIdx.x * TPB + threadIdx.x;
  if (idx >= K * Nc) return;
  int nc = idx / K, k = idx - nc * K;
  Wt[idx] = f2b(W[(size_t)k * Nc + nc]);
}

// ---------- MFMA GEMM: C[n,BN](bf16) = A[n,K] @ W[K,BN], Wt pre-transposed ----------
// BM=64, BN=Nc (64 or 128), BK=64, 256 threads = 4 waves (2 row x 2 col)
// Each wave: 32 rows x BN/2 cols. FUSE (BN=128): emit als/ald per (row, head).
template <int ABF16, int BN, bool FUSE>
__global__ __launch_bounds__(256) void gemm_mfma(const void* __restrict__ Ap,
                                                 const ushort* __restrict__ Wt,
                                                 ushort* __restrict__ Cb,
                                                 int n, int K,
                                                 const float* __restrict__ a_s,
                                                 const float* __restrict__ a_d,
                                                 float* __restrict__ als,
                                                 float* __restrict__ ald) {
  constexpr int NF = BN / 32;  // col frags per wave (4 or 2)
  __shared__ short As[64 * 72];
  __shared__ short Bs[BN * 72];
  const int tid = threadIdx.x;
  const int row0 = blockIdx.x * 64;
  const int srow = tid >> 2, sks = (tid & 3) << 4;  // A staging
  const int wave = tid >> 6, lane = tid & 63;
  const int wr = wave >> 1, wc = wave & 1;
  const int lm = lane & 15, lg = lane >> 4;

  f32x4 acc[2][NF] = {};

  for (int k0 = 0; k0 < K; k0 += 64) {
    // ---- stage A tile ----
    {
      int gr = row0 + srow;
      short8 v0 = {0, 0, 0, 0, 0, 0, 0, 0}, v1 = v0;
      if constexpr (ABF16 == 0) {
        const float* A = (const float*)Ap;
        if (gr < n) {
          const float* p = A + (size_t)gr * K + k0 + sks;
          float4 f0 = *(const float4*)(p + 0);
          float4 f1 = *(const float4*)(p + 4);
          float4 f2 = *(const float4*)(p + 8);
          float4 f3 = *(const float4*)(p + 12);
          v0[0] = (short)f2b(f0.x); v0[1] = (short)f2b(f0.y); v0[2] = (short)f2b(f0.z); v0[3] = (short)f2b(f0.w);
          v0[4] = (short)f2b(f1.x); v0[5] = (short)f2b(f1.y); v0[6] = (short)f2b(f1.z); v0[7] = (short)f2b(f1.w);
          v1[0] = (short)f2b(f2.x); v1[1] = (short)f2b(f2.y); v1[2] = (short)f2b(f2.z); v1[3] = (short)f2b(f2.w);
          v1[4] = (short)f2b(f3.x); v1[5] = (short)f2b(f3.y); v1[6] = (short)f2b(f3.z); v1[7] = (short)f2b(f3.w);
        }
      } else {
        const ushort* A = (const ushort*)Ap;
        if (gr < n) {
          const ushort* p = A + (size_t)gr * K + k0 + sks;
          v0 = *(const short8*)(p + 0);
          v1 = *(const short8*)(p + 8);
        }
      }
      *(short8*)&As[srow * 72 + sks + 0] = v0;
      *(short8*)&As[srow * 72 + sks + 8] = v1;
    }
    // ---- stage B tile from Wt [BN][K] ----
    if constexpr (BN == 128) {
      const int brow = tid >> 1, bks = (tid & 1) << 5;
      const ushort* wp = Wt + (size_t)brow * K + k0 + bks;
      *(short8*)&Bs[brow * 72 + bks + 0]  = *(const short8*)(wp + 0);
      *(short8*)&Bs[brow * 72 + bks + 8]  = *(const short8*)(wp + 8);
      *(short8*)&Bs[brow * 72 + bks + 16] = *(const short8*)(wp + 16);
      *(short8*)&Bs[brow * 72 + bks + 24] = *(const short8*)(wp + 24);
    } else {
      const ushort* wp = Wt + (size_t)srow * K + k0 + sks;
      *(short8*)&Bs[srow * 72 + sks + 0] = *(const short8*)(wp + 0);
      *(short8*)&Bs[srow * 72 + sks + 8] = *(const short8*)(wp + 8);
    }
    __syncthreads();
#pragma unroll
    for (int kk = 0; kk < 64; kk += 32) {
      short8 a0 = *(const short8*)&As[(wr * 32 + lm) * 72 + kk + lg * 8];
      short8 a1 = *(const short8*)&As[(wr * 32 + 16 + lm) * 72 + kk + lg * 8];
      short8 bf[NF];
#pragma unroll
      for (int f = 0; f < NF; ++f)
        bf[f] = *(const short8*)&Bs[(wc * (BN / 2) + f * 16 + lm) * 72 + kk + lg * 8];
#pragma unroll
      for (int f = 0; f < NF; ++f) {
        acc[0][f] = __builtin_amdgcn_mfma_f32_16x16x32_bf16(a0, bf[f], acc[0][f], 0, 0, 0);
        acc[1][f] = __builtin_amdgcn_mfma_f32_16x16x32_bf16(a1, bf[f], acc[1][f], 0, 0, 0);
      }
    }
    __syncthreads();
  }
  // C epilogue
#pragma unroll
  for (int m = 0; m < 2; ++m)
#pragma unroll
    for (int f = 0; f < NF; ++f)
#pragma unroll
      for (int r = 0; r < 4; ++r) {
        int row = row0 + wr * 32 + m * 16 + lg * 4 + r;
        if (row < n) {
          int col = wc * (BN / 2) + f * 16 + lm;
          Cb[(size_t)row * BN + col] = f2b(acc[m][f][r]);
        }
      }
  // fused attention-logit epilogue (BN=128: wave wc covers heads 2wc, 2wc+1)
  if constexpr (FUSE) {
#pragma unroll
    for (int hh = 0; hh < 2; ++hh) {
      const int head = 2 * wc + hh;
      float as0 = a_s[head * 32 + lm], as1 = a_s[head * 32 + 16 + lm];
      float ad0 = a_d[head * 32 + lm], ad1 = a_d[head * 32 + 16 + lm];
#pragma unroll
      for (int m = 0; m < 2; ++m)
#pragma unroll
        for (int r = 0; r < 4; ++r) {
          float tS = acc[m][2 * hh][r] * as0 + acc[m][2 * hh + 1][r] * as1;
          float tD = acc[m][2 * hh][r] * ad0 + acc[m][2 * hh + 1][r] * ad1;
#pragma unroll
          for (int off = 8; off >= 1; off >>= 1) {
            tS += __shfl_xor(tS, off);
            tD += __shfl_xor(tD, off);
          }
          if (lm == 0) {
            int row = row0 + wr * 32 + m * 16 + lg * 4 + r;
            if (row < n) {
              als[(size_t)row * 4 + head] = tS;
              ald[(size_t)row * 4 + head] = tD;
            }
          }
        }
    }
  }
}

// ---------- per-(node,head) attention logits from bf16 h (layer 3 only) ----------
template <int HH, int CC>
__global__ void compute_al(const ushort* __restrict__ hb, const float* __restrict__ a_s,
                           const float* __restrict__ a_d, float* __restrict__ als,
                           float* __restrict__ ald, int n) {
  int idx = blockIdx.x * TPB + threadIdx.x;
  if (idx >= n * HH) return;
  int node = idx / HH, h = idx - (idx / HH) * HH;
  const ushort* hp = hb + (size_t)node * (HH * CC) + h * CC;
  float s = 0.f, d = 0.f;
#pragma unroll
  for (int c8 = 0; c8 < CC; c8 += 8) {
    short8 v = *(const short8*)(hp + c8);
#pragma unroll
    for (int j = 0; j < 8; ++j) {
      float f = b2f((ushort)v[j]);
      s += f * a_s[h * CC + c8 + j];
      d += f * a_d[h * CC + c8 + j];
    }
  }
  als[idx] = s;
  ald[idx] = d;
}

// ---------- CSR build ----------
__global__ void zero_int(int* __restrict__ p, int n) {
  int i = blockIdx.x * TPB + threadIdx.x;
  if (i < n) p[i] = 0;
}

__global__ void hist_dst(const int* __restrict__ edst, int* __restrict__ counts,
                         int E0, int Et) {
  int e = blockIdx.x * TPB + threadIdx.x;
  if (e >= Et) return;
  int d = e < E0 ? edst[e] : e - E0;
  atomicAdd(&counts[d], 1);
}

__global__ void block_sums(const int* __restrict__ counts, int* __restrict__ bsum, int N) {
  __shared__ int sh[256];
  int t = threadIdx.x, idx = blockIdx.x * 256 + t;
  sh[t] = idx < N ? counts[idx] : 0;
  __syncthreads();
  for (int off = 128; off >= 1; off >>= 1) {
    if (t < off) sh[t] += sh[t + off];
    __syncthreads();
  }
  if (t == 0) bsum[blockIdx.x] = sh[0];
}

__global__ void scan_bsum(int* __restrict__ bsum, int nb) {
  __shared__ int sh[256];
  int t = threadIdx.x;
  int v = t < nb ? bsum[t] : 0;
  sh[t] = v;
  __syncthreads();
  for (int off = 1; off < 256; off <<= 1) {
    int u = (t >= off) ? sh[t - off] : 0;
    __syncthreads();
    sh[t] += u;
    __syncthreads();
  }
  if (t < nb) bsum[t] = sh[t] - v;  // exclusive
}

__global__ void scan_final(const int* __restrict__ counts, const int* __restrict__ bsum_ex,
                           int* __restrict__ offsets, int* __restrict__ cursor,
                           int N, int Et) {
  __shared__ int sh[256];
  int t = threadIdx.x, b = blockIdx.x;
  int idx = b * 256 + t;
  int v = (idx < N) ? counts[idx] : 0;
  sh[t] = v;
  __syncthreads();
  for (int off = 1; off < 256; off <<= 1) {
    int u = (t >= off) ? sh[t - off] : 0;
    __syncthreads();
    sh[t] += u;
    __syncthreads();
  }
  if (idx < N) {
    int o = bsum_ex[b] + sh[t] - v;
    offsets[idx] = o;
    cursor[idx] = o;
  }
  if (idx == 0) offsets[N] = Et;
}

__global__ void scatter_csr(const int* __restrict__ esrc, const int* __restrict__ edst,
                            int* __restrict__ cursor, int* __restrict__ csr_src,
                            int E0, int Et) {
  int e = blockIdx.x * TPB + threadIdx.x;
  if (e >= Et) return;
  int s = e < E0 ? esrc[e] : e - E0;
  int d = e < E0 ? edst[e] : e - E0;
  int pos = atomicAdd(&cursor[d], 1);
  csr_src[pos] = s;
}

// ---------- fused attention + bias + LayerNorm + ELU, one wave per dst node ----------
// Grouped gather: LPE = W/8 lanes per edge (each lane owns 8 channels via dwordx4),
// NEG = 64/LPE edges concurrently in flight (4 for W=128, 8 for W=64).
template <int HH, int CC>
__global__ __launch_bounds__(256) void fused_attn(
    const ushort* __restrict__ hb, const float* __restrict__ als,
    const float* __restrict__ ald, const int* __restrict__ offsets,
    const int* __restrict__ csr_src, const float* __restrict__ bias,
    const float* __restrict__ g, const float* __restrict__ be,
    ushort* __restrict__ xout, int n) {
  constexpr int W = HH * CC;        // 128 or 64
  constexpr int LPE = W / 8;        // 16 or 8 lanes per edge
  constexpr int NEG = 64 / LPE;     // 4 or 8 concurrent edges
  int wid = (int)((blockIdx.x * (size_t)blockDim.x + threadIdx.x) >> 6);
  int lane = threadIdx.x & 63;
  if (wid >= n) return;
  const int d = wid;
  const int begin = offsets[d], end = offsets[d + 1];
  const int deg = end - begin;

  const int grp = lane / LPE, sub = lane % LPE;
  const int c0 = sub * 8;
  const int hsel = sub >> 2;        // my head (HH=4)

  float aldv[HH];
  if constexpr (HH == 4) {
    float4 t = *(const float4*)(ald + (size_t)d * 4);
    aldv[0] = t.x; aldv[1] = t.y; aldv[2] = t.z; aldv[3] = t.w;
  } else {
    aldv[0] = ald[d];
  }

  auto sel4 = [&](float x0, float x1, float x2, float x3) {
    float lo = (hsel & 1) ? x1 : x0;
    float hi = (hsel & 1) ? x3 : x2;
    return (hsel & 2) ? hi : lo;
  };

  float acc[8] = {};

  if (deg <= 64) {
    // ---- logits: one lane per edge ----
    bool act = lane < deg;
    int s_e = act ? csr_src[begin + lane] : 0;
    float e0 = -1e30f, e1 = -1e30f, e2 = -1e30f, e3 = -1e30f;
    if constexpr (HH == 4) {
      if (act) {
        float4 t = *(const float4*)(als + (size_t)s_e * 4);
        e0 = t.x + aldv[0]; e0 = e0 > 0.f ? e0 : 0.2f * e0;
        e1 = t.y + aldv[1]; e1 = e1 > 0.f ? e1 : 0.2f * e1;
        e2 = t.z + aldv[2]; e2 = e2 > 0.f ? e2 : 0.2f * e2;
        e3 = t.w + aldv[3]; e3 = e3 > 0.f ? e3 : 0.2f * e3;
      }
    } else {
      if (act) {
        e0 = als[s_e] + aldv[0]; e0 = e0 > 0.f ? e0 : 0.2f * e0;
      }
    }
    float m0 = e0, m1 = e1, m2 = e2, m3 = e3;
#pragma unroll
    for (int off = 32; off >= 1; off >>= 1) {
      m0 = fmaxf(m0, __shfl_xor(m0, off));
      if constexpr (HH == 4) {
        m1 = fmaxf(m1, __shfl_xor(m1, off));
        m2 = fmaxf(m2, __shfl_xor(m2, off));
        m3 = fmaxf(m3, __shfl_xor(m3, off));
      }
    }
    float p0 = act ? __expf(e0 - m0) : 0.f;
    float p1 = 0.f, p2 = 0.f, p3 = 0.f;
    if constexpr (HH == 4) {
      p1 = act ? __expf(e1 - m1) : 0.f;
      p2 = act ? __expf(e2 - m2) : 0.f;
      p3 = act ? __expf(e3 - m3) : 0.f;
    }
    float s0 = p0, s1 = p1, s2 = p2, s3 = p3;
#pragma unroll
    for (int off = 32; off >= 1; off >>= 1) {
      s0 += __shfl_xor(s0, off);
      if constexpr (HH == 4) {
        s1 += __shfl_xor(s1, off);
        s2 += __shfl_xor(s2, off);
        s3 += __shfl_xor(s3, off);
      }
    }
    float a0 = p0 / (s0 + 1e-16f);
    float a1 = 0.f, a2 = 0.f, a3 = 0.f;
    if constexpr (HH == 4) {
      a1 = p1 / (s1 + 1e-16f);
      a2 = p2 / (s2 + 1e-16f);
      a3 = p3 / (s3 + 1e-16f);
    }

    // ---- grouped gather: NEG edges in flight, depth-2 pipeline ----
    int j = grp;
    int sj = __shfl(s_e, j < 64 ? j : 0);
    uint4v u = *(const uint4v*)(hb + (size_t)sj * W + c0);
    for (int j0 = 0; j0 < deg; j0 += NEG) {
      uint4v ucur = u;
      int jcur = j;
      j += NEG;
      if (j0 + NEG < deg) {
        int sn = __shfl(s_e, j < 64 ? j : 0);
        u = *(const uint4v*)(hb + (size_t)sn * W + c0);
      }
      int jc = jcur < 64 ? jcur : 0;
      float w;
      if constexpr (HH == 4) {
        float wa = __shfl(a0, jc), wb = __shfl(a1, jc), wcx = __shfl(a2, jc), wd = __shfl(a3, jc);
        w = sel4(wa, wb, wcx, wd);
      } else {
        w = __shfl(a0, jc);
      }
      if (jcur >= deg) w = 0.f;
#pragma unroll
      for (int i = 0; i < 4; ++i) {
        acc[2 * i]     = fmaf(w, blo(ucur[i]), acc[2 * i]);
        acc[2 * i + 1] = fmaf(w, bhi(ucur[i]), acc[2 * i + 1]);
      }
    }
  } else {
    // ---- slow path (deg > 64): strided logits + grouped gather w/ recompute ----
    float me[HH];
#pragma unroll
    for (int h = 0; h < HH; ++h) me[h] = -1e30f;
    for (int k = begin + lane; k < end; k += 64) {
      int s = csr_src[k];
      if constexpr (HH == 4) {
        float4 t = *(const float4*)(als + (size_t)s * 4);
        float e0 = t.x + aldv[0]; e0 = e0 > 0.f ? e0 : 0.2f * e0; me[0] = fmaxf(me[0], e0);
        float e1 = t.y + aldv[1]; e1 = e1 > 0.f ? e1 : 0.2f * e1; me[1] = fmaxf(me[1], e1);
        float e2 = t.z + aldv[2]; e2 = e2 > 0.f ? e2 : 0.2f * e2; me[2] = fmaxf(me[2], e2);
        float e3 = t.w + aldv[3]; e3 = e3 > 0.f ? e3 : 0.2f * e3; me[3] = fmaxf(me[3], e3);
      } else {
        float e0 = als[s] + aldv[0]; e0 = e0 > 0.f ? e0 : 0.2f * e0; me[0] = fmaxf(me[0], e0);
      }
    }
#pragma unroll
    for (int off = 32; off >= 1; off >>= 1)
#pragma unroll
      for (int h = 0; h < HH; ++h) me[h] = fmaxf(me[h], __shfl_xor(me[h], off));
    float se[HH];
#pragma unroll
    for (int h = 0; h < HH; ++h) se[h] = 0.f;
    for (int k = begin + lane; k < end; k += 64) {
      int s = csr_src[k];
      if constexpr (HH == 4) {
        float4 t = *(const float4*)(als + (size_t)s * 4);
        float e0 = t.x + aldv[0]; e0 = e0 > 0.f ? e0 : 0.2f * e0; se[0] += __expf(e0 - me[0]);
        float e1 = t.y + aldv[1]; e1 = e1 > 0.f ? e1 : 0.2f * e1; se[1] += __expf(e1 - me[1]);
        float e2 = t.z + aldv[2]; e2 = e2 > 0.f ? e2 : 0.2f * e2; se[2] += __expf(e2 - me[2]);
        float e3 = t.w + aldv[3]; e3 = e3 > 0.f ? e3 : 0.2f * e3; se[3] += __expf(e3 - me[3]);
      } else {
        float e0 = als[s] + aldv[0]; e0 = e0 > 0.f ? e0 : 0.2f * e0; se[0] += __expf(e0 - me[0]);
      }
    }
#pragma unroll
    for (int off = 32; off >= 1; off >>= 1)
#pragma unroll
      for (int h = 0; h < HH; ++h) se[h] += __shfl_xor(se[h], off);
    float inv[HH];
#pragma unroll
    for (int h = 0; h < HH; ++h) inv[h] = 1.f / (se[h] + 1e-16f);

    float m_my, i_my, ad_my;
    if constexpr (HH == 4) {
      m_my = sel4(me[0], me[1], me[2], me[3]);
      i_my = sel4(inv[0], inv[1], inv[2], inv[3]);
      ad_my = sel4(aldv[0], aldv[1], aldv[2], aldv[3]);
    } else {
      m_my = me[0]; i_my = inv[0]; ad_my = aldv[0];
    }
    for (int j0 = 0; j0 < deg; j0 += NEG) {
      int j = j0 + grp;
      if (j < deg) {
        int s = csr_src[begin + j];
        float as_my;
        if constexpr (HH == 4) {
          float4 t = *(const float4*)(als + (size_t)s * 4);
          as_my = sel4(t.x, t.y, t.z, t.w);
        } else {
          as_my = als[s];
        }
        float e = as_my + ad_my; e = e > 0.f ? e : 0.2f * e;
        float w = __expf(e - m_my) * i_my;
        uint4v u = *(const uint4v*)(hb + (size_t)s * W + c0);
#pragma unroll
        for (int i = 0; i < 4; ++i) {
          acc[2 * i]     = fmaf(w, blo(u[i]), acc[2 * i]);
          acc[2 * i + 1] = fmaf(w, bhi(u[i]), acc[2 * i + 1]);
        }
      }
    }
  }

  // ---- cross-group reduce: sum over edge groups ----
#pragma unroll
  for (int i = 0; i < 8; ++i) {
    if constexpr (HH == 1) acc[i] += __shfl_xor(acc[i], 8);
    acc[i] += __shfl_xor(acc[i], 16);
    acc[i] += __shfl_xor(acc[i], 32);
  }

  // ---- bias + LayerNorm + ELU on my 8 channels ----
  float4 bv0 = *(const float4*)(bias + c0);
  float4 bv1 = *(const float4*)(bias + c0 + 4);
  float v[8];
  v[0] = acc[0] + bv0.x; v[1] = acc[1] + bv0.y; v[2] = acc[2] + bv0.z; v[3] = acc[3] + bv0.w;
  v[4] = acc[4] + bv1.x; v[5] = acc[5] + bv1.y; v[6] = acc[6] + bv1.z; v[7] = acc[7] + bv1.w;
  float sm = 0.f, s2 = 0.f;
#pragma unroll
  for (int i = 0; i < 8; ++i) { sm += v[i]; s2 += v[i] * v[i]; }
  constexpr int TOPOFF = LPE / 2;  // 8 (W=128) or 4 (W=64)
#pragma unroll
  for (int off = TOPOFF; off >= 1; off >>= 1) {
    sm += __shfl_xor(sm, off);
    s2 += __shfl_xor(s2, off);
  }
  const float invW = 1.0f / W;
  float mu = sm * invW;
  float var = s2 * invW - mu * mu;
  float r = rsqrtf(var + 1e-5f);
  float4 gv0 = *(const float4*)(g + c0);
  float4 gv1 = *(const float4*)(g + c0 + 4);
  float4 be0 = *(const float4*)(be + c0);
  float4 be1 = *(const float4*)(be + c0 + 4);
  float gg[8] = {gv0.x, gv0.y, gv0.z, gv0.w, gv1.x, gv1.y, gv1.z, gv1.w};
  float bb[8] = {be0.x, be0.y, be0.z, be0.w, be1.x, be1.y, be1.z, be1.w};
  uint4v pk;
#pragma unroll
  for (int i = 0; i < 4; ++i) {
    float y0 = gg[2 * i] * (v[2 * i] - mu) * r + bb[2 * i];
    y0 = y0 > 0.f ? y0 : __expf(y0) - 1.f;
    float y1 = gg[2 * i + 1] * (v[2 * i + 1] - mu) * r + bb[2 * i + 1];
    y1 = y1 > 0.f ? y1 : __expf(y1) - 1.f;
    pk[i] = (uint)f2b(y0) | ((uint)f2b(y1) << 16);
  }
  if (grp == 0)
    *(uint4v*)(xout + (size_t)wid * W + c0) = pk;
}

// ---------- pooling over bf16 h3 ----------
__global__ void pool_partial(const ushort* __restrict__ h, float* __restrict__ psum,
                             float* __restrict__ pmax, int n) {
  int tid = threadIdx.x;
  float lsum = 0.f, lmax = -1e30f;
  for (size_t idx = (size_t)blockIdx.x * 256 + tid; idx < (size_t)n * 64;
       idx += (size_t)gridDim.x * 256) {
    float v = b2f(h[idx]);
    lsum += v;
    lmax = fmaxf(lmax, v);
  }
  __shared__ float ss[256], sm[256];
  ss[tid] = lsum; sm[tid] = lmax;
  __syncthreads();
  if (tid < 64) {
    float a = ss[tid] + ss[tid + 64] + ss[tid + 128] + ss[tid + 192];
    float m = fmaxf(fmaxf(sm[tid], sm[tid + 64]), fmaxf(sm[tid + 128], sm[tid + 192]));
    psum[blockIdx.x * 64 + tid] = a;
    pmax[blockIdx.x * 64 + tid] = m;
  }
}

// ---------- final reduce + classifier ----------
__global__ void pool_final(const float* __restrict__ psum, const float* __restrict__ pmax,
                           int nblocks, int n, const float* __restrict__ cW1,
                           const float* __restrict__ cb1, const float* __restrict__ cW2,
                           const float* __restrict__ cb2, float* __restrict__ out) {
  __shared__ float z[128];
  __shared__ float hid[128];
  int tid = threadIdx.x;
  if (tid < 64) {
    float s = 0.f, m = -1e30f;
    for (int b = 0; b < nblocks; ++b) {
      s += psum[b * 64 + tid];
      m = fmaxf(m, pmax[b * 64 + tid]);
    }
    z[tid] = s / (float)n;
    z[64 + tid] = m;
  }
  __syncthreads();
  float a = cb1[tid];
  for (int k = 0; k < 128; ++k) a += z[k] * cW1[k * 128 + tid];
  hid[tid] = fmaxf(a, 0.f);
  __syncthreads();
  if (tid < 2) {
    float o = cb2[tid];
    for (int j = 0; j < 128; ++j) o += hid[j] * cW2[j * 2 + tid];
    out[tid] = o;
  }
}

static inline int cdiv(long long a, long long b) { return (int)((a + b - 1) / b); }

extern "C" void kernel_launch(void* const* d_in, const int* in_sizes, int n_in,
                              void* d_out, int out_size, void* d_ws, size_t ws_size,
                              hipStream_t stream) {
  const float* x   = (const float*)d_in[0];
  const int*   ei  = (const int*)d_in[1];
  const float* W1  = (const float*)d_in[3];
  const float* as1 = (const float*)d_in[4];
  const float* ad1 = (const float*)d_in[5];
  const float* b1  = (const float*)d_in[6];
  const float* g1  = (const float*)d_in[7];
  const float* be1 = (const float*)d_in[8];
  const float* W2  = (const float*)d_in[9];
  const float* as2 = (const float*)d_in[10];
  const float* ad2 = (const float*)d_in[11];
  const float* b2  = (const float*)d_in[12];
  const float* g2  = (const float*)d_in[13];
  const float* be2 = (const float*)d_in[14];
  const float* W3  = (const float*)d_in[15];
  const float* as3 = (const float*)d_in[16];
  const float* ad3 = (const float*)d_in[17];
  const float* b3  = (const float*)d_in[18];
  const float* g3  = (const float*)d_in[19];
  const float* be3 = (const float*)d_in[20];
  const float* cW1 = (const float*)d_in[21];
  const float* cb1 = (const float*)d_in[22];
  const float* cW2 = (const float*)d_in[23];
  const float* cb2 = (const float*)d_in[24];
  float* out = (float*)d_out;

  const int N   = in_sizes[2];
  const int E0  = in_sizes[1] / 2;
  const int Et  = E0 + N;
  const int FIN = in_sizes[0] / N;

  float* ws = (float*)d_ws;
  size_t o = 0;
  ushort* Ab = (ushort*)(ws + o); o += (size_t)N * 64;   // N x 128 bf16 (h)
  ushort* Bb = (ushort*)(ws + o); o += (size_t)N * 64;   // N x 128 bf16 (x_l)
  float* als  = ws + o; o += (size_t)N * 4;
  float* ald  = ws + o; o += (size_t)N * 4;
  ushort* Wt1 = (ushort*)(ws + o); o += (128 * 512) / 2;
  ushort* Wt2 = (ushort*)(ws + o); o += (128 * 128) / 2;
  ushort* Wt3 = (ushort*)(ws + o); o += (64 * 128) / 2;
  float* psum = ws + o; o += 256 * 64;
  float* pmax = ws + o; o += 256 * 64;
  int* counts  = (int*)(ws + o); o += N + 1;
  int* offsets = (int*)(ws + o); o += N + 1;
  int* cursor  = (int*)(ws + o); o += N;
  int* bsum    = (int*)(ws + o); o += 256;
  int* csr_src = (int*)(ws + o); o += Et;

  const int* esrc = ei;
  const int* edst = ei + E0;
  const int NB = cdiv(N, 256);

  // ===== weight prep =====
  prep_wt<<<cdiv((long long)FIN * 128, TPB), TPB, 0, stream>>>(W1, Wt1, FIN, 128);
  prep_wt<<<cdiv((long long)128 * 128, TPB), TPB, 0, stream>>>(W2, Wt2, 128, 128);
  prep_wt<<<cdiv((long long)128 * 64, TPB), TPB, 0, stream>>>(W3, Wt3, 128, 64);

  // ===== CSR build (once, reused by all 3 layers) =====
  zero_int<<<cdiv(N + 1, TPB), TPB, 0, stream>>>(counts, N + 1);
  hist_dst<<<cdiv(Et, TPB), TPB, 0, stream>>>(edst, counts, E0, Et);
  block_sums<<<NB, 256, 0, stream>>>(counts, bsum, N);
  scan_bsum<<<1, 256, 0, stream>>>(bsum, NB);
  scan_final<<<NB, 256, 0, stream>>>(counts, bsum, offsets, cursor, N, Et);
  scatter_csr<<<cdiv(Et, TPB), TPB, 0, stream>>>(esrc, edst, cursor, csr_src, E0, Et);

  // ===== Layer 1: x[N,512] fp32 -> h(Ab)+al -> x1(Bb) =====
  gemm_mfma<0, 128, true><<<cdiv(N, 64), 256, 0, stream>>>(x, Wt1, Ab, N, FIN, as1, ad1, als, ald);
  fused_attn<4, 32><<<cdiv(N, 4), 256, 0, stream>>>(Ab, als, ald, offsets, csr_src, b1, g1, be1, Bb, N);
  // ===== Layer 2: x1(Bb) -> h(Ab)+al -> x2(Bb) =====
  gemm_mfma<1, 128, true><<<cdiv(N, 64), 256, 0, stream>>>(Bb, Wt2, Ab, N, 128, as2, ad2, als, ald);
  fused_attn<4, 32><<<cdiv(N, 4), 256, 0, stream>>>(Ab, als, ald, offsets, csr_src, b2, g2, be2, Bb, N);
  // ===== Layer 3: x2(Bb) -> h[N,64](Ab) -> x3(Bb) =====
  gemm_mfma<1, 64, false><<<cdiv(N, 64), 256, 0, stream>>>(Bb, Wt3, Ab, N, 128, nullptr, nullptr, nullptr, nullptr);
  compute_al<1, 64><<<cdiv((long long)N, TPB), TPB, 0, stream>>>(Ab, as3, ad3, als, ald, N);
  fused_attn<1, 64><<<cdiv(N, 4), 256, 0, stream>>>(Ab, als, ald, offsets, csr_src, b3, g3, be3, Bb, N);
  // ===== Pool + classifier =====
  pool_partial<<<256, 256, 0, stream>>>(Bb, psum, pmax, N);
  pool_final<<<1, 128, 0, stream>>>(psum, pmax, 256, N, cW1, cb1, cW2, cb2, out);
}

// Round 6
// 350.101 us; speedup vs baseline: 3.6662x; 1.0547x over previous
//
#include <hip/hip_runtime.h>
#include <cmath>

static constexpr int TPB = 256;

using short8 = __attribute__((ext_vector_type(8))) short;
using f32x4  = __attribute__((ext_vector_type(4))) float;
using uint4v = __attribute__((ext_vector_type(4))) unsigned int;
typedef unsigned short ushort;
typedef unsigned int uint;

__device__ __forceinline__ ushort f2b(float f) {
  unsigned x = __builtin_bit_cast(unsigned, f);
  unsigned r = (x + 0x7fffu + ((x >> 16) & 1u)) >> 16;   // RNE
  return (ushort)r;
}
__device__ __forceinline__ float b2f(ushort u) {
  unsigned v = ((unsigned)u) << 16;
  return __builtin_bit_cast(float, v);
}
__device__ __forceinline__ float blo(uint u) { return __builtin_bit_cast(float, u << 16); }
__device__ __forceinline__ float bhi(uint u) { return __builtin_bit_cast(float, u & 0xffff0000u); }

// ---------- W [K][Nc] fp32 -> Wt [Nc][K] bf16 ----------
__global__ void prep_wt(const float* __restrict__ W, ushort* __restrict__ Wt, int K, int Nc) {
  int idx = blockIdx.x * TPB + threadIdx.x;
  if (idx >= K * Nc) return;
  int nc = idx / K, k = idx - nc * K;
  Wt[idx] = f2b(W[(size_t)k * Nc + nc]);
}

// ---------- MFMA GEMM: C[n,BN](bf16) = A[n,K] @ W[K,BN], Wt pre-transposed ----------
// BM=64, BN=Nc (64 or 128), BK=64, 256 threads = 4 waves (2 row x 2 col)
// Each wave: 32 rows x BN/2 cols. FUSE (BN=128): emit als/ald per (row, head).
template <int ABF16, int BN, bool FUSE>
__global__ __launch_bounds__(256) void gemm_mfma(const void* __restrict__ Ap,
                                                 const ushort* __restrict__ Wt,
                                                 ushort* __restrict__ Cb,
                                                 int n, int K,
                                                 const float* __restrict__ a_s,
                                                 const float* __restrict__ a_d,
                                                 float* __restrict__ als,
                                                 float* __restrict__ ald) {
  constexpr int NF = BN / 32;  // col frags per wave (4 or 2)
  __shared__ short As[64 * 72];
  __shared__ short Bs[BN * 72];
  const int tid = threadIdx.x;
  const int row0 = blockIdx.x * 64;
  const int srow = tid >> 2, sks = (tid & 3) << 4;  // A staging
  const int wave = tid >> 6, lane = tid & 63;
  const int wr = wave >> 1, wc = wave & 1;
  const int lm = lane & 15, lg = lane >> 4;

  f32x4 acc[2][NF] = {};

  for (int k0 = 0; k0 < K; k0 += 64) {
    // ---- stage A tile ----
    {
      int gr = row0 + srow;
      short8 v0 = {0, 0, 0, 0, 0, 0, 0, 0}, v1 = v0;
      if constexpr (ABF16 == 0) {
        const float* A = (const float*)Ap;
        if (gr < n) {
          const float* p = A + (size_t)gr * K + k0 + sks;
          float4 f0 = *(const float4*)(p + 0);
          float4 f1 = *(const float4*)(p + 4);
          float4 f2 = *(const float4*)(p + 8);
          float4 f3 = *(const float4*)(p + 12);
          v0[0] = (short)f2b(f0.x); v0[1] = (short)f2b(f0.y); v0[2] = (short)f2b(f0.z); v0[3] = (short)f2b(f0.w);
          v0[4] = (short)f2b(f1.x); v0[5] = (short)f2b(f1.y); v0[6] = (short)f2b(f1.z); v0[7] = (short)f2b(f1.w);
          v1[0] = (short)f2b(f2.x); v1[1] = (short)f2b(f2.y); v1[2] = (short)f2b(f2.z); v1[3] = (short)f2b(f2.w);
          v1[4] = (short)f2b(f3.x); v1[5] = (short)f2b(f3.y); v1[6] = (short)f2b(f3.z); v1[7] = (short)f2b(f3.w);
        }
      } else {
        const ushort* A = (const ushort*)Ap;
        if (gr < n) {
          const ushort* p = A + (size_t)gr * K + k0 + sks;
          v0 = *(const short8*)(p + 0);
          v1 = *(const short8*)(p + 8);
        }
      }
      *(short8*)&As[srow * 72 + sks + 0] = v0;
      *(short8*)&As[srow * 72 + sks + 8] = v1;
    }
    // ---- stage B tile from Wt [BN][K] ----
    if constexpr (BN == 128) {
      const int brow = tid >> 1, bks = (tid & 1) << 5;
      const ushort* wp = Wt + (size_t)brow * K + k0 + bks;
      *(short8*)&Bs[brow * 72 + bks + 0]  = *(const short8*)(wp + 0);
      *(short8*)&Bs[brow * 72 + bks + 8]  = *(const short8*)(wp + 8);
      *(short8*)&Bs[brow * 72 + bks + 16] = *(const short8*)(wp + 16);
      *(short8*)&Bs[brow * 72 + bks + 24] = *(const short8*)(wp + 24);
    } else {
      const ushort* wp = Wt + (size_t)srow * K + k0 + sks;
      *(short8*)&Bs[srow * 72 + sks + 0] = *(const short8*)(wp + 0);
      *(short8*)&Bs[srow * 72 + sks + 8] = *(const short8*)(wp + 8);
    }
    __syncthreads();
#pragma unroll
    for (int kk = 0; kk < 64; kk += 32) {
      short8 a0 = *(const short8*)&As[(wr * 32 + lm) * 72 + kk + lg * 8];
      short8 a1 = *(const short8*)&As[(wr * 32 + 16 + lm) * 72 + kk + lg * 8];
      short8 bf[NF];
#pragma unroll
      for (int f = 0; f < NF; ++f)
        bf[f] = *(const short8*)&Bs[(wc * (BN / 2) + f * 16 + lm) * 72 + kk + lg * 8];
#pragma unroll
      for (int f = 0; f < NF; ++f) {
        acc[0][f] = __builtin_amdgcn_mfma_f32_16x16x32_bf16(a0, bf[f], acc[0][f], 0, 0, 0);
        acc[1][f] = __builtin_amdgcn_mfma_f32_16x16x32_bf16(a1, bf[f], acc[1][f], 0, 0, 0);
      }
    }
    __syncthreads();
  }
  // C epilogue
#pragma unroll
  for (int m = 0; m < 2; ++m)
#pragma unroll
    for (int f = 0; f < NF; ++f)
#pragma unroll
      for (int r = 0; r < 4; ++r) {
        int row = row0 + wr * 32 + m * 16 + lg * 4 + r;
        if (row < n) {
          int col = wc * (BN / 2) + f * 16 + lm;
          Cb[(size_t)row * BN + col] = f2b(acc[m][f][r]);
        }
      }
  // fused attention-logit epilogue (BN=128: wave wc covers heads 2wc, 2wc+1)
  if constexpr (FUSE) {
#pragma unroll
    for (int hh = 0; hh < 2; ++hh) {
      const int head = 2 * wc + hh;
      float as0 = a_s[head * 32 + lm], as1 = a_s[head * 32 + 16 + lm];
      float ad0 = a_d[head * 32 + lm], ad1 = a_d[head * 32 + 16 + lm];
#pragma unroll
      for (int m = 0; m < 2; ++m)
#pragma unroll
        for (int r = 0; r < 4; ++r) {
          float tS = acc[m][2 * hh][r] * as0 + acc[m][2 * hh + 1][r] * as1;
          float tD = acc[m][2 * hh][r] * ad0 + acc[m][2 * hh + 1][r] * ad1;
#pragma unroll
          for (int off = 8; off >= 1; off >>= 1) {
            tS += __shfl_xor(tS, off);
            tD += __shfl_xor(tD, off);
          }
          if (lm == 0) {
            int row = row0 + wr * 32 + m * 16 + lg * 4 + r;
            if (row < n) {
              als[(size_t)row * 4 + head] = tS;
              ald[(size_t)row * 4 + head] = tD;
            }
          }
        }
    }
  }
}

// ---------- per-(node,head) attention logits from bf16 h (layer 3 only) ----------
template <int HH, int CC>
__global__ void compute_al(const ushort* __restrict__ hb, const float* __restrict__ a_s,
                           const float* __restrict__ a_d, float* __restrict__ als,
                           float* __restrict__ ald, int n) {
  int idx = blockIdx.x * TPB + threadIdx.x;
  if (idx >= n * HH) return;
  int node = idx / HH, h = idx - (idx / HH) * HH;
  const ushort* hp = hb + (size_t)node * (HH * CC) + h * CC;
  float s = 0.f, d = 0.f;
#pragma unroll
  for (int c8 = 0; c8 < CC; c8 += 8) {
    short8 v = *(const short8*)(hp + c8);
#pragma unroll
    for (int j = 0; j < 8; ++j) {
      float f = b2f((ushort)v[j]);
      s += f * a_s[h * CC + c8 + j];
      d += f * a_d[h * CC + c8 + j];
    }
  }
  als[idx] = s;
  ald[idx] = d;
}

// ---------- CSR build ----------
__global__ void zero_int(int* __restrict__ p, int n) {
  int i = blockIdx.x * TPB + threadIdx.x;
  if (i < n) p[i] = 0;
}

__global__ void hist_dst(const int* __restrict__ edst, int* __restrict__ counts,
                         int E0, int Et) {
  int e = blockIdx.x * TPB + threadIdx.x;
  if (e >= Et) return;
  int d = e < E0 ? edst[e] : e - E0;
  atomicAdd(&counts[d], 1);
}

__global__ void block_sums(const int* __restrict__ counts, int* __restrict__ bsum, int N) {
  __shared__ int sh[256];
  int t = threadIdx.x, idx = blockIdx.x * 256 + t;
  sh[t] = idx < N ? counts[idx] : 0;
  __syncthreads();
  for (int off = 128; off >= 1; off >>= 1) {
    if (t < off) sh[t] += sh[t + off];
    __syncthreads();
  }
  if (t == 0) bsum[blockIdx.x] = sh[0];
}

__global__ void scan_bsum(int* __restrict__ bsum, int nb) {
  __shared__ int sh[256];
  int t = threadIdx.x;
  int v = t < nb ? bsum[t] : 0;
  sh[t] = v;
  __syncthreads();
  for (int off = 1; off < 256; off <<= 1) {
    int u = (t >= off) ? sh[t - off] : 0;
    __syncthreads();
    sh[t] += u;
    __syncthreads();
  }
  if (t < nb) bsum[t] = sh[t] - v;  // exclusive
}

__global__ void scan_final(const int* __restrict__ counts, const int* __restrict__ bsum_ex,
                           int* __restrict__ offsets, int* __restrict__ cursor,
                           int N, int Et) {
  __shared__ int sh[256];
  int t = threadIdx.x, b = blockIdx.x;
  int idx = b * 256 + t;
  int v = (idx < N) ? counts[idx] : 0;
  sh[t] = v;
  __syncthreads();
  for (int off = 1; off < 256; off <<= 1) {
    int u = (t >= off) ? sh[t - off] : 0;
    __syncthreads();
    sh[t] += u;
    __syncthreads();
  }
  if (idx < N) {
    int o = bsum_ex[b] + sh[t] - v;
    offsets[idx] = o;
    cursor[idx] = o;
  }
  if (idx == 0) offsets[N] = Et;
}

__global__ void scatter_csr(const int* __restrict__ esrc, const int* __restrict__ edst,
                            int* __restrict__ cursor, int* __restrict__ csr_src,
                            int E0, int Et) {
  int e = blockIdx.x * TPB + threadIdx.x;
  if (e >= Et) return;
  int s = e < E0 ? esrc[e] : e - E0;
  int d = e < E0 ? edst[e] : e - E0;
  int pos = atomicAdd(&cursor[d], 1);
  csr_src[pos] = s;
}

// ---------- fused attention + bias + LayerNorm + ELU, one wave per dst node ----------
// Grouped gather: LPE = W/8 lanes per edge (each lane owns 8 channels via dwordx4),
// NEG = 64/LPE edges concurrently in flight (4 for W=128, 8 for W=64).
template <int HH, int CC>
__global__ __launch_bounds__(256) void fused_attn(
    const ushort* __restrict__ hb, const float* __restrict__ als,
    const float* __restrict__ ald, const int* __restrict__ offsets,
    const int* __restrict__ csr_src, const float* __restrict__ bias,
    const float* __restrict__ g, const float* __restrict__ be,
    ushort* __restrict__ xout, int n) {
  constexpr int W = HH * CC;        // 128 or 64
  constexpr int LPE = W / 8;        // 16 or 8 lanes per edge
  constexpr int NEG = 64 / LPE;     // 4 or 8 concurrent edges
  int wid = (int)((blockIdx.x * (size_t)blockDim.x + threadIdx.x) >> 6);
  int lane = threadIdx.x & 63;
  if (wid >= n) return;
  const int d = wid;
  const int begin = offsets[d], end = offsets[d + 1];
  const int deg = end - begin;

  const int grp = lane / LPE, sub = lane % LPE;
  const int c0 = sub * 8;
  const int hsel = sub >> 2;        // my head (HH=4)

  float aldv[HH];
  if constexpr (HH == 4) {
    float4 t = *(const float4*)(ald + (size_t)d * 4);
    aldv[0] = t.x; aldv[1] = t.y; aldv[2] = t.z; aldv[3] = t.w;
  } else {
    aldv[0] = ald[d];
  }

  auto sel4 = [&](float x0, float x1, float x2, float x3) {
    float lo = (hsel & 1) ? x1 : x0;
    float hi = (hsel & 1) ? x3 : x2;
    return (hsel & 2) ? hi : lo;
  };

  float acc[8] = {};

  if (deg <= 64) {
    // ---- logits: one lane per edge ----
    bool act = lane < deg;
    int s_e = act ? csr_src[begin + lane] : 0;
    float e0 = -1e30f, e1 = -1e30f, e2 = -1e30f, e3 = -1e30f;
    if constexpr (HH == 4) {
      if (act) {
        float4 t = *(const float4*)(als + (size_t)s_e * 4);
        e0 = t.x + aldv[0]; e0 = e0 > 0.f ? e0 : 0.2f * e0;
        e1 = t.y + aldv[1]; e1 = e1 > 0.f ? e1 : 0.2f * e1;
        e2 = t.z + aldv[2]; e2 = e2 > 0.f ? e2 : 0.2f * e2;
        e3 = t.w + aldv[3]; e3 = e3 > 0.f ? e3 : 0.2f * e3;
      }
    } else {
      if (act) {
        e0 = als[s_e] + aldv[0]; e0 = e0 > 0.f ? e0 : 0.2f * e0;
      }
    }
    float m0 = e0, m1 = e1, m2 = e2, m3 = e3;
#pragma unroll
    for (int off = 32; off >= 1; off >>= 1) {
      m0 = fmaxf(m0, __shfl_xor(m0, off));
      if constexpr (HH == 4) {
        m1 = fmaxf(m1, __shfl_xor(m1, off));
        m2 = fmaxf(m2, __shfl_xor(m2, off));
        m3 = fmaxf(m3, __shfl_xor(m3, off));
      }
    }
    float p0 = act ? __expf(e0 - m0) : 0.f;
    float p1 = 0.f, p2 = 0.f, p3 = 0.f;
    if constexpr (HH == 4) {
      p1 = act ? __expf(e1 - m1) : 0.f;
      p2 = act ? __expf(e2 - m2) : 0.f;
      p3 = act ? __expf(e3 - m3) : 0.f;
    }
    float s0 = p0, s1 = p1, s2 = p2, s3 = p3;
#pragma unroll
    for (int off = 32; off >= 1; off >>= 1) {
      s0 += __shfl_xor(s0, off);
      if constexpr (HH == 4) {
        s1 += __shfl_xor(s1, off);
        s2 += __shfl_xor(s2, off);
        s3 += __shfl_xor(s3, off);
      }
    }
    float a0 = p0 / (s0 + 1e-16f);
    float a1 = 0.f, a2 = 0.f, a3 = 0.f;
    if constexpr (HH == 4) {
      a1 = p1 / (s1 + 1e-16f);
      a2 = p2 / (s2 + 1e-16f);
      a3 = p3 / (s3 + 1e-16f);
    }

    // ---- grouped gather: NEG edges in flight, depth-2 pipeline ----
    int j = grp;
    int sj = __shfl(s_e, j < 64 ? j : 0);
    uint4v u = *(const uint4v*)(hb + (size_t)sj * W + c0);
    for (int j0 = 0; j0 < deg; j0 += NEG) {
      uint4v ucur = u;
      int jcur = j;
      j += NEG;
      if (j0 + NEG < deg) {
        int sn = __shfl(s_e, j < 64 ? j : 0);
        u = *(const uint4v*)(hb + (size_t)sn * W + c0);
      }
      int jc = jcur < 64 ? jcur : 0;
      float w;
      if constexpr (HH == 4) {
        float wa = __shfl(a0, jc), wb = __shfl(a1, jc), wcx = __shfl(a2, jc), wd = __shfl(a3, jc);
        w = sel4(wa, wb, wcx, wd);
      } else {
        w = __shfl(a0, jc);
      }
      if (jcur >= deg) w = 0.f;
#pragma unroll
      for (int i = 0; i < 4; ++i) {
        acc[2 * i]     = fmaf(w, blo(ucur[i]), acc[2 * i]);
        acc[2 * i + 1] = fmaf(w, bhi(ucur[i]), acc[2 * i + 1]);
      }
    }
  } else {
    // ---- slow path (deg > 64): strided logits + grouped gather w/ recompute ----
    float me[HH];
#pragma unroll
    for (int h = 0; h < HH; ++h) me[h] = -1e30f;
    for (int k = begin + lane; k < end; k += 64) {
      int s = csr_src[k];
      if constexpr (HH == 4) {
        float4 t = *(const float4*)(als + (size_t)s * 4);
        float e0 = t.x + aldv[0]; e0 = e0 > 0.f ? e0 : 0.2f * e0; me[0] = fmaxf(me[0], e0);
        float e1 = t.y + aldv[1]; e1 = e1 > 0.f ? e1 : 0.2f * e1; me[1] = fmaxf(me[1], e1);
        float e2 = t.z + aldv[2]; e2 = e2 > 0.f ? e2 : 0.2f * e2; me[2] = fmaxf(me[2], e2);
        float e3 = t.w + aldv[3]; e3 = e3 > 0.f ? e3 : 0.2f * e3; me[3] = fmaxf(me[3], e3);
      } else {
        float e0 = als[s] + aldv[0]; e0 = e0 > 0.f ? e0 : 0.2f * e0; me[0] = fmaxf(me[0], e0);
      }
    }
#pragma unroll
    for (int off = 32; off >= 1; off >>= 1)
#pragma unroll
      for (int h = 0; h < HH; ++h) me[h] = fmaxf(me[h], __shfl_xor(me[h], off));
    float se[HH];
#pragma unroll
    for (int h = 0; h < HH; ++h) se[h] = 0.f;
    for (int k = begin + lane; k < end; k += 64) {
      int s = csr_src[k];
      if constexpr (HH == 4) {
        float4 t = *(const float4*)(als + (size_t)s * 4);
        float e0 = t.x + aldv[0]; e0 = e0 > 0.f ? e0 : 0.2f * e0; se[0] += __expf(e0 - me[0]);
        float e1 = t.y + aldv[1]; e1 = e1 > 0.f ? e1 : 0.2f * e1; se[1] += __expf(e1 - me[1]);
        float e2 = t.z + aldv[2]; e2 = e2 > 0.f ? e2 : 0.2f * e2; se[2] += __expf(e2 - me[2]);
        float e3 = t.w + aldv[3]; e3 = e3 > 0.f ? e3 : 0.2f * e3; se[3] += __expf(e3 - me[3]);
      } else {
        float e0 = als[s] + aldv[0]; e0 = e0 > 0.f ? e0 : 0.2f * e0; se[0] += __expf(e0 - me[0]);
      }
    }
#pragma unroll
    for (int off = 32; off >= 1; off >>= 1)
#pragma unroll
      for (int h = 0; h < HH; ++h) se[h] += __shfl_xor(se[h], off);
    float inv[HH];
#pragma unroll
    for (int h = 0; h < HH; ++h) inv[h] = 1.f / (se[h] + 1e-16f);

    float m_my, i_my, ad_my;
    if constexpr (HH == 4) {
      m_my = sel4(me[0], me[1], me[2], me[3]);
      i_my = sel4(inv[0], inv[1], inv[2], inv[3]);
      ad_my = sel4(aldv[0], aldv[1], aldv[2], aldv[3]);
    } else {
      m_my = me[0]; i_my = inv[0]; ad_my = aldv[0];
    }
    for (int j0 = 0; j0 < deg; j0 += NEG) {
      int j = j0 + grp;
      if (j < deg) {
        int s = csr_src[begin + j];
        float as_my;
        if constexpr (HH == 4) {
          float4 t = *(const float4*)(als + (size_t)s * 4);
          as_my = sel4(t.x, t.y, t.z, t.w);
        } else {
          as_my = als[s];
        }
        float e = as_my + ad_my; e = e > 0.f ? e : 0.2f * e;
        float w = __expf(e - m_my) * i_my;
        uint4v u = *(const uint4v*)(hb + (size_t)s * W + c0);
#pragma unroll
        for (int i = 0; i < 4; ++i) {
          acc[2 * i]     = fmaf(w, blo(u[i]), acc[2 * i]);
          acc[2 * i + 1] = fmaf(w, bhi(u[i]), acc[2 * i + 1]);
        }
      }
    }
  }

  // ---- cross-group reduce: sum over edge groups ----
#pragma unroll
  for (int i = 0; i < 8; ++i) {
    if constexpr (HH == 1) acc[i] += __shfl_xor(acc[i], 8);
    acc[i] += __shfl_xor(acc[i], 16);
    acc[i] += __shfl_xor(acc[i], 32);
  }

  // ---- bias + LayerNorm + ELU on my 8 channels ----
  float4 bv0 = *(const float4*)(bias + c0);
  float4 bv1 = *(const float4*)(bias + c0 + 4);
  float v[8];
  v[0] = acc[0] + bv0.x; v[1] = acc[1] + bv0.y; v[2] = acc[2] + bv0.z; v[3] = acc[3] + bv0.w;
  v[4] = acc[4] + bv1.x; v[5] = acc[5] + bv1.y; v[6] = acc[6] + bv1.z; v[7] = acc[7] + bv1.w;
  float sm = 0.f, s2 = 0.f;
#pragma unroll
  for (int i = 0; i < 8; ++i) { sm += v[i]; s2 += v[i] * v[i]; }
  constexpr int TOPOFF = LPE / 2;  // 8 (W=128) or 4 (W=64)
#pragma unroll
  for (int off = TOPOFF; off >= 1; off >>= 1) {
    sm += __shfl_xor(sm, off);
    s2 += __shfl_xor(s2, off);
  }
  const float invW = 1.0f / W;
  float mu = sm * invW;
  float var = s2 * invW - mu * mu;
  float r = rsqrtf(var + 1e-5f);
  float4 gv0 = *(const float4*)(g + c0);
  float4 gv1 = *(const float4*)(g + c0 + 4);
  float4 be0 = *(const float4*)(be + c0);
  float4 be1 = *(const float4*)(be + c0 + 4);
  float gg[8] = {gv0.x, gv0.y, gv0.z, gv0.w, gv1.x, gv1.y, gv1.z, gv1.w};
  float bb[8] = {be0.x, be0.y, be0.z, be0.w, be1.x, be1.y, be1.z, be1.w};
  uint4v pk;
#pragma unroll
  for (int i = 0; i < 4; ++i) {
    float y0 = gg[2 * i] * (v[2 * i] - mu) * r + bb[2 * i];
    y0 = y0 > 0.f ? y0 : __expf(y0) - 1.f;
    float y1 = gg[2 * i + 1] * (v[2 * i + 1] - mu) * r + bb[2 * i + 1];
    y1 = y1 > 0.f ? y1 : __expf(y1) - 1.f;
    pk[i] = (uint)f2b(y0) | ((uint)f2b(y1) << 16);
  }
  if (grp == 0)
    *(uint4v*)(xout + (size_t)wid * W + c0) = pk;
}

// ---------- pooling over bf16 h3 (64 partial blocks) ----------
__global__ void pool_partial(const ushort* __restrict__ h, float* __restrict__ psum,
                             float* __restrict__ pmax, int n) {
  int tid = threadIdx.x;
  float lsum = 0.f, lmax = -1e30f;
  for (size_t idx = (size_t)blockIdx.x * 256 + tid; idx < (size_t)n * 64;
       idx += (size_t)gridDim.x * 256) {
    float v = b2f(h[idx]);
    lsum += v;
    lmax = fmaxf(lmax, v);
  }
  __shared__ float ss[256], sm[256];
  ss[tid] = lsum; sm[tid] = lmax;
  __syncthreads();
  if (tid < 64) {
    float a = ss[tid] + ss[tid + 64] + ss[tid + 128] + ss[tid + 192];
    float m = fmaxf(fmaxf(sm[tid], sm[tid + 64]), fmaxf(sm[tid + 128], sm[tid + 192]));
    psum[blockIdx.x * 64 + tid] = a;
    pmax[blockIdx.x * 64 + tid] = m;
  }
}

// ---------- parallel final reduce + classifier (256 threads, 1 block) ----------
// 4 threads per channel; each handles 16 of the 64 partial blocks with
// independent (pipelined) loads, then LDS cross-group reduce.
__global__ __launch_bounds__(256) void pool_final(
    const float* __restrict__ psum, const float* __restrict__ pmax,
    int nblocks, int n, const float* __restrict__ cW1,
    const float* __restrict__ cb1, const float* __restrict__ cW2,
    const float* __restrict__ cb2, float* __restrict__ out) {
  __shared__ float sred[4][64], mred[4][64];
  __shared__ float z[128];
  __shared__ float hid[128];
  int tid = threadIdx.x;
  int c = tid & 63, q = tid >> 6;  // q in 0..3
  float s = 0.f, m = -1e30f;
  for (int b = q; b < nblocks; b += 4) {
    s += psum[b * 64 + c];
    m = fmaxf(m, pmax[b * 64 + c]);
  }
  sred[q][c] = s; mred[q][c] = m;
  __syncthreads();
  if (q == 0) {
    float st = sred[0][c] + sred[1][c] + sred[2][c] + sred[3][c];
    float mt = fmaxf(fmaxf(mred[0][c], mred[1][c]), fmaxf(mred[2][c], mred[3][c]));
    z[c] = st / (float)n;
    z[64 + c] = mt;
  }
  __syncthreads();
  if (tid < 128) {
    float a = cb1[tid];
#pragma unroll 4
    for (int k = 0; k < 128; ++k) a += z[k] * cW1[k * 128 + tid];
    hid[tid] = fmaxf(a, 0.f);
  }
  __syncthreads();
  if (tid < 2) {
    float o = cb2[tid];
    for (int j = 0; j < 128; ++j) o += hid[j] * cW2[j * 2 + tid];
    out[tid] = o;
  }
}

static inline int cdiv(long long a, long long b) { return (int)((a + b - 1) / b); }

extern "C" void kernel_launch(void* const* d_in, const int* in_sizes, int n_in,
                              void* d_out, int out_size, void* d_ws, size_t ws_size,
                              hipStream_t stream) {
  const float* x   = (const float*)d_in[0];
  const int*   ei  = (const int*)d_in[1];
  const float* W1  = (const float*)d_in[3];
  const float* as1 = (const float*)d_in[4];
  const float* ad1 = (const float*)d_in[5];
  const float* b1  = (const float*)d_in[6];
  const float* g1  = (const float*)d_in[7];
  const float* be1 = (const float*)d_in[8];
  const float* W2  = (const float*)d_in[9];
  const float* as2 = (const float*)d_in[10];
  const float* ad2 = (const float*)d_in[11];
  const float* b2  = (const float*)d_in[12];
  const float* g2  = (const float*)d_in[13];
  const float* be2 = (const float*)d_in[14];
  const float* W3  = (const float*)d_in[15];
  const float* as3 = (const float*)d_in[16];
  const float* ad3 = (const float*)d_in[17];
  const float* b3  = (const float*)d_in[18];
  const float* g3  = (const float*)d_in[19];
  const float* be3 = (const float*)d_in[20];
  const float* cW1 = (const float*)d_in[21];
  const float* cb1 = (const float*)d_in[22];
  const float* cW2 = (const float*)d_in[23];
  const float* cb2 = (const float*)d_in[24];
  float* out = (float*)d_out;

  const int N   = in_sizes[2];
  const int E0  = in_sizes[1] / 2;
  const int Et  = E0 + N;
  const int FIN = in_sizes[0] / N;

  float* ws = (float*)d_ws;
  size_t o = 0;
  ushort* Ab = (ushort*)(ws + o); o += (size_t)N * 64;   // N x 128 bf16 (h)
  ushort* Bb = (ushort*)(ws + o); o += (size_t)N * 64;   // N x 128 bf16 (x_l)
  float* als  = ws + o; o += (size_t)N * 4;
  float* ald  = ws + o; o += (size_t)N * 4;
  ushort* Wt1 = (ushort*)(ws + o); o += (128 * 512) / 2;
  ushort* Wt2 = (ushort*)(ws + o); o += (128 * 128) / 2;
  ushort* Wt3 = (ushort*)(ws + o); o += (64 * 128) / 2;
  float* psum = ws + o; o += 64 * 64;
  float* pmax = ws + o; o += 64 * 64;
  int* counts  = (int*)(ws + o); o += N + 1;
  int* offsets = (int*)(ws + o); o += N + 1;
  int* cursor  = (int*)(ws + o); o += N;
  int* bsum    = (int*)(ws + o); o += 256;
  int* csr_src = (int*)(ws + o); o += Et;

  const int* esrc = ei;
  const int* edst = ei + E0;
  const int NB = cdiv(N, 256);

  // ===== weight prep =====
  prep_wt<<<cdiv((long long)FIN * 128, TPB), TPB, 0, stream>>>(W1, Wt1, FIN, 128);
  prep_wt<<<cdiv((long long)128 * 128, TPB), TPB, 0, stream>>>(W2, Wt2, 128, 128);
  prep_wt<<<cdiv((long long)128 * 64, TPB), TPB, 0, stream>>>(W3, Wt3, 128, 64);

  // ===== CSR build (once, reused by all 3 layers) =====
  zero_int<<<cdiv(N + 1, TPB), TPB, 0, stream>>>(counts, N + 1);
  hist_dst<<<cdiv(Et, TPB), TPB, 0, stream>>>(edst, counts, E0, Et);
  block_sums<<<NB, 256, 0, stream>>>(counts, bsum, N);
  scan_bsum<<<1, 256, 0, stream>>>(bsum, NB);
  scan_final<<<NB, 256, 0, stream>>>(counts, bsum, offsets, cursor, N, Et);
  scatter_csr<<<cdiv(Et, TPB), TPB, 0, stream>>>(esrc, edst, cursor, csr_src, E0, Et);

  // ===== Layer 1: x[N,512] fp32 -> h(Ab)+al -> x1(Bb) =====
  gemm_mfma<0, 128, true><<<cdiv(N, 64), 256, 0, stream>>>(x, Wt1, Ab, N, FIN, as1, ad1, als, ald);
  fused_attn<4, 32><<<cdiv(N, 4), 256, 0, stream>>>(Ab, als, ald, offsets, csr_src, b1, g1, be1, Bb, N);
  // ===== Layer 2: x1(Bb) -> h(Ab)+al -> x2(Bb) =====
  gemm_mfma<1, 128, true><<<cdiv(N, 64), 256, 0, stream>>>(Bb, Wt2, Ab, N, 128, as2, ad2, als, ald);
  fused_attn<4, 32><<<cdiv(N, 4), 256, 0, stream>>>(Ab, als, ald, offsets, csr_src, b2, g2, be2, Bb, N);
  // ===== Layer 3: x2(Bb) -> h[N,64](Ab) -> x3(Bb) =====
  gemm_mfma<1, 64, false><<<cdiv(N, 64), 256, 0, stream>>>(Bb, Wt3, Ab, N, 128, nullptr, nullptr, nullptr, nullptr);
  compute_al<1, 64><<<cdiv((long long)N, TPB), TPB, 0, stream>>>(Ab, as3, ad3, als, ald, N);
  fused_attn<1, 64><<<cdiv(N, 4), 256, 0, stream>>>(Ab, als, ald, offsets, csr_src, b3, g3, be3, Bb, N);
  // ===== Pool + classifier =====
  pool_partial<<<64, 256, 0, stream>>>(Bb, psum, pmax, N);
  pool_final<<<1, 256, 0, stream>>>(psum, pmax, 64, N, cW1, cb1, cW2, cb2, out);
}

// Round 7
// 324.358 us; speedup vs baseline: 3.9572x; 1.0794x over previous
//
#include <hip/hip_runtime.h>
#include <cmath>

static constexpr int TPB = 256;

using short8 = __attribute__((ext_vector_type(8))) short;
using f32x4  = __attribute__((ext_vector_type(4))) float;
using uint4v = __attribute__((ext_vector_type(4))) unsigned int;
typedef unsigned short ushort;
typedef unsigned int uint;

__device__ __forceinline__ ushort f2b(float f) {
  unsigned x = __builtin_bit_cast(unsigned, f);
  unsigned r = (x + 0x7fffu + ((x >> 16) & 1u)) >> 16;   // RNE
  return (ushort)r;
}
__device__ __forceinline__ float b2f(ushort u) {
  unsigned v = ((unsigned)u) << 16;
  return __builtin_bit_cast(float, v);
}
__device__ __forceinline__ float blo(uint u) { return __builtin_bit_cast(float, u << 16); }
__device__ __forceinline__ float bhi(uint u) { return __builtin_bit_cast(float, u & 0xffff0000u); }

// ---------- all three W [K][Nc] fp32 -> Wt [Nc][K] bf16, one launch ----------
__global__ void prep_wt3(const float* __restrict__ W1, ushort* __restrict__ Wt1,
                         const float* __restrict__ W2, ushort* __restrict__ Wt2,
                         const float* __restrict__ W3, ushort* __restrict__ Wt3,
                         int FIN) {
  int idx = blockIdx.x * TPB + threadIdx.x;
  const int n1 = FIN * 128, n2 = 128 * 128, n3 = 128 * 64;
  if (idx < n1) {
    int nc = idx / FIN, k = idx - nc * FIN;
    Wt1[idx] = f2b(W1[(size_t)k * 128 + nc]);
  } else if (idx < n1 + n2) {
    int i = idx - n1;
    int nc = i / 128, k = i - nc * 128;
    Wt2[i] = f2b(W2[(size_t)k * 128 + nc]);
  } else if (idx < n1 + n2 + n3) {
    int i = idx - n1 - n2;
    int nc = i / 128, k = i - nc * 128;
    Wt3[i] = f2b(W3[(size_t)k * 64 + nc]);
  }
}

// ---------- MFMA GEMM: C[n,BN](bf16) = A[n,K] @ W[K,BN], Wt pre-transposed ----------
template <int ABF16, int BN, bool FUSE>
__global__ __launch_bounds__(256) void gemm_mfma(const void* __restrict__ Ap,
                                                 const ushort* __restrict__ Wt,
                                                 ushort* __restrict__ Cb,
                                                 int n, int K,
                                                 const float* __restrict__ a_s,
                                                 const float* __restrict__ a_d,
                                                 float* __restrict__ als,
                                                 float* __restrict__ ald) {
  constexpr int NF = BN / 32;  // col frags per wave (4 or 2)
  __shared__ short As[64 * 72];
  __shared__ short Bs[BN * 72];
  const int tid = threadIdx.x;
  const int row0 = blockIdx.x * 64;
  const int srow = tid >> 2, sks = (tid & 3) << 4;  // A staging
  const int wave = tid >> 6, lane = tid & 63;
  const int wr = wave >> 1, wc = wave & 1;
  const int lm = lane & 15, lg = lane >> 4;

  f32x4 acc[2][NF] = {};

  for (int k0 = 0; k0 < K; k0 += 64) {
    {
      int gr = row0 + srow;
      short8 v0 = {0, 0, 0, 0, 0, 0, 0, 0}, v1 = v0;
      if constexpr (ABF16 == 0) {
        const float* A = (const float*)Ap;
        if (gr < n) {
          const float* p = A + (size_t)gr * K + k0 + sks;
          float4 f0 = *(const float4*)(p + 0);
          float4 f1 = *(const float4*)(p + 4);
          float4 f2 = *(const float4*)(p + 8);
          float4 f3 = *(const float4*)(p + 12);
          v0[0] = (short)f2b(f0.x); v0[1] = (short)f2b(f0.y); v0[2] = (short)f2b(f0.z); v0[3] = (short)f2b(f0.w);
          v0[4] = (short)f2b(f1.x); v0[5] = (short)f2b(f1.y); v0[6] = (short)f2b(f1.z); v0[7] = (short)f2b(f1.w);
          v1[0] = (short)f2b(f2.x); v1[1] = (short)f2b(f2.y); v1[2] = (short)f2b(f2.z); v1[3] = (short)f2b(f2.w);
          v1[4] = (short)f2b(f3.x); v1[5] = (short)f2b(f3.y); v1[6] = (short)f2b(f3.z); v1[7] = (short)f2b(f3.w);
        }
      } else {
        const ushort* A = (const ushort*)Ap;
        if (gr < n) {
          const ushort* p = A + (size_t)gr * K + k0 + sks;
          v0 = *(const short8*)(p + 0);
          v1 = *(const short8*)(p + 8);
        }
      }
      *(short8*)&As[srow * 72 + sks + 0] = v0;
      *(short8*)&As[srow * 72 + sks + 8] = v1;
    }
    if constexpr (BN == 128) {
      const int brow = tid >> 1, bks = (tid & 1) << 5;
      const ushort* wp = Wt + (size_t)brow * K + k0 + bks;
      *(short8*)&Bs[brow * 72 + bks + 0]  = *(const short8*)(wp + 0);
      *(short8*)&Bs[brow * 72 + bks + 8]  = *(const short8*)(wp + 8);
      *(short8*)&Bs[brow * 72 + bks + 16] = *(const short8*)(wp + 16);
      *(short8*)&Bs[brow * 72 + bks + 24] = *(const short8*)(wp + 24);
    } else {
      const ushort* wp = Wt + (size_t)srow * K + k0 + sks;
      *(short8*)&Bs[srow * 72 + sks + 0] = *(const short8*)(wp + 0);
      *(short8*)&Bs[srow * 72 + sks + 8] = *(const short8*)(wp + 8);
    }
    __syncthreads();
#pragma unroll
    for (int kk = 0; kk < 64; kk += 32) {
      short8 a0 = *(const short8*)&As[(wr * 32 + lm) * 72 + kk + lg * 8];
      short8 a1 = *(const short8*)&As[(wr * 32 + 16 + lm) * 72 + kk + lg * 8];
      short8 bf[NF];
#pragma unroll
      for (int f = 0; f < NF; ++f)
        bf[f] = *(const short8*)&Bs[(wc * (BN / 2) + f * 16 + lm) * 72 + kk + lg * 8];
#pragma unroll
      for (int f = 0; f < NF; ++f) {
        acc[0][f] = __builtin_amdgcn_mfma_f32_16x16x32_bf16(a0, bf[f], acc[0][f], 0, 0, 0);
        acc[1][f] = __builtin_amdgcn_mfma_f32_16x16x32_bf16(a1, bf[f], acc[1][f], 0, 0, 0);
      }
    }
    __syncthreads();
  }
#pragma unroll
  for (int m = 0; m < 2; ++m)
#pragma unroll
    for (int f = 0; f < NF; ++f)
#pragma unroll
      for (int r = 0; r < 4; ++r) {
        int row = row0 + wr * 32 + m * 16 + lg * 4 + r;
        if (row < n) {
          int col = wc * (BN / 2) + f * 16 + lm;
          Cb[(size_t)row * BN + col] = f2b(acc[m][f][r]);
        }
      }
  if constexpr (FUSE) {
#pragma unroll
    for (int hh = 0; hh < 2; ++hh) {
      const int head = 2 * wc + hh;
      float as0 = a_s[head * 32 + lm], as1 = a_s[head * 32 + 16 + lm];
      float ad0 = a_d[head * 32 + lm], ad1 = a_d[head * 32 + 16 + lm];
#pragma unroll
      for (int m = 0; m < 2; ++m)
#pragma unroll
        for (int r = 0; r < 4; ++r) {
          float tS = acc[m][2 * hh][r] * as0 + acc[m][2 * hh + 1][r] * as1;
          float tD = acc[m][2 * hh][r] * ad0 + acc[m][2 * hh + 1][r] * ad1;
#pragma unroll
          for (int off = 8; off >= 1; off >>= 1) {
            tS += __shfl_xor(tS, off);
            tD += __shfl_xor(tD, off);
          }
          if (lm == 0) {
            int row = row0 + wr * 32 + m * 16 + lg * 4 + r;
            if (row < n) {
              als[(size_t)row * 4 + head] = tS;
              ald[(size_t)row * 4 + head] = tD;
            }
          }
        }
    }
  }
}

// ---------- per-(node,head) attention logits from bf16 h (layer 3 only) ----------
template <int HH, int CC>
__global__ void compute_al(const ushort* __restrict__ hb, const float* __restrict__ a_s,
                           const float* __restrict__ a_d, float* __restrict__ als,
                           float* __restrict__ ald, int n) {
  int idx = blockIdx.x * TPB + threadIdx.x;
  if (idx >= n * HH) return;
  int node = idx / HH, h = idx - (idx / HH) * HH;
  const ushort* hp = hb + (size_t)node * (HH * CC) + h * CC;
  float s = 0.f, d = 0.f;
#pragma unroll
  for (int c8 = 0; c8 < CC; c8 += 8) {
    short8 v = *(const short8*)(hp + c8);
#pragma unroll
    for (int j = 0; j < 8; ++j) {
      float f = b2f((ushort)v[j]);
      s += f * a_s[h * CC + c8 + j];
      d += f * a_d[h * CC + c8 + j];
    }
  }
  als[idx] = s;
  ald[idx] = d;
}

// ---------- CSR build ----------
__global__ void zero_int(int* __restrict__ p, int n) {
  int i = blockIdx.x * TPB + threadIdx.x;
  if (i < n) p[i] = 0;
}

__global__ void hist_dst(const int* __restrict__ edst, int* __restrict__ counts,
                         int E0, int Et) {
  int e = blockIdx.x * TPB + threadIdx.x;
  if (e >= Et) return;
  int d = e < E0 ? edst[e] : e - E0;
  atomicAdd(&counts[d], 1);
}

__global__ void block_sums(const int* __restrict__ counts, int* __restrict__ bsum, int N) {
  __shared__ int sh[256];
  int t = threadIdx.x, idx = blockIdx.x * 256 + t;
  sh[t] = idx < N ? counts[idx] : 0;
  __syncthreads();
  for (int off = 128; off >= 1; off >>= 1) {
    if (t < off) sh[t] += sh[t + off];
    __syncthreads();
  }
  if (t == 0) bsum[blockIdx.x] = sh[0];
}

__global__ void scan_bsum(int* __restrict__ bsum, int nb) {
  __shared__ int sh[256];
  int t = threadIdx.x;
  int v = t < nb ? bsum[t] : 0;
  sh[t] = v;
  __syncthreads();
  for (int off = 1; off < 256; off <<= 1) {
    int u = (t >= off) ? sh[t - off] : 0;
    __syncthreads();
    sh[t] += u;
    __syncthreads();
  }
  if (t < nb) bsum[t] = sh[t] - v;  // exclusive
}

__global__ void scan_final(const int* __restrict__ counts, const int* __restrict__ bsum_ex,
                           int* __restrict__ offsets, int* __restrict__ cursor,
                           int N, int Et) {
  __shared__ int sh[256];
  int t = threadIdx.x, b = blockIdx.x;
  int idx = b * 256 + t;
  int v = (idx < N) ? counts[idx] : 0;
  sh[t] = v;
  __syncthreads();
  for (int off = 1; off < 256; off <<= 1) {
    int u = (t >= off) ? sh[t - off] : 0;
    __syncthreads();
    sh[t] += u;
    __syncthreads();
  }
  if (idx < N) {
    int o = bsum_ex[b] + sh[t] - v;
    offsets[idx] = o;
    cursor[idx] = o;
  }
  if (idx == 0) offsets[N] = Et;
}

__global__ void scatter_csr(const int* __restrict__ esrc, const int* __restrict__ edst,
                            int* __restrict__ cursor, int* __restrict__ csr_src,
                            int E0, int Et) {
  int e = blockIdx.x * TPB + threadIdx.x;
  if (e >= Et) return;
  int s = e < E0 ? esrc[e] : e - E0;
  int d = e < E0 ? edst[e] : e - E0;
  int pos = atomicAdd(&cursor[d], 1);
  csr_src[pos] = s;
}

// ---------- fused attention + bias + LayerNorm + ELU, one wave per dst node ----------
template <int HH, int CC>
__global__ __launch_bounds__(256) void fused_attn(
    const ushort* __restrict__ hb, const float* __restrict__ als,
    const float* __restrict__ ald, const int* __restrict__ offsets,
    const int* __restrict__ csr_src, const float* __restrict__ bias,
    const float* __restrict__ g, const float* __restrict__ be,
    ushort* __restrict__ xout, int n) {
  constexpr int W = HH * CC;        // 128 or 64
  constexpr int LPE = W / 8;        // 16 or 8 lanes per edge
  constexpr int NEG = 64 / LPE;     // 4 or 8 concurrent edges
  int wid = (int)((blockIdx.x * (size_t)blockDim.x + threadIdx.x) >> 6);
  int lane = threadIdx.x & 63;
  if (wid >= n) return;
  const int d = wid;
  const int begin = offsets[d], end = offsets[d + 1];
  const int deg = end - begin;

  const int grp = lane / LPE, sub = lane % LPE;
  const int c0 = sub * 8;

  float acc[8] = {};

  if (HH == 4 && deg <= 16) {
    // ======== FAST16 path: lane = (head h16, edge j16) ========
    const int h16 = lane >> 4, j16 = lane & 15;
    bool act = j16 < deg;
    int s_e = csr_src[begin + (act ? j16 : 0)];
    float e;
    {
      float ad_h = ald[(size_t)d * 4 + h16];
      e = act ? (als[(size_t)s_e * 4 + h16] + ad_h) : -1e30f;
      e = e > 0.f ? e : 0.2f * e;
    }
    float m = e;
#pragma unroll
    for (int off = 8; off >= 1; off >>= 1) m = fmaxf(m, __shfl_xor(m, off));
    float p = act ? __expf(e - m) : 0.f;
    float s = p;
#pragma unroll
    for (int off = 8; off >= 1; off >>= 1) s += __shfl_xor(s, off);
    float alpha = p / (s + 1e-16f);  // 0 for inactive lanes

    const int hc = sub >> 2;          // head of my channel block
    // grouped gather: group grp walks edges grp, grp+4, ...; depth-2 pipeline
    int j = grp;
    int sj = __shfl(s_e, j & 15);
    uint4v u = *(const uint4v*)(hb + (size_t)sj * W + c0);
    for (int j0 = 0; j0 < deg; j0 += NEG) {
      uint4v ucur = u;
      int jcur = j;
      j += NEG;
      if (j0 + NEG < deg) {
        int sn = __shfl(s_e, j & 15);
        u = *(const uint4v*)(hb + (size_t)sn * W + c0);
      }
      float w = __shfl(alpha, (hc << 4) | (jcur & 15));  // 0 if jcur >= deg
#pragma unroll
      for (int i = 0; i < 4; ++i) {
        acc[2 * i]     = fmaf(w, blo(ucur[i]), acc[2 * i]);
        acc[2 * i + 1] = fmaf(w, bhi(ucur[i]), acc[2 * i + 1]);
      }
    }
  } else {

  const int hsel = sub >> 2;        // my head (HH=4)
  float aldv[HH];
  if constexpr (HH == 4) {
    float4 t = *(const float4*)(ald + (size_t)d * 4);
    aldv[0] = t.x; aldv[1] = t.y; aldv[2] = t.z; aldv[3] = t.w;
  } else {
    aldv[0] = ald[d];
  }

  auto sel4 = [&](float x0, float x1, float x2, float x3) {
    float lo = (hsel & 1) ? x1 : x0;
    float hi = (hsel & 1) ? x3 : x2;
    return (hsel & 2) ? hi : lo;
  };

  if (deg <= 64) {
    // ---- logits: one lane per edge ----
    bool act = lane < deg;
    int s_e = act ? csr_src[begin + lane] : 0;
    float e0 = -1e30f, e1 = -1e30f, e2 = -1e30f, e3 = -1e30f;
    if constexpr (HH == 4) {
      if (act) {
        float4 t = *(const float4*)(als + (size_t)s_e * 4);
        e0 = t.x + aldv[0]; e0 = e0 > 0.f ? e0 : 0.2f * e0;
        e1 = t.y + aldv[1]; e1 = e1 > 0.f ? e1 : 0.2f * e1;
        e2 = t.z + aldv[2]; e2 = e2 > 0.f ? e2 : 0.2f * e2;
        e3 = t.w + aldv[3]; e3 = e3 > 0.f ? e3 : 0.2f * e3;
      }
    } else {
      if (act) {
        e0 = als[s_e] + aldv[0]; e0 = e0 > 0.f ? e0 : 0.2f * e0;
      }
    }
    float m0 = e0, m1 = e1, m2 = e2, m3 = e3;
#pragma unroll
    for (int off = 32; off >= 1; off >>= 1) {
      m0 = fmaxf(m0, __shfl_xor(m0, off));
      if constexpr (HH == 4) {
        m1 = fmaxf(m1, __shfl_xor(m1, off));
        m2 = fmaxf(m2, __shfl_xor(m2, off));
        m3 = fmaxf(m3, __shfl_xor(m3, off));
      }
    }
    float p0 = act ? __expf(e0 - m0) : 0.f;
    float p1 = 0.f, p2 = 0.f, p3 = 0.f;
    if constexpr (HH == 4) {
      p1 = act ? __expf(e1 - m1) : 0.f;
      p2 = act ? __expf(e2 - m2) : 0.f;
      p3 = act ? __expf(e3 - m3) : 0.f;
    }
    float s0 = p0, s1 = p1, s2 = p2, s3 = p3;
#pragma unroll
    for (int off = 32; off >= 1; off >>= 1) {
      s0 += __shfl_xor(s0, off);
      if constexpr (HH == 4) {
        s1 += __shfl_xor(s1, off);
        s2 += __shfl_xor(s2, off);
        s3 += __shfl_xor(s3, off);
      }
    }
    float a0 = p0 / (s0 + 1e-16f);
    float a1 = 0.f, a2 = 0.f, a3 = 0.f;
    if constexpr (HH == 4) {
      a1 = p1 / (s1 + 1e-16f);
      a2 = p2 / (s2 + 1e-16f);
      a3 = p3 / (s3 + 1e-16f);
    }

    // ---- grouped gather: NEG edges in flight, depth-2 pipeline ----
    int j = grp;
    int sj = __shfl(s_e, j < 64 ? j : 0);
    uint4v u = *(const uint4v*)(hb + (size_t)sj * W + c0);
    for (int j0 = 0; j0 < deg; j0 += NEG) {
      uint4v ucur = u;
      int jcur = j;
      j += NEG;
      if (j0 + NEG < deg) {
        int sn = __shfl(s_e, j < 64 ? j : 0);
        u = *(const uint4v*)(hb + (size_t)sn * W + c0);
      }
      int jc = jcur < 64 ? jcur : 0;
      float w;
      if constexpr (HH == 4) {
        float wa = __shfl(a0, jc), wb = __shfl(a1, jc), wcx = __shfl(a2, jc), wd = __shfl(a3, jc);
        w = sel4(wa, wb, wcx, wd);
      } else {
        w = __shfl(a0, jc);
      }
      if (jcur >= deg) w = 0.f;
#pragma unroll
      for (int i = 0; i < 4; ++i) {
        acc[2 * i]     = fmaf(w, blo(ucur[i]), acc[2 * i]);
        acc[2 * i + 1] = fmaf(w, bhi(ucur[i]), acc[2 * i + 1]);
      }
    }
  } else {
    // ---- slow path (deg > 64) ----
    float me[HH];
#pragma unroll
    for (int h = 0; h < HH; ++h) me[h] = -1e30f;
    for (int k = begin + lane; k < end; k += 64) {
      int s = csr_src[k];
      if constexpr (HH == 4) {
        float4 t = *(const float4*)(als + (size_t)s * 4);
        float e0 = t.x + aldv[0]; e0 = e0 > 0.f ? e0 : 0.2f * e0; me[0] = fmaxf(me[0], e0);
        float e1 = t.y + aldv[1]; e1 = e1 > 0.f ? e1 : 0.2f * e1; me[1] = fmaxf(me[1], e1);
        float e2 = t.z + aldv[2]; e2 = e2 > 0.f ? e2 : 0.2f * e2; me[2] = fmaxf(me[2], e2);
        float e3 = t.w + aldv[3]; e3 = e3 > 0.f ? e3 : 0.2f * e3; me[3] = fmaxf(me[3], e3);
      } else {
        float e0 = als[s] + aldv[0]; e0 = e0 > 0.f ? e0 : 0.2f * e0; me[0] = fmaxf(me[0], e0);
      }
    }
#pragma unroll
    for (int off = 32; off >= 1; off >>= 1)
#pragma unroll
      for (int h = 0; h < HH; ++h) me[h] = fmaxf(me[h], __shfl_xor(me[h], off));
    float se[HH];
#pragma unroll
    for (int h = 0; h < HH; ++h) se[h] = 0.f;
    for (int k = begin + lane; k < end; k += 64) {
      int s = csr_src[k];
      if constexpr (HH == 4) {
        float4 t = *(const float4*)(als + (size_t)s * 4);
        float e0 = t.x + aldv[0]; e0 = e0 > 0.f ? e0 : 0.2f * e0; se[0] += __expf(e0 - me[0]);
        float e1 = t.y + aldv[1]; e1 = e1 > 0.f ? e1 : 0.2f * e1; se[1] += __expf(e1 - me[1]);
        float e2 = t.z + aldv[2]; e2 = e2 > 0.f ? e2 : 0.2f * e2; se[2] += __expf(e2 - me[2]);
        float e3 = t.w + aldv[3]; e3 = e3 > 0.f ? e3 : 0.2f * e3; se[3] += __expf(e3 - me[3]);
      } else {
        float e0 = als[s] + aldv[0]; e0 = e0 > 0.f ? e0 : 0.2f * e0; se[0] += __expf(e0 - me[0]);
      }
    }
#pragma unroll
    for (int off = 32; off >= 1; off >>= 1)
#pragma unroll
      for (int h = 0; h < HH; ++h) se[h] += __shfl_xor(se[h], off);
    float inv[HH];
#pragma unroll
    for (int h = 0; h < HH; ++h) inv[h] = 1.f / (se[h] + 1e-16f);

    float m_my, i_my, ad_my;
    if constexpr (HH == 4) {
      m_my = sel4(me[0], me[1], me[2], me[3]);
      i_my = sel4(inv[0], inv[1], inv[2], inv[3]);
      ad_my = sel4(aldv[0], aldv[1], aldv[2], aldv[3]);
    } else {
      m_my = me[0]; i_my = inv[0]; ad_my = aldv[0];
    }
    for (int j0 = 0; j0 < deg; j0 += NEG) {
      int j = j0 + grp;
      if (j < deg) {
        int s = csr_src[begin + j];
        float as_my;
        if constexpr (HH == 4) {
          float4 t = *(const float4*)(als + (size_t)s * 4);
          as_my = sel4(t.x, t.y, t.z, t.w);
        } else {
          as_my = als[s];
        }
        float e = as_my + ad_my; e = e > 0.f ? e : 0.2f * e;
        float w = __expf(e - m_my) * i_my;
        uint4v u = *(const uint4v*)(hb + (size_t)s * W + c0);
#pragma unroll
        for (int i = 0; i < 4; ++i) {
          acc[2 * i]     = fmaf(w, blo(u[i]), acc[2 * i]);
          acc[2 * i + 1] = fmaf(w, bhi(u[i]), acc[2 * i + 1]);
        }
      }
    }
  }
  }  // end non-fast16

  // ---- cross-group reduce: sum over edge groups ----
#pragma unroll
  for (int i = 0; i < 8; ++i) {
    if constexpr (HH == 1) acc[i] += __shfl_xor(acc[i], 8);
    acc[i] += __shfl_xor(acc[i], 16);
    acc[i] += __shfl_xor(acc[i], 32);
  }

  // ---- bias + LayerNorm + ELU on my 8 channels ----
  float4 bv0 = *(const float4*)(bias + c0);
  float4 bv1 = *(const float4*)(bias + c0 + 4);
  float v[8];
  v[0] = acc[0] + bv0.x; v[1] = acc[1] + bv0.y; v[2] = acc[2] + bv0.z; v[3] = acc[3] + bv0.w;
  v[4] = acc[4] + bv1.x; v[5] = acc[5] + bv1.y; v[6] = acc[6] + bv1.z; v[7] = acc[7] + bv1.w;
  float sm = 0.f, s2 = 0.f;
#pragma unroll
  for (int i = 0; i < 8; ++i) { sm += v[i]; s2 += v[i] * v[i]; }
  constexpr int TOPOFF = LPE / 2;  // 8 (W=128) or 4 (W=64)
#pragma unroll
  for (int off = TOPOFF; off >= 1; off >>= 1) {
    sm += __shfl_xor(sm, off);
    s2 += __shfl_xor(s2, off);
  }
  const float invW = 1.0f / W;
  float mu = sm * invW;
  float var = s2 * invW - mu * mu;
  float r = rsqrtf(var + 1e-5f);
  float4 gv0 = *(const float4*)(g + c0);
  float4 gv1 = *(const float4*)(g + c0 + 4);
  float4 be0 = *(const float4*)(be + c0);
  float4 be1 = *(const float4*)(be + c0 + 4);
  float gg[8] = {gv0.x, gv0.y, gv0.z, gv0.w, gv1.x, gv1.y, gv1.z, gv1.w};
  float bb[8] = {be0.x, be0.y, be0.z, be0.w, be1.x, be1.y, be1.z, be1.w};
  uint4v pk;
#pragma unroll
  for (int i = 0; i < 4; ++i) {
    float y0 = gg[2 * i] * (v[2 * i] - mu) * r + bb[2 * i];
    y0 = y0 > 0.f ? y0 : __expf(y0) - 1.f;
    float y1 = gg[2 * i + 1] * (v[2 * i + 1] - mu) * r + bb[2 * i + 1];
    y1 = y1 > 0.f ? y1 : __expf(y1) - 1.f;
    pk[i] = (uint)f2b(y0) | ((uint)f2b(y1) << 16);
  }
  if (grp == 0)
    *(uint4v*)(xout + (size_t)wid * W + c0) = pk;
}

// ---------- pooling over bf16 h3 (64 partial blocks) ----------
__global__ void pool_partial(const ushort* __restrict__ h, float* __restrict__ psum,
                             float* __restrict__ pmax, int n) {
  int tid = threadIdx.x;
  float lsum = 0.f, lmax = -1e30f;
  for (size_t idx = (size_t)blockIdx.x * 256 + tid; idx < (size_t)n * 64;
       idx += (size_t)gridDim.x * 256) {
    float v = b2f(h[idx]);
    lsum += v;
    lmax = fmaxf(lmax, v);
  }
  __shared__ float ss[256], sm[256];
  ss[tid] = lsum; sm[tid] = lmax;
  __syncthreads();
  if (tid < 64) {
    float a = ss[tid] + ss[tid + 64] + ss[tid + 128] + ss[tid + 192];
    float m = fmaxf(fmaxf(sm[tid], sm[tid + 64]), fmaxf(sm[tid + 128], sm[tid + 192]));
    psum[blockIdx.x * 64 + tid] = a;
    pmax[blockIdx.x * 64 + tid] = m;
  }
}

// ---------- parallel final reduce + classifier (256 threads, 1 block) ----------
__global__ __launch_bounds__(256) void pool_final(
    const float* __restrict__ psum, const float* __restrict__ pmax,
    int nblocks, int n, const float* __restrict__ cW1,
    const float* __restrict__ cb1, const float* __restrict__ cW2,
    const float* __restrict__ cb2, float* __restrict__ out) {
  __shared__ float sred[4][64], mred[4][64];
  __shared__ float z[128];
  __shared__ float hid[128];
  int tid = threadIdx.x;
  int c = tid & 63, q = tid >> 6;  // q in 0..3
  float s = 0.f, m = -1e30f;
  for (int b = q; b < nblocks; b += 4) {
    s += psum[b * 64 + c];
    m = fmaxf(m, pmax[b * 64 + c]);
  }
  sred[q][c] = s; mred[q][c] = m;
  __syncthreads();
  if (q == 0) {
    float st = sred[0][c] + sred[1][c] + sred[2][c] + sred[3][c];
    float mt = fmaxf(fmaxf(mred[0][c], mred[1][c]), fmaxf(mred[2][c], mred[3][c]));
    z[c] = st / (float)n;
    z[64 + c] = mt;
  }
  __syncthreads();
  if (tid < 128) {
    float a = cb1[tid];
#pragma unroll 4
    for (int k = 0; k < 128; ++k) a += z[k] * cW1[k * 128 + tid];
    hid[tid] = fmaxf(a, 0.f);
  }
  __syncthreads();
  if (tid < 2) {
    float o = cb2[tid];
    for (int j = 0; j < 128; ++j) o += hid[j] * cW2[j * 2 + tid];
    out[tid] = o;
  }
}

static inline int cdiv(long long a, long long b) { return (int)((a + b - 1) / b); }

extern "C" void kernel_launch(void* const* d_in, const int* in_sizes, int n_in,
                              void* d_out, int out_size, void* d_ws, size_t ws_size,
                              hipStream_t stream) {
  const float* x   = (const float*)d_in[0];
  const int*   ei  = (const int*)d_in[1];
  const float* W1  = (const float*)d_in[3];
  const float* as1 = (const float*)d_in[4];
  const float* ad1 = (const float*)d_in[5];
  const float* b1  = (const float*)d_in[6];
  const float* g1  = (const float*)d_in[7];
  const float* be1 = (const float*)d_in[8];
  const float* W2  = (const float*)d_in[9];
  const float* as2 = (const float*)d_in[10];
  const float* ad2 = (const float*)d_in[11];
  const float* b2  = (const float*)d_in[12];
  const float* g2  = (const float*)d_in[13];
  const float* be2 = (const float*)d_in[14];
  const float* W3  = (const float*)d_in[15];
  const float* as3 = (const float*)d_in[16];
  const float* ad3 = (const float*)d_in[17];
  const float* b3  = (const float*)d_in[18];
  const float* g3  = (const float*)d_in[19];
  const float* be3 = (const float*)d_in[20];
  const float* cW1 = (const float*)d_in[21];
  const float* cb1 = (const float*)d_in[22];
  const float* cW2 = (const float*)d_in[23];
  const float* cb2 = (const float*)d_in[24];
  float* out = (float*)d_out;

  const int N   = in_sizes[2];
  const int E0  = in_sizes[1] / 2;
  const int Et  = E0 + N;
  const int FIN = in_sizes[0] / N;

  float* ws = (float*)d_ws;
  size_t o = 0;
  ushort* Ab = (ushort*)(ws + o); o += (size_t)N * 64;   // N x 128 bf16 (h)
  ushort* Bb = (ushort*)(ws + o); o += (size_t)N * 64;   // N x 128 bf16 (x_l)
  float* als  = ws + o; o += (size_t)N * 4;
  float* ald  = ws + o; o += (size_t)N * 4;
  ushort* Wt1 = (ushort*)(ws + o); o += (128 * 512) / 2;
  ushort* Wt2 = (ushort*)(ws + o); o += (128 * 128) / 2;
  ushort* Wt3 = (ushort*)(ws + o); o += (64 * 128) / 2;
  float* psum = ws + o; o += 64 * 64;
  float* pmax = ws + o; o += 64 * 64;
  int* counts  = (int*)(ws + o); o += N + 1;
  int* offsets = (int*)(ws + o); o += N + 1;
  int* cursor  = (int*)(ws + o); o += N;
  int* bsum    = (int*)(ws + o); o += 256;
  int* csr_src = (int*)(ws + o); o += Et;

  const int* esrc = ei;
  const int* edst = ei + E0;
  const int NB = cdiv(N, 256);

  // ===== weight prep (single launch) =====
  prep_wt3<<<cdiv((long long)FIN * 128 + 128 * 128 + 128 * 64, TPB), TPB, 0, stream>>>(
      W1, Wt1, W2, Wt2, W3, Wt3, FIN);

  // ===== CSR build (once, reused by all 3 layers) =====
  zero_int<<<cdiv(N + 1, TPB), TPB, 0, stream>>>(counts, N + 1);
  hist_dst<<<cdiv(Et, TPB), TPB, 0, stream>>>(edst, counts, E0, Et);
  block_sums<<<NB, 256, 0, stream>>>(counts, bsum, N);
  scan_bsum<<<1, 256, 0, stream>>>(bsum, NB);
  scan_final<<<NB, 256, 0, stream>>>(counts, bsum, offsets, cursor, N, Et);
  scatter_csr<<<cdiv(Et, TPB), TPB, 0, stream>>>(esrc, edst, cursor, csr_src, E0, Et);

  // ===== Layer 1: x[N,512] fp32 -> h(Ab)+al -> x1(Bb) =====
  gemm_mfma<0, 128, true><<<cdiv(N, 64), 256, 0, stream>>>(x, Wt1, Ab, N, FIN, as1, ad1, als, ald);
  fused_attn<4, 32><<<cdiv(N, 4), 256, 0, stream>>>(Ab, als, ald, offsets, csr_src, b1, g1, be1, Bb, N);
  // ===== Layer 2: x1(Bb) -> h(Ab)+al -> x2(Bb) =====
  gemm_mfma<1, 128, true><<<cdiv(N, 64), 256, 0, stream>>>(Bb, Wt2, Ab, N, 128, as2, ad2, als, ald);
  fused_attn<4, 32><<<cdiv(N, 4), 256, 0, stream>>>(Ab, als, ald, offsets, csr_src, b2, g2, be2, Bb, N);
  // ===== Layer 3: x2(Bb) -> h[N,64](Ab) -> x3(Bb) =====
  gemm_mfma<1, 64, false><<<cdiv(N, 64), 256, 0, stream>>>(Bb, Wt3, Ab, N, 128, nullptr, nullptr, nullptr, nullptr);
  compute_al<1, 64><<<cdiv((long long)N, TPB), TPB, 0, stream>>>(Ab, as3, ad3, als, ald, N);
  fused_attn<1, 64><<<cdiv(N, 4), 256, 0, stream>>>(Ab, als, ald, offsets, csr_src, b3, g3, be3, Bb, N);
  // ===== Pool + classifier =====
  pool_partial<<<64, 256, 0, stream>>>(Bb, psum, pmax, N);
  pool_final<<<1, 256, 0, stream>>>(psum, pmax, 64, N, cW1, cb1, cW2, cb2, out);
}

// Round 9
// 321.147 us; speedup vs baseline: 3.9968x; 1.0100x over previous
//
#include <hip/hip_runtime.h>
#include <cmath>

static constexpr int TPB = 256;

using short8 = __attribute__((ext_vector_type(8))) short;
using half8  = __attribute__((ext_vector_type(8))) _Float16;
using f32x4  = __attribute__((ext_vector_type(4))) float;
using uint4v = __attribute__((ext_vector_type(4))) unsigned int;
typedef unsigned short ushort;
typedef unsigned int uint;

// fp16 helpers (RNE via hardware convert)
__device__ __forceinline__ ushort f2h(float f) {
  _Float16 h = (_Float16)f;
  return __builtin_bit_cast(ushort, h);
}
__device__ __forceinline__ float h2f(ushort u) {
  return (float)__builtin_bit_cast(_Float16, u);
}
__device__ __forceinline__ float hlo(uint u) { return h2f((ushort)(u & 0xffffu)); }
__device__ __forceinline__ float hhi(uint u) { return h2f((ushort)(u >> 16)); }

// ---------- all three W [K][Nc] fp32 -> Wt [Nc][K] fp16, one launch ----------
__global__ void prep_wt3(const float* __restrict__ W1, ushort* __restrict__ Wt1,
                         const float* __restrict__ W2, ushort* __restrict__ Wt2,
                         const float* __restrict__ W3, ushort* __restrict__ Wt3,
                         int FIN) {
  int idx = blockIdx.x * TPB + threadIdx.x;
  const int n1 = FIN * 128, n2 = 128 * 128, n3 = 128 * 64;
  if (idx < n1) {
    int nc = idx / FIN, k = idx - nc * FIN;
    Wt1[idx] = f2h(W1[(size_t)k * 128 + nc]);
  } else if (idx < n1 + n2) {
    int i = idx - n1;
    int nc = i / 128, k = i - nc * 128;
    Wt2[i] = f2h(W2[(size_t)k * 128 + nc]);
  } else if (idx < n1 + n2 + n3) {
    int i = idx - n1 - n2;
    int nc = i / 128, k = i - nc * 128;
    Wt3[i] = f2h(W3[(size_t)k * 64 + nc]);
  }
}

// ---------- MFMA GEMM (fp16): C[n,BN](fp16) = A[n,K] @ W[K,BN] ----------
// BM=64, BN=Nc (64 or 128), BK=64, 256 threads = 4 waves (2 row x 2 col)
template <int ABF16, int BN, bool FUSE>
__global__ __launch_bounds__(256) void gemm_mfma(const void* __restrict__ Ap,
                                                 const ushort* __restrict__ Wt,
                                                 ushort* __restrict__ Cb,
                                                 int n, int K,
                                                 const float* __restrict__ a_s,
                                                 const float* __restrict__ a_d,
                                                 float* __restrict__ als,
                                                 float* __restrict__ ald) {
  constexpr int NF = BN / 32;  // col frags per wave (4 or 2)
  __shared__ short As[64 * 72];
  __shared__ short Bs[BN * 72];
  const int tid = threadIdx.x;
  const int row0 = blockIdx.x * 64;
  const int srow = tid >> 2, sks = (tid & 3) << 4;  // A staging
  const int wave = tid >> 6, lane = tid & 63;
  const int wr = wave >> 1, wc = wave & 1;
  const int lm = lane & 15, lg = lane >> 4;

  f32x4 acc[2][NF] = {};

  for (int k0 = 0; k0 < K; k0 += 64) {
    {
      int gr = row0 + srow;
      short8 v0 = {0, 0, 0, 0, 0, 0, 0, 0}, v1 = v0;
      if constexpr (ABF16 == 0) {
        const float* A = (const float*)Ap;
        if (gr < n) {
          const float* p = A + (size_t)gr * K + k0 + sks;
          float4 f0 = *(const float4*)(p + 0);
          float4 f1 = *(const float4*)(p + 4);
          float4 f2 = *(const float4*)(p + 8);
          float4 f3 = *(const float4*)(p + 12);
          v0[0] = (short)f2h(f0.x); v0[1] = (short)f2h(f0.y); v0[2] = (short)f2h(f0.z); v0[3] = (short)f2h(f0.w);
          v0[4] = (short)f2h(f1.x); v0[5] = (short)f2h(f1.y); v0[6] = (short)f2h(f1.z); v0[7] = (short)f2h(f1.w);
          v1[0] = (short)f2h(f2.x); v1[1] = (short)f2h(f2.y); v1[2] = (short)f2h(f2.z); v1[3] = (short)f2h(f2.w);
          v1[4] = (short)f2h(f3.x); v1[5] = (short)f2h(f3.y); v1[6] = (short)f2h(f3.z); v1[7] = (short)f2h(f3.w);
        }
      } else {
        const ushort* A = (const ushort*)Ap;
        if (gr < n) {
          const ushort* p = A + (size_t)gr * K + k0 + sks;
          v0 = *(const short8*)(p + 0);
          v1 = *(const short8*)(p + 8);
        }
      }
      *(short8*)&As[srow * 72 + sks + 0] = v0;
      *(short8*)&As[srow * 72 + sks + 8] = v1;
    }
    if constexpr (BN == 128) {
      const int brow = tid >> 1, bks = (tid & 1) << 5;
      const ushort* wp = Wt + (size_t)brow * K + k0 + bks;
      *(short8*)&Bs[brow * 72 + bks + 0]  = *(const short8*)(wp + 0);
      *(short8*)&Bs[brow * 72 + bks + 8]  = *(const short8*)(wp + 8);
      *(short8*)&Bs[brow * 72 + bks + 16] = *(const short8*)(wp + 16);
      *(short8*)&Bs[brow * 72 + bks + 24] = *(const short8*)(wp + 24);
    } else {
      const ushort* wp = Wt + (size_t)srow * K + k0 + sks;
      *(short8*)&Bs[srow * 72 + sks + 0] = *(const short8*)(wp + 0);
      *(short8*)&Bs[srow * 72 + sks + 8] = *(const short8*)(wp + 8);
    }
    __syncthreads();
#pragma unroll
    for (int kk = 0; kk < 64; kk += 32) {
      half8 a0 = *(const half8*)&As[(wr * 32 + lm) * 72 + kk + lg * 8];
      half8 a1 = *(const half8*)&As[(wr * 32 + 16 + lm) * 72 + kk + lg * 8];
      half8 bf[NF];
#pragma unroll
      for (int f = 0; f < NF; ++f)
        bf[f] = *(const half8*)&Bs[(wc * (BN / 2) + f * 16 + lm) * 72 + kk + lg * 8];
#pragma unroll
      for (int f = 0; f < NF; ++f) {
        acc[0][f] = __builtin_amdgcn_mfma_f32_16x16x32_f16(a0, bf[f], acc[0][f], 0, 0, 0);
        acc[1][f] = __builtin_amdgcn_mfma_f32_16x16x32_f16(a1, bf[f], acc[1][f], 0, 0, 0);
      }
    }
    __syncthreads();
  }
#pragma unroll
  for (int m = 0; m < 2; ++m)
#pragma unroll
    for (int f = 0; f < NF; ++f)
#pragma unroll
      for (int r = 0; r < 4; ++r) {
        int row = row0 + wr * 32 + m * 16 + lg * 4 + r;
        if (row < n) {
          int col = wc * (BN / 2) + f * 16 + lm;
          Cb[(size_t)row * BN + col] = f2h(acc[m][f][r]);
        }
      }
  if constexpr (FUSE) {
#pragma unroll
    for (int hh = 0; hh < 2; ++hh) {
      const int head = 2 * wc + hh;
      float as0 = a_s[head * 32 + lm], as1 = a_s[head * 32 + 16 + lm];
      float ad0 = a_d[head * 32 + lm], ad1 = a_d[head * 32 + 16 + lm];
#pragma unroll
      for (int m = 0; m < 2; ++m)
#pragma unroll
        for (int r = 0; r < 4; ++r) {
          float tS = acc[m][2 * hh][r] * as0 + acc[m][2 * hh + 1][r] * as1;
          float tD = acc[m][2 * hh][r] * ad0 + acc[m][2 * hh + 1][r] * ad1;
#pragma unroll
          for (int off = 8; off >= 1; off >>= 1) {
            tS += __shfl_xor(tS, off);
            tD += __shfl_xor(tD, off);
          }
          if (lm == 0) {
            int row = row0 + wr * 32 + m * 16 + lg * 4 + r;
            if (row < n) {
              als[(size_t)row * 4 + head] = tS;
              ald[(size_t)row * 4 + head] = tD;
            }
          }
        }
    }
  }
}

// ---------- per-(node,head) attention logits from fp16 h (layer 3 only) ----------
template <int HH, int CC>
__global__ void compute_al(const ushort* __restrict__ hb, const float* __restrict__ a_s,
                           const float* __restrict__ a_d, float* __restrict__ als,
                           float* __restrict__ ald, int n) {
  int idx = blockIdx.x * TPB + threadIdx.x;
  if (idx >= n * HH) return;
  int node = idx / HH, h = idx - (idx / HH) * HH;
  const ushort* hp = hb + (size_t)node * (HH * CC) + h * CC;
  float s = 0.f, d = 0.f;
#pragma unroll
  for (int c8 = 0; c8 < CC; c8 += 8) {
    short8 v = *(const short8*)(hp + c8);
#pragma unroll
    for (int j = 0; j < 8; ++j) {
      float f = h2f((ushort)v[j]);
      s += f * a_s[h * CC + c8 + j];
      d += f * a_d[h * CC + c8 + j];
    }
  }
  als[idx] = s;
  ald[idx] = d;
}

// ---------- CSR build ----------
__global__ void zero_int(int* __restrict__ p, int n) {
  int i = blockIdx.x * TPB + threadIdx.x;
  if (i < n) p[i] = 0;
}

__global__ void hist_dst(const int* __restrict__ edst, int* __restrict__ counts,
                         int E0, int Et) {
  int e = blockIdx.x * TPB + threadIdx.x;
  if (e >= Et) return;
  int d = e < E0 ? edst[e] : e - E0;
  atomicAdd(&counts[d], 1);
}

__global__ void block_sums(const int* __restrict__ counts, int* __restrict__ bsum, int N) {
  __shared__ int sh[256];
  int t = threadIdx.x, idx = blockIdx.x * 256 + t;
  sh[t] = idx < N ? counts[idx] : 0;
  __syncthreads();
  for (int off = 128; off >= 1; off >>= 1) {
    if (t < off) sh[t] += sh[t + off];
    __syncthreads();
  }
  if (t == 0) bsum[blockIdx.x] = sh[0];
}

__global__ void scan_bsum(int* __restrict__ bsum, int nb) {
  __shared__ int sh[256];
  int t = threadIdx.x;
  int v = t < nb ? bsum[t] : 0;
  sh[t] = v;
  __syncthreads();
  for (int off = 1; off < 256; off <<= 1) {
    int u = (t >= off) ? sh[t - off] : 0;
    __syncthreads();
    sh[t] += u;
    __syncthreads();
  }
  if (t < nb) bsum[t] = sh[t] - v;  // exclusive
}

__global__ void scan_final(const int* __restrict__ counts, const int* __restrict__ bsum_ex,
                           int* __restrict__ offsets, int* __restrict__ cursor,
                           int N, int Et) {
  __shared__ int sh[256];
  int t = threadIdx.x, b = blockIdx.x;
  int idx = b * 256 + t;
  int v = (idx < N) ? counts[idx] : 0;
  sh[t] = v;
  __syncthreads();
  for (int off = 1; off < 256; off <<= 1) {
    int u = (t >= off) ? sh[t - off] : 0;
    __syncthreads();
    sh[t] += u;
    __syncthreads();
  }
  if (idx < N) {
    int o = bsum_ex[b] + sh[t] - v;
    offsets[idx] = o;
    cursor[idx] = o;
  }
  if (idx == 0) offsets[N] = Et;
}

__global__ void scatter_csr(const int* __restrict__ esrc, const int* __restrict__ edst,
                            int* __restrict__ cursor, int* __restrict__ csr_src,
                            int E0, int Et) {
  int e = blockIdx.x * TPB + threadIdx.x;
  if (e >= Et) return;
  int s = e < E0 ? esrc[e] : e - E0;
  int d = e < E0 ? edst[e] : e - E0;
  int pos = atomicAdd(&cursor[d], 1);
  csr_src[pos] = s;
}

// ---------- fused attention + bias + LayerNorm + ELU, one wave per dst node ----------
template <int HH, int CC>
__global__ __launch_bounds__(256) void fused_attn(
    const ushort* __restrict__ hb, const float* __restrict__ als,
    const float* __restrict__ ald, const int* __restrict__ offsets,
    const int* __restrict__ csr_src, const float* __restrict__ bias,
    const float* __restrict__ g, const float* __restrict__ be,
    ushort* __restrict__ xout, int n) {
  constexpr int W = HH * CC;        // 128 or 64
  constexpr int LPE = W / 8;        // 16 or 8 lanes per edge
  constexpr int NEG = 64 / LPE;     // 4 or 8 concurrent edges
  int wid = (int)((blockIdx.x * (size_t)blockDim.x + threadIdx.x) >> 6);
  int lane = threadIdx.x & 63;
  if (wid >= n) return;
  const int d = wid;
  const int begin = offsets[d], end = offsets[d + 1];
  const int deg = end - begin;

  const int grp = lane / LPE, sub = lane % LPE;
  const int c0 = sub * 8;

  float acc[8] = {};

  if (HH == 4 && deg <= 16) {
    // ======== FAST16 path: lane = (head h16, edge j16) ========
    const int h16 = lane >> 4, j16 = lane & 15;
    bool act = j16 < deg;
    int s_e = csr_src[begin + (act ? j16 : 0)];
    float e;
    {
      float ad_h = ald[(size_t)d * 4 + h16];
      e = act ? (als[(size_t)s_e * 4 + h16] + ad_h) : -1e30f;
      e = e > 0.f ? e : 0.2f * e;
    }
    float m = e;
#pragma unroll
    for (int off = 8; off >= 1; off >>= 1) m = fmaxf(m, __shfl_xor(m, off));
    float p = act ? __expf(e - m) : 0.f;
    float s = p;
#pragma unroll
    for (int off = 8; off >= 1; off >>= 1) s += __shfl_xor(s, off);
    float alpha = p / (s + 1e-16f);  // 0 for inactive lanes

    const int hc = sub >> 2;          // head of my channel block
    int j = grp;
    int sj = __shfl(s_e, j & 15);
    uint4v u = *(const uint4v*)(hb + (size_t)sj * W + c0);
    for (int j0 = 0; j0 < deg; j0 += NEG) {
      uint4v ucur = u;
      int jcur = j;
      j += NEG;
      if (j0 + NEG < deg) {
        int sn = __shfl(s_e, j & 15);
        u = *(const uint4v*)(hb + (size_t)sn * W + c0);
      }
      float w = __shfl(alpha, (hc << 4) | (jcur & 15));  // 0 if jcur >= deg
#pragma unroll
      for (int i = 0; i < 4; ++i) {
        acc[2 * i]     = fmaf(w, hlo(ucur[i]), acc[2 * i]);
        acc[2 * i + 1] = fmaf(w, hhi(ucur[i]), acc[2 * i + 1]);
      }
    }
  } else {

  const int hsel = sub >> 2;        // my head (HH=4)
  float aldv[HH];
  if constexpr (HH == 4) {
    float4 t = *(const float4*)(ald + (size_t)d * 4);
    aldv[0] = t.x; aldv[1] = t.y; aldv[2] = t.z; aldv[3] = t.w;
  } else {
    aldv[0] = ald[d];
  }

  auto sel4 = [&](float x0, float x1, float x2, float x3) {
    float lo = (hsel & 1) ? x1 : x0;
    float hi = (hsel & 1) ? x3 : x2;
    return (hsel & 2) ? hi : lo;
  };

  if (deg <= 64) {
    // ---- logits: one lane per edge ----
    bool act = lane < deg;
    int s_e = act ? csr_src[begin + lane] : 0;
    float e0 = -1e30f, e1 = -1e30f, e2 = -1e30f, e3 = -1e30f;
    if constexpr (HH == 4) {
      if (act) {
        float4 t = *(const float4*)(als + (size_t)s_e * 4);
        e0 = t.x + aldv[0]; e0 = e0 > 0.f ? e0 : 0.2f * e0;
        e1 = t.y + aldv[1]; e1 = e1 > 0.f ? e1 : 0.2f * e1;
        e2 = t.z + aldv[2]; e2 = e2 > 0.f ? e2 : 0.2f * e2;
        e3 = t.w + aldv[3]; e3 = e3 > 0.f ? e3 : 0.2f * e3;
      }
    } else {
      if (act) {
        e0 = als[s_e] + aldv[0]; e0 = e0 > 0.f ? e0 : 0.2f * e0;
      }
    }
    float m0 = e0, m1 = e1, m2 = e2, m3 = e3;
#pragma unroll
    for (int off = 32; off >= 1; off >>= 1) {
      m0 = fmaxf(m0, __shfl_xor(m0, off));
      if constexpr (HH == 4) {
        m1 = fmaxf(m1, __shfl_xor(m1, off));
        m2 = fmaxf(m2, __shfl_xor(m2, off));
        m3 = fmaxf(m3, __shfl_xor(m3, off));
      }
    }
    float p0 = act ? __expf(e0 - m0) : 0.f;
    float p1 = 0.f, p2 = 0.f, p3 = 0.f;
    if constexpr (HH == 4) {
      p1 = act ? __expf(e1 - m1) : 0.f;
      p2 = act ? __expf(e2 - m2) : 0.f;
      p3 = act ? __expf(e3 - m3) : 0.f;
    }
    float s0 = p0, s1 = p1, s2 = p2, s3 = p3;
#pragma unroll
    for (int off = 32; off >= 1; off >>= 1) {
      s0 += __shfl_xor(s0, off);
      if constexpr (HH == 4) {
        s1 += __shfl_xor(s1, off);
        s2 += __shfl_xor(s2, off);
        s3 += __shfl_xor(s3, off);
      }
    }
    float a0 = p0 / (s0 + 1e-16f);
    float a1 = 0.f, a2 = 0.f, a3 = 0.f;
    if constexpr (HH == 4) {
      a1 = p1 / (s1 + 1e-16f);
      a2 = p2 / (s2 + 1e-16f);
      a3 = p3 / (s3 + 1e-16f);
    }

    // ---- grouped gather: NEG edges in flight, depth-2 pipeline ----
    int j = grp;
    int sj = __shfl(s_e, j < 64 ? j : 0);
    uint4v u = *(const uint4v*)(hb + (size_t)sj * W + c0);
    for (int j0 = 0; j0 < deg; j0 += NEG) {
      uint4v ucur = u;
      int jcur = j;
      j += NEG;
      if (j0 + NEG < deg) {
        int sn = __shfl(s_e, j < 64 ? j : 0);
        u = *(const uint4v*)(hb + (size_t)sn * W + c0);
      }
      int jc = jcur < 64 ? jcur : 0;
      float w;
      if constexpr (HH == 4) {
        float wa = __shfl(a0, jc), wb = __shfl(a1, jc), wcx = __shfl(a2, jc), wd = __shfl(a3, jc);
        w = sel4(wa, wb, wcx, wd);
      } else {
        w = __shfl(a0, jc);
      }
      if (jcur >= deg) w = 0.f;
#pragma unroll
      for (int i = 0; i < 4; ++i) {
        acc[2 * i]     = fmaf(w, hlo(ucur[i]), acc[2 * i]);
        acc[2 * i + 1] = fmaf(w, hhi(ucur[i]), acc[2 * i + 1]);
      }
    }
  } else {
    // ---- slow path (deg > 64) ----
    float me[HH];
#pragma unroll
    for (int h = 0; h < HH; ++h) me[h] = -1e30f;
    for (int k = begin + lane; k < end; k += 64) {
      int s = csr_src[k];
      if constexpr (HH == 4) {
        float4 t = *(const float4*)(als + (size_t)s * 4);
        float e0 = t.x + aldv[0]; e0 = e0 > 0.f ? e0 : 0.2f * e0; me[0] = fmaxf(me[0], e0);
        float e1 = t.y + aldv[1]; e1 = e1 > 0.f ? e1 : 0.2f * e1; me[1] = fmaxf(me[1], e1);
        float e2 = t.z + aldv[2]; e2 = e2 > 0.f ? e2 : 0.2f * e2; me[2] = fmaxf(me[2], e2);
        float e3 = t.w + aldv[3]; e3 = e3 > 0.f ? e3 : 0.2f * e3; me[3] = fmaxf(me[3], e3);
      } else {
        float e0 = als[s] + aldv[0]; e0 = e0 > 0.f ? e0 : 0.2f * e0; me[0] = fmaxf(me[0], e0);
      }
    }
#pragma unroll
    for (int off = 32; off >= 1; off >>= 1)
#pragma unroll
      for (int h = 0; h < HH; ++h) me[h] = fmaxf(me[h], __shfl_xor(me[h], off));
    float se[HH];
#pragma unroll
    for (int h = 0; h < HH; ++h) se[h] = 0.f;
    for (int k = begin + lane; k < end; k += 64) {
      int s = csr_src[k];
      if constexpr (HH == 4) {
        float4 t = *(const float4*)(als + (size_t)s * 4);
        float e0 = t.x + aldv[0]; e0 = e0 > 0.f ? e0 : 0.2f * e0; se[0] += __expf(e0 - me[0]);
        float e1 = t.y + aldv[1]; e1 = e1 > 0.f ? e1 : 0.2f * e1; se[1] += __expf(e1 - me[1]);
        float e2 = t.z + aldv[2]; e2 = e2 > 0.f ? e2 : 0.2f * e2; se[2] += __expf(e2 - me[2]);
        float e3 = t.w + aldv[3]; e3 = e3 > 0.f ? e3 : 0.2f * e3; se[3] += __expf(e3 - me[3]);
      } else {
        float e0 = als[s] + aldv[0]; e0 = e0 > 0.f ? e0 : 0.2f * e0; se[0] += __expf(e0 - me[0]);
      }
    }
#pragma unroll
    for (int off = 32; off >= 1; off >>= 1)
#pragma unroll
      for (int h = 0; h < HH; ++h) se[h] += __shfl_xor(se[h], off);
    float inv[HH];
#pragma unroll
    for (int h = 0; h < HH; ++h) inv[h] = 1.f / (se[h] + 1e-16f);

    float m_my, i_my, ad_my;
    if constexpr (HH == 4) {
      m_my = sel4(me[0], me[1], me[2], me[3]);
      i_my = sel4(inv[0], inv[1], inv[2], inv[3]);
      ad_my = sel4(aldv[0], aldv[1], aldv[2], aldv[3]);
    } else {
      m_my = me[0]; i_my = inv[0]; ad_my = aldv[0];
    }
    for (int j0 = 0; j0 < deg; j0 += NEG) {
      int j = j0 + grp;
      if (j < deg) {
        int s = csr_src[begin + j];
        float as_my;
        if constexpr (HH == 4) {
          float4 t = *(const float4*)(als + (size_t)s * 4);
          as_my = sel4(t.x, t.y, t.z, t.w);
        } else {
          as_my = als[s];
        }
        float e = as_my + ad_my; e = e > 0.f ? e : 0.2f * e;
        float w = __expf(e - m_my) * i_my;
        uint4v u = *(const uint4v*)(hb + (size_t)s * W + c0);
#pragma unroll
        for (int i = 0; i < 4; ++i) {
          acc[2 * i]     = fmaf(w, hlo(u[i]), acc[2 * i]);
          acc[2 * i + 1] = fmaf(w, hhi(u[i]), acc[2 * i + 1]);
        }
      }
    }
  }
  }  // end non-fast16

  // ---- cross-group reduce: sum over edge groups ----
#pragma unroll
  for (int i = 0; i < 8; ++i) {
    if constexpr (HH == 1) acc[i] += __shfl_xor(acc[i], 8);
    acc[i] += __shfl_xor(acc[i], 16);
    acc[i] += __shfl_xor(acc[i], 32);
  }

  // ---- bias + LayerNorm + ELU on my 8 channels ----
  float4 bv0 = *(const float4*)(bias + c0);
  float4 bv1 = *(const float4*)(bias + c0 + 4);
  float v[8];
  v[0] = acc[0] + bv0.x; v[1] = acc[1] + bv0.y; v[2] = acc[2] + bv0.z; v[3] = acc[3] + bv0.w;
  v[4] = acc[4] + bv1.x; v[5] = acc[5] + bv1.y; v[6] = acc[6] + bv1.z; v[7] = acc[7] + bv1.w;
  float sm = 0.f, s2 = 0.f;
#pragma unroll
  for (int i = 0; i < 8; ++i) { sm += v[i]; s2 += v[i] * v[i]; }
  constexpr int TOPOFF = LPE / 2;  // 8 (W=128) or 4 (W=64)
#pragma unroll
  for (int off = TOPOFF; off >= 1; off >>= 1) {
    sm += __shfl_xor(sm, off);
    s2 += __shfl_xor(s2, off);
  }
  const float invW = 1.0f / W;
  float mu = sm * invW;
  float var = s2 * invW - mu * mu;
  float r = rsqrtf(var + 1e-5f);
  float4 gv0 = *(const float4*)(g + c0);
  float4 gv1 = *(const float4*)(g + c0 + 4);
  float4 be0 = *(const float4*)(be + c0);
  float4 be1 = *(const float4*)(be + c0 + 4);
  float gg[8] = {gv0.x, gv0.y, gv0.z, gv0.w, gv1.x, gv1.y, gv1.z, gv1.w};
  float bb[8] = {be0.x, be0.y, be0.z, be0.w, be1.x, be1.y, be1.z, be1.w};
  uint4v pk;
#pragma unroll
  for (int i = 0; i < 4; ++i) {
    float y0 = gg[2 * i] * (v[2 * i] - mu) * r + bb[2 * i];
    y0 = y0 > 0.f ? y0 : __expf(y0) - 1.f;
    float y1 = gg[2 * i + 1] * (v[2 * i + 1] - mu) * r + bb[2 * i + 1];
    y1 = y1 > 0.f ? y1 : __expf(y1) - 1.f;
    pk[i] = (uint)f2h(y0) | ((uint)f2h(y1) << 16);
  }
  if (grp == 0)
    *(uint4v*)(xout + (size_t)wid * W + c0) = pk;
}

// ---------- pooling over fp16 h3 (64 partial blocks) ----------
__global__ void pool_partial(const ushort* __restrict__ h, float* __restrict__ psum,
                             float* __restrict__ pmax, int n) {
  int tid = threadIdx.x;
  float lsum = 0.f, lmax = -1e30f;
  for (size_t idx = (size_t)blockIdx.x * 256 + tid; idx < (size_t)n * 64;
       idx += (size_t)gridDim.x * 256) {
    float v = h2f(h[idx]);
    lsum += v;
    lmax = fmaxf(lmax, v);
  }
  __shared__ float ss[256], sm[256];
  ss[tid] = lsum; sm[tid] = lmax;
  __syncthreads();
  if (tid < 64) {
    float a = ss[tid] + ss[tid + 64] + ss[tid + 128] + ss[tid + 192];
    float m = fmaxf(fmaxf(sm[tid], sm[tid + 64]), fmaxf(sm[tid + 128], sm[tid + 192]));
    psum[blockIdx.x * 64 + tid] = a;
    pmax[blockIdx.x * 64 + tid] = m;
  }
}

// ---------- parallel final reduce + classifier (256 threads, 1 block) ----------
__global__ __launch_bounds__(256) void pool_final(
    const float* __restrict__ psum, const float* __restrict__ pmax,
    int nblocks, int n, const float* __restrict__ cW1,
    const float* __restrict__ cb1, const float* __restrict__ cW2,
    const float* __restrict__ cb2, float* __restrict__ out) {
  __shared__ float sred[4][64], mred[4][64];
  __shared__ float z[128];
  __shared__ float hid[128];
  int tid = threadIdx.x;
  int c = tid & 63, q = tid >> 6;  // q in 0..3
  float s = 0.f, m = -1e30f;
  for (int b = q; b < nblocks; b += 4) {
    s += psum[b * 64 + c];
    m = fmaxf(m, pmax[b * 64 + c]);
  }
  sred[q][c] = s; mred[q][c] = m;
  __syncthreads();
  if (q == 0) {
    float st = sred[0][c] + sred[1][c] + sred[2][c] + sred[3][c];
    float mt = fmaxf(fmaxf(mred[0][c], mred[1][c]), fmaxf(mred[2][c], mred[3][c]));
    z[c] = st / (float)n;
    z[64 + c] = mt;
  }
  __syncthreads();
  if (tid < 128) {
    float a = cb1[tid];
#pragma unroll 4
    for (int k = 0; k < 128; ++k) a += z[k] * cW1[k * 128 + tid];
    hid[tid] = fmaxf(a, 0.f);
  }
  __syncthreads();
  if (tid < 2) {
    float o = cb2[tid];
    for (int j = 0; j < 128; ++j) o += hid[j] * cW2[j * 2 + tid];
    out[tid] = o;
  }
}

static inline int cdiv(long long a, long long b) { return (int)((a + b - 1) / b); }

extern "C" void kernel_launch(void* const* d_in, const int* in_sizes, int n_in,
                              void* d_out, int out_size, void* d_ws, size_t ws_size,
                              hipStream_t stream) {
  const float* x   = (const float*)d_in[0];
  const int*   ei  = (const int*)d_in[1];
  const float* W1  = (const float*)d_in[3];
  const float* as1 = (const float*)d_in[4];
  const float* ad1 = (const float*)d_in[5];
  const float* b1  = (const float*)d_in[6];
  const float* g1  = (const float*)d_in[7];
  const float* be1 = (const float*)d_in[8];
  const float* W2  = (const float*)d_in[9];
  const float* as2 = (const float*)d_in[10];
  const float* ad2 = (const float*)d_in[11];
  const float* b2  = (const float*)d_in[12];
  const float* g2  = (const float*)d_in[13];
  const float* be2 = (const float*)d_in[14];
  const float* W3  = (const float*)d_in[15];
  const float* as3 = (const float*)d_in[16];
  const float* ad3 = (const float*)d_in[17];
  const float* b3  = (const float*)d_in[18];
  const float* g3  = (const float*)d_in[19];
  const float* be3 = (const float*)d_in[20];
  const float* cW1 = (const float*)d_in[21];
  const float* cb1 = (const float*)d_in[22];
  const float* cW2 = (const float*)d_in[23];
  const float* cb2 = (const float*)d_in[24];
  float* out = (float*)d_out;

  const int N   = in_sizes[2];
  const int E0  = in_sizes[1] / 2;
  const int Et  = E0 + N;
  const int FIN = in_sizes[0] / N;

  float* ws = (float*)d_ws;
  size_t o = 0;
  ushort* Ab = (ushort*)(ws + o); o += (size_t)N * 64;   // N x 128 fp16 (h)
  ushort* Bb = (ushort*)(ws + o); o += (size_t)N * 64;   // N x 128 fp16 (x_l)
  float* als  = ws + o; o += (size_t)N * 4;
  float* ald  = ws + o; o += (size_t)N * 4;
  ushort* Wt1 = (ushort*)(ws + o); o += (128 * 512) / 2;
  ushort* Wt2 = (ushort*)(ws + o); o += (128 * 128) / 2;
  ushort* Wt3 = (ushort*)(ws + o); o += (64 * 128) / 2;
  float* psum = ws + o; o += 64 * 64;
  float* pmax = ws + o; o += 64 * 64;
  int* counts  = (int*)(ws + o); o += N + 1;
  int* offsets = (int*)(ws + o); o += N + 1;
  int* cursor  = (int*)(ws + o); o += N;
  int* bsum    = (int*)(ws + o); o += 256;
  int* csr_src = (int*)(ws + o); o += Et;

  const int* esrc = ei;
  const int* edst = ei + E0;
  const int NB = cdiv(N, 256);

  // ===== weight prep (single launch) =====
  prep_wt3<<<cdiv((long long)FIN * 128 + 128 * 128 + 128 * 64, TPB), TPB, 0, stream>>>(
      W1, Wt1, W2, Wt2, W3, Wt3, FIN);

  // ===== CSR build (once, reused by all 3 layers) =====
  zero_int<<<cdiv(N + 1, TPB), TPB, 0, stream>>>(counts, N + 1);
  hist_dst<<<cdiv(Et, TPB), TPB, 0, stream>>>(edst, counts, E0, Et);
  block_sums<<<NB, 256, 0, stream>>>(counts, bsum, N);
  scan_bsum<<<1, 256, 0, stream>>>(bsum, NB);
  scan_final<<<NB, 256, 0, stream>>>(counts, bsum, offsets, cursor, N, Et);
  scatter_csr<<<cdiv(Et, TPB), TPB, 0, stream>>>(esrc, edst, cursor, csr_src, E0, Et);

  // ===== Layer 1: x[N,512] fp32 -> h(Ab)+al -> x1(Bb) =====
  gemm_mfma<0, 128, true><<<cdiv(N, 64), 256, 0, stream>>>(x, Wt1, Ab, N, FIN, as1, ad1, als, ald);
  fused_attn<4, 32><<<cdiv(N, 4), 256, 0, stream>>>(Ab, als, ald, offsets, csr_src, b1, g1, be1, Bb, N);
  // ===== Layer 2: x1(Bb) -> h(Ab)+al -> x2(Bb) =====
  gemm_mfma<1, 128, true><<<cdiv(N, 64), 256, 0, stream>>>(Bb, Wt2, Ab, N, 128, as2, ad2, als, ald);
  fused_attn<4, 32><<<cdiv(N, 4), 256, 0, stream>>>(Ab, als, ald, offsets, csr_src, b2, g2, be2, Bb, N);
  // ===== Layer 3: x2(Bb) -> h[N,64](Ab) -> x3(Bb) =====
  gemm_mfma<1, 64, false><<<cdiv(N, 64), 256, 0, stream>>>(Bb, Wt3, Ab, N, 128, nullptr, nullptr, nullptr, nullptr);
  compute_al<1, 64><<<cdiv((long long)N, TPB), TPB, 0, stream>>>(Ab, as3, ad3, als, ald, N);
  fused_attn<1, 64><<<cdiv(N, 4), 256, 0, stream>>>(Ab, als, ald, offsets, csr_src, b3, g3, be3, Bb, N);
  // ===== Pool + classifier =====
  pool_partial<<<64, 256, 0, stream>>>(Bb, psum, pmax, N);
  pool_final<<<1, 256, 0, stream>>>(psum, pmax, 64, N, cW1, cb1, cW2, cb2, out);
}